// Round 3
// baseline (452.249 us; speedup 1.0000x reference)
//
#include <hip/hip_runtime.h>

typedef unsigned short u16;
typedef __attribute__((ext_vector_type(8))) short short8;
typedef __attribute__((ext_vector_type(4))) float floatx4;

__device__ __forceinline__ float bf2f(u16 u) {
  unsigned int v = ((unsigned int)u) << 16;
  return __builtin_bit_cast(float, v);
}
__device__ __forceinline__ u16 f2bf(float f) {
  unsigned int u = __builtin_bit_cast(unsigned int, f);
  u += 0x7FFFu + ((u >> 16) & 1u);
  return (u16)(u >> 16);
}
__device__ __forceinline__ void gload_lds16(const void* g, void* l) {
  __builtin_amdgcn_global_load_lds(
      (const __attribute__((address_space(1))) unsigned int*)g,
      (__attribute__((address_space(3))) unsigned int*)l, 16, 0, 0);
}

// ---------- transpose+convert: in fp32 [K][N] -> out bf16 [N][K] ----------
__global__ __launch_bounds__(256) void transpose_f32_bf16(const float* __restrict__ in,
                                                          u16* __restrict__ out,
                                                          int K, int N) {
  __shared__ float tile[32][33];
  int n0 = blockIdx.x * 32, k0 = blockIdx.y * 32;
  int tx = threadIdx.x & 31, ty = threadIdx.x >> 5;  // ty 0..7
#pragma unroll
  for (int i = 0; i < 4; i++) {
    int r = ty + i * 8;
    tile[r][tx] = in[(size_t)(k0 + r) * N + n0 + tx];
  }
  __syncthreads();
#pragma unroll
  for (int i = 0; i < 4; i++) {
    int r = ty + i * 8;
    out[(size_t)(n0 + r) * K + k0 + tx] = f2bf(tile[tx][r]);
  }
}

// ---------------- layernorm (Bessel std, eps added to std) -> bf16 ----------------
__global__ __launch_bounds__(256) void ln_f32(const float* __restrict__ xin,
                                              const float* __restrict__ wgt,
                                              const float* __restrict__ bia,
                                              u16* __restrict__ out) {
  int row = blockIdx.x, t = threadIdx.x;
  const float* xr = xin + (size_t)row * 1024 + t * 4;
  float4 f = *(const float4*)xr;
  float v[4] = {f.x, f.y, f.z, f.w};
  float s1 = v[0] + v[1] + v[2] + v[3];
  float s2 = v[0] * v[0] + v[1] * v[1] + v[2] * v[2] + v[3] * v[3];
#pragma unroll
  for (int off = 32; off; off >>= 1) {
    s1 += __shfl_down(s1, off);
    s2 += __shfl_down(s2, off);
  }
  __shared__ float red[8];
  int lane = t & 63, w = t >> 6;
  if (lane == 0) { red[w] = s1; red[4 + w] = s2; }
  __syncthreads();
  s1 = red[0] + red[1] + red[2] + red[3];
  s2 = red[4] + red[5] + red[6] + red[7];
  float mean = s1 * (1.f / 1024.f);
  float var = (s2 - 1024.f * mean * mean) * (1.f / 1023.f);
  var = var < 0.f ? 0.f : var;
  float inv = 1.f / (sqrtf(var) + 1e-5f);
  float4 wv = *(const float4*)(wgt + t * 4);
  float4 bv = *(const float4*)(bia + t * 4);
  float wa[4] = {wv.x, wv.y, wv.z, wv.w};
  float ba[4] = {bv.x, bv.y, bv.z, bv.w};
#pragma unroll
  for (int j = 0; j < 4; j++)
    out[(size_t)row * 1024 + t * 4 + j] = f2bf(wa[j] * ((v[j] - mean) * inv) + ba[j]);
}

// ------- m97-style MFMA GEMM: C = A(bf16,[M][K]) @ Bt(bf16,[N][K])^T -------
// EPI 0: bf16 out (with optional row-split across outp/outp2 at msplit)
// EPI 1: f32 out = v + res   EPI 2: bf16 gelu(v)   EPI 3: f32 += v (no bias)
// EPI 4: f32 += v (with bias)
template <int EPI>
__global__ __launch_bounds__(256) void gemm_bt(const u16* __restrict__ A,
                                               const u16* __restrict__ Bt,
                                               const float* __restrict__ bias,
                                               const float* __restrict__ res,
                                               void* __restrict__ outp,
                                               void* __restrict__ outp2,
                                               int msplit,
                                               int ldc, int K) {
  __shared__ __align__(16) u16 As[128 * 64];
  __shared__ __align__(16) u16 Bs[128 * 64];
  int tid = threadIdx.x;
  int lane = tid & 63, w = tid >> 6;
  int quad = lane >> 4, c16 = lane & 15;
  int wm = w >> 1, wn = w & 1;
  int bn = blockIdx.x, bm = blockIdx.y;
  const u16* Ab = A + (size_t)bm * 128 * K;
  const u16* Bb = Bt + (size_t)bn * 128 * K;

  floatx4 zf = {0.f, 0.f, 0.f, 0.f};
  floatx4 acc[4][4];
#pragma unroll
  for (int i = 0; i < 4; i++)
#pragma unroll
    for (int j = 0; j < 4; j++) acc[i][j] = zf;

  int kIters = K >> 6;
  for (int kt = 0; kt < kIters; ++kt) {
    __syncthreads();
    const u16* Abase = Ab + kt * 64;
    const u16* Bbase = Bb + kt * 64;
#pragma unroll
    for (int t2 = 0; t2 < 4; ++t2) {
      int chunk = w * 4 + t2;
      int idx = chunk * 512 + lane * 8;
      int r = idx >> 6, cc = idx & 63;
      gload_lds16(Abase + (size_t)r * K + cc, &As[chunk * 512]);
      gload_lds16(Bbase + (size_t)r * K + cc, &Bs[chunk * 512]);
    }
    __syncthreads();
#pragma unroll
    for (int ks = 0; ks < 2; ++ks) {
      short8 af[4], bfr[4];
#pragma unroll
      for (int mt = 0; mt < 4; mt++)
        af[mt] = *(const short8*)&As[(wm * 64 + mt * 16 + c16) * 64 + ks * 32 + quad * 8];
#pragma unroll
      for (int nt = 0; nt < 4; nt++)
        bfr[nt] = *(const short8*)&Bs[(wn * 64 + nt * 16 + c16) * 64 + ks * 32 + quad * 8];
#pragma unroll
      for (int mt = 0; mt < 4; mt++)
#pragma unroll
        for (int nt = 0; nt < 4; nt++)
          acc[mt][nt] = __builtin_amdgcn_mfma_f32_16x16x32_bf16(af[mt], bfr[nt], acc[mt][nt], 0, 0, 0);
    }
  }
  int gm0 = bm * 128 + wm * 64;
  int gn0 = bn * 128 + wn * 64;
#pragma unroll
  for (int nt = 0; nt < 4; nt++) {
    int gn = gn0 + nt * 16 + c16;
    float bia = 0.f;
    if constexpr (EPI != 3) bia = bias[gn];
#pragma unroll
    for (int mt = 0; mt < 4; mt++) {
#pragma unroll
      for (int r = 0; r < 4; r++) {
        int gm = gm0 + mt * 16 + quad * 4 + r;
        float v = acc[mt][nt][r] + bia;
        if constexpr (EPI == 0) {
          void* op = outp;
          int gmo = gm;
          if (gm >= msplit) { op = outp2; gmo = gm - msplit; }
          ((u16*)op)[(size_t)gmo * ldc + gn] = f2bf(v);
        } else if constexpr (EPI == 1) {
          size_t o = (size_t)gm * ldc + gn;
          ((float*)outp)[o] = v + res[o];
        } else if constexpr (EPI == 2) {
          size_t o = (size_t)gm * ldc + gn;
          float g = 0.5f * v * (1.f + tanhf(0.7978845608f * (v + 0.044715f * v * v * v)));
          ((u16*)outp)[o] = f2bf(g);
        } else {
          size_t o = (size_t)gm * ldc + gn;
          ((float*)outp)[o] += v;
        }
      }
    }
  }
}

// ---------------- flash attention v2: pair-tiled, 64-key tiles ----------------
// Ks stride 72 (pad); Vt [d][key ^ (d&56)] xor-swizzle; P stride 72.
__device__ __forceinline__ void attn_process(
    const short8& qf0, const short8& qf1,
    float* m_run, float* l_run, floatx4* oacc,
    const u16* __restrict__ Ks, const u16* __restrict__ Vt, u16* __restrict__ pw,
    int kt, int qt, int w, int quad, int c16, bool diag) {
  floatx4 zf = {0.f, 0.f, 0.f, 0.f};
  floatx4 s[4];
#pragma unroll
  for (int n = 0; n < 4; n++) {
    short8 kf0 = *(const short8*)&Ks[(n * 16 + c16) * 72 + quad * 8];
    short8 kf1 = *(const short8*)&Ks[(n * 16 + c16) * 72 + 32 + quad * 8];
    floatx4 a = zf;
    a = __builtin_amdgcn_mfma_f32_16x16x32_bf16(qf0, kf0, a, 0, 0, 0);
    a = __builtin_amdgcn_mfma_f32_16x16x32_bf16(qf1, kf1, a, 0, 0, 0);
    s[n] = a;
  }
  if (diag) {
#pragma unroll
    for (int n = 0; n < 4; n++) {
      int kg = kt * 64 + n * 16 + c16;
#pragma unroll
      for (int r = 0; r < 4; r++) {
        int qg = qt * 64 + w * 16 + quad * 4 + r;
        float sv = s[n][r] * 0.125f;
        s[n][r] = (kg > qg) ? -1e30f : sv;
      }
    }
  } else {
#pragma unroll
    for (int n = 0; n < 4; n++)
#pragma unroll
      for (int r = 0; r < 4; r++) s[n][r] *= 0.125f;
  }
  float mt[4];
#pragma unroll
  for (int r = 0; r < 4; r++)
    mt[r] = fmaxf(fmaxf(s[0][r], s[1][r]), fmaxf(s[2][r], s[3][r]));
#pragma unroll
  for (int off = 1; off < 16; off <<= 1)
#pragma unroll
    for (int r = 0; r < 4; r++) mt[r] = fmaxf(mt[r], __shfl_xor(mt[r], off));
  float alpha[4], lsum[4];
#pragma unroll
  for (int r = 0; r < 4; r++) {
    float mn = fmaxf(m_run[r], mt[r]);
    alpha[r] = __expf(m_run[r] - mn);
    m_run[r] = mn;
    lsum[r] = 0.f;
  }
#pragma unroll
  for (int n = 0; n < 4; n++)
#pragma unroll
    for (int r = 0; r < 4; r++) {
      float p = __expf(s[n][r] - m_run[r]);
      s[n][r] = p;
      lsum[r] += p;
    }
#pragma unroll
  for (int off = 1; off < 16; off <<= 1)
#pragma unroll
    for (int r = 0; r < 4; r++) lsum[r] += __shfl_xor(lsum[r], off);
#pragma unroll
  for (int r = 0; r < 4; r++) l_run[r] = l_run[r] * alpha[r] + lsum[r];
#pragma unroll
  for (int c = 0; c < 4; c++)
#pragma unroll
    for (int r = 0; r < 4; r++) oacc[c][r] *= alpha[r];
  // P (C-layout) -> per-wave LDS, stride 72
#pragma unroll
  for (int n = 0; n < 4; n++)
#pragma unroll
    for (int r = 0; r < 4; r++)
      pw[(quad * 4 + r) * 72 + n * 16 + c16] = f2bf(s[n][r]);
  short8 pf0 = *(const short8*)&pw[c16 * 72 + quad * 8];
  short8 pf1 = *(const short8*)&pw[c16 * 72 + 32 + quad * 8];
#pragma unroll
  for (int c = 0; c < 4; c++) {
    int d = c * 16 + c16;
    short8 vf0 = *(const short8*)&Vt[d * 64 + ((quad * 8) ^ (d & 56))];
    short8 vf1 = *(const short8*)&Vt[d * 64 + ((32 + quad * 8) ^ (d & 56))];
    oacc[c] = __builtin_amdgcn_mfma_f32_16x16x32_bf16(pf0, vf0, oacc[c], 0, 0, 0);
    oacc[c] = __builtin_amdgcn_mfma_f32_16x16x32_bf16(pf1, vf1, oacc[c], 0, 0, 0);
  }
}

// grid (16 pairs, 16 heads, 2 batches), 256 thr; block does q-tiles pr and 31-pr
__global__ __launch_bounds__(256) void attn_mfma2(const u16* __restrict__ qkv0,
                                                  const u16* __restrict__ qkv1,
                                                  u16* __restrict__ aout) {
  int pr = blockIdx.x, h = blockIdx.y;
  const u16* qkvb = blockIdx.z ? qkv1 : qkv0;
  aout += (size_t)blockIdx.z * 2048 * 1024;
  int qt0 = pr, qt1 = 31 - pr;
  int tid = threadIdx.x, lane = tid & 63, w = tid >> 6;
  int quad = lane >> 4, c16 = lane & 15;
  __shared__ __align__(16) u16 Ks[64 * 72];
  __shared__ __align__(16) u16 Vt[64 * 64];
  __shared__ __align__(16) u16 Ps[4][16 * 72];

  size_t qoffA = (size_t)(qt0 * 64 + w * 16 + c16) * 3072 + h * 64;
  short8 qfA0 = *(const short8*)(qkvb + qoffA + quad * 8);
  short8 qfA1 = *(const short8*)(qkvb + qoffA + 32 + quad * 8);
  size_t qoffB = (size_t)(qt1 * 64 + w * 16 + c16) * 3072 + h * 64;
  short8 qfB0 = *(const short8*)(qkvb + qoffB + quad * 8);
  short8 qfB1 = *(const short8*)(qkvb + qoffB + 32 + quad * 8);

  floatx4 zf = {0.f, 0.f, 0.f, 0.f};
  float mA[4], lA[4], mB[4], lB[4];
  floatx4 oA[4], oB[4];
#pragma unroll
  for (int r = 0; r < 4; r++) { mA[r] = -1e30f; lA[r] = 0.f; mB[r] = -1e30f; lB[r] = 0.f; }
#pragma unroll
  for (int c = 0; c < 4; c++) { oA[c] = zf; oB[c] = zf; }

  u16* pw = &Ps[w][0];
  for (int kt = 0; kt <= qt1; ++kt) {
    __syncthreads();
    // stage K (b128, stride 72) and V (xor-swizzled transpose) for 64 keys
#pragma unroll
    for (int u = 0; u < 2; u++) {
      int i = tid * 2 + u;             // 0..511
      int row = i >> 3, d8 = (i & 7) * 8;
      size_t gbase = (size_t)(kt * 64 + row) * 3072 + h * 64 + d8;
      short8 kv = *(const short8*)(qkvb + gbase + 1024);
      *(short8*)&Ks[row * 72 + d8] = kv;
      short8 vv = *(const short8*)(qkvb + gbase + 2048);
#pragma unroll
      for (int j = 0; j < 8; j++) {
        int d = d8 + j;
        Vt[d * 64 + (row ^ (d & 56))] = (u16)vv[j];
      }
    }
    __syncthreads();

    attn_process(qfB0, qfB1, mB, lB, oB, Ks, Vt, pw, kt, qt1, w, quad, c16, kt == qt1);
    if (kt <= qt0)
      attn_process(qfA0, qfA1, mA, lA, oA, Ks, Vt, pw, kt, qt0, w, quad, c16, kt == qt0);
  }

  size_t obA = (size_t)(qt0 * 64 + w * 16) * 1024 + h * 64;
  size_t obB = (size_t)(qt1 * 64 + w * 16) * 1024 + h * 64;
#pragma unroll
  for (int r = 0; r < 4; r++) {
    float invA = 1.f / lA[r], invB = 1.f / lB[r];
#pragma unroll
    for (int c = 0; c < 4; c++) {
      aout[obA + (size_t)(quad * 4 + r) * 1024 + c * 16 + c16] = f2bf(oA[c][r] * invA);
      aout[obB + (size_t)(quad * 4 + r) * 1024 + c * 16 + c16] = f2bf(oB[c][r] * invB);
    }
  }
}

extern "C" void kernel_launch(void* const* d_in, const int* in_sizes, int n_in,
                              void* d_out, int out_size, void* d_ws, size_t ws_size,
                              hipStream_t stream) {
  const float* x        = (const float*)d_in[0];
  const float* ln1_w    = (const float*)d_in[1];
  const float* ln1_b    = (const float*)d_in[2];
  const float* c_attn_w = (const float*)d_in[3];
  const float* c_attn_b = (const float*)d_in[4];
  const float* c_proj_w = (const float*)d_in[5];
  const float* c_proj_b = (const float*)d_in[6];
  const float* ln2_w    = (const float*)d_in[7];
  const float* ln2_b    = (const float*)d_in[8];
  const float* fc_w     = (const float*)d_in[9];
  const float* fc_b     = (const float*)d_in[10];
  const float* proj_w   = (const float*)d_in[11];
  const float* proj_b   = (const float*)d_in[12];

  char* ws = (char*)d_ws;
  const size_t MiB = 1u << 20;
  const int BIG = 1 << 30;

  // ---- phase 1 (merged batches; peak ws = 28 MiB + qkv0 parked in d_out) ----
  u16* wt_attn  = (u16*)(ws + 0);          // [3072][1024] bf16, 6 MiB
  u16* wt_cproj = (u16*)(ws + 6 * MiB);    // [1024][1024] bf16, 2 MiB
  u16* ln1b     = (u16*)(ws + 8 * MiB);    // [4096][1024] bf16, 8 MiB
  u16* qkv1     = (u16*)(ws + 16 * MiB);   // batch1 [2048][3072] bf16, 12 MiB
  u16* qkv0     = (u16*)d_out;             // batch0 [2048][3072] bf16 in out buf (dead until c_proj)
  u16* attn_out = (u16*)(ws + 8 * MiB);    // [4096][1024] bf16, reuses ln1b slot
  float* x1     = (float*)d_out;           // [4096][1024] fp32; final out in place

  transpose_f32_bf16<<<dim3(96, 32), 256, 0, stream>>>(c_attn_w, wt_attn, 1024, 3072);
  transpose_f32_bf16<<<dim3(32, 32), 256, 0, stream>>>(c_proj_w, wt_cproj, 1024, 1024);
  ln_f32<<<4096, 256, 0, stream>>>(x, ln1_w, ln1_b, ln1b);
  // one merged qkv GEMM, rows >=2048 routed to qkv1
  gemm_bt<0><<<dim3(24, 32), 256, 0, stream>>>(ln1b, wt_attn, c_attn_b, nullptr,
                                               qkv0, qkv1, 2048, 3072, 1024);
  attn_mfma2<<<dim3(16, 16, 2), 256, 0, stream>>>(qkv0, qkv1, attn_out);
  gemm_bt<1><<<dim3(8, 32), 256, 0, stream>>>(attn_out, wt_cproj, c_proj_b, x,
                                              x1, nullptr, BIG, 1024, 1024);

  // ---- phase 2 (chunk count adapts to workspace) ----
  // needs: 16 MiB (wt_fc+ln2b) + 4096*CN*2 (h) + 1024*CN*2 (projT)
  int NC = (ws_size >= 58720256) ? 1 : (ws_size >= 37748736) ? 2 : 4;
  int CN = 4096 / NC;
  u16* wt_fc = (u16*)(ws + 0);                                 // [4096][1024] bf16, 8 MiB
  u16* ln2b  = (u16*)(ws + 8 * MiB);                           // [4096][1024] bf16, 8 MiB
  u16* h_c   = (u16*)(ws + 16 * MiB);                          // [4096][CN] bf16
  u16* projT = (u16*)(ws + 16 * MiB + (size_t)4096 * CN * 2);  // [1024][CN] bf16

  transpose_f32_bf16<<<dim3(128, 32), 256, 0, stream>>>(fc_w, wt_fc, 1024, 4096);
  ln_f32<<<4096, 256, 0, stream>>>(x1, ln2_w, ln2_b, ln2b);
  for (int c = 0; c < NC; c++) {
    transpose_f32_bf16<<<dim3(32, CN / 32), 256, 0, stream>>>(
        proj_w + (size_t)c * CN * 1024, projT, CN, 1024);
    gemm_bt<2><<<dim3(CN / 128, 32), 256, 0, stream>>>(
        ln2b, wt_fc + (size_t)c * CN * 1024, fc_b + c * CN, nullptr,
        h_c, nullptr, BIG, CN, 1024);
    if (NC == 1)
      gemm_bt<1><<<dim3(8, 32), 256, 0, stream>>>(h_c, projT, proj_b, x1,
                                                  x1, nullptr, BIG, 1024, CN);
    else if (c < NC - 1)
      gemm_bt<3><<<dim3(8, 32), 256, 0, stream>>>(h_c, projT, nullptr, nullptr,
                                                  x1, nullptr, BIG, 1024, CN);
    else
      gemm_bt<4><<<dim3(8, 32), 256, 0, stream>>>(h_c, projT, proj_b, nullptr,
                                                  x1, nullptr, BIG, 1024, CN);
  }
}

// Round 4
// 448.573 us; speedup vs baseline: 1.0082x; 1.0082x over previous
//
#include <hip/hip_runtime.h>

typedef unsigned short u16;
typedef __attribute__((ext_vector_type(8))) short short8;
typedef __attribute__((ext_vector_type(4))) float floatx4;

__device__ __forceinline__ float bf2f(u16 u) {
  unsigned int v = ((unsigned int)u) << 16;
  return __builtin_bit_cast(float, v);
}
__device__ __forceinline__ u16 f2bf(float f) {
  unsigned int u = __builtin_bit_cast(unsigned int, f);
  u += 0x7FFFu + ((u >> 16) & 1u);
  return (u16)(u >> 16);
}
__device__ __forceinline__ void gload_lds16(const void* g, void* l) {
  __builtin_amdgcn_global_load_lds(
      (const __attribute__((address_space(1))) unsigned int*)g,
      (__attribute__((address_space(3))) unsigned int*)l, 16, 0, 0);
}

// ---------- transpose+convert: in fp32 [K][N] -> out bf16 [N][K] ----------
__global__ __launch_bounds__(256) void transpose_f32_bf16(const float* __restrict__ in,
                                                          u16* __restrict__ out,
                                                          int K, int N) {
  __shared__ float tile[32][33];
  int n0 = blockIdx.x * 32, k0 = blockIdx.y * 32;
  int tx = threadIdx.x & 31, ty = threadIdx.x >> 5;  // ty 0..7
#pragma unroll
  for (int i = 0; i < 4; i++) {
    int r = ty + i * 8;
    tile[r][tx] = in[(size_t)(k0 + r) * N + n0 + tx];
  }
  __syncthreads();
#pragma unroll
  for (int i = 0; i < 4; i++) {
    int r = ty + i * 8;
    out[(size_t)(n0 + r) * K + k0 + tx] = f2bf(tile[tx][r]);
  }
}

// ---------------- layernorm (Bessel std, eps added to std) -> bf16 ----------------
__global__ __launch_bounds__(256) void ln_f32(const float* __restrict__ xin,
                                              const float* __restrict__ wgt,
                                              const float* __restrict__ bia,
                                              u16* __restrict__ out) {
  int row = blockIdx.x, t = threadIdx.x;
  const float* xr = xin + (size_t)row * 1024 + t * 4;
  float4 f = *(const float4*)xr;
  float v[4] = {f.x, f.y, f.z, f.w};
  float s1 = v[0] + v[1] + v[2] + v[3];
  float s2 = v[0] * v[0] + v[1] * v[1] + v[2] * v[2] + v[3] * v[3];
#pragma unroll
  for (int off = 32; off; off >>= 1) {
    s1 += __shfl_down(s1, off);
    s2 += __shfl_down(s2, off);
  }
  __shared__ float red[8];
  int lane = t & 63, w = t >> 6;
  if (lane == 0) { red[w] = s1; red[4 + w] = s2; }
  __syncthreads();
  s1 = red[0] + red[1] + red[2] + red[3];
  s2 = red[4] + red[5] + red[6] + red[7];
  float mean = s1 * (1.f / 1024.f);
  float var = (s2 - 1024.f * mean * mean) * (1.f / 1023.f);
  var = var < 0.f ? 0.f : var;
  float inv = 1.f / (sqrtf(var) + 1e-5f);
  float4 wv = *(const float4*)(wgt + t * 4);
  float4 bv = *(const float4*)(bia + t * 4);
  float wa[4] = {wv.x, wv.y, wv.z, wv.w};
  float ba[4] = {bv.x, bv.y, bv.z, bv.w};
#pragma unroll
  for (int j = 0; j < 4; j++)
    out[(size_t)row * 1024 + t * 4 + j] = f2bf(wa[j] * ((v[j] - mean) * inv) + ba[j]);
}

// ------- m97-style MFMA GEMM: C = A(bf16,[M][K]) @ Bt(bf16,[N][K])^T -------
// EPI 0: bf16 out (with optional row-split across outp/outp2 at msplit)
// EPI 1: f32 out = v + res   EPI 2: bf16 gelu(v)   EPI 3: f32 += v (no bias)
// EPI 4: f32 += v (with bias)
template <int EPI>
__global__ __launch_bounds__(256) void gemm_bt(const u16* __restrict__ A,
                                               const u16* __restrict__ Bt,
                                               const float* __restrict__ bias,
                                               const float* __restrict__ res,
                                               void* __restrict__ outp,
                                               void* __restrict__ outp2,
                                               int msplit,
                                               int ldc, int K) {
  __shared__ __align__(16) u16 As[128 * 64];
  __shared__ __align__(16) u16 Bs[128 * 64];
  int tid = threadIdx.x;
  int lane = tid & 63, w = tid >> 6;
  int quad = lane >> 4, c16 = lane & 15;
  int wm = w >> 1, wn = w & 1;
  int bn = blockIdx.x, bm = blockIdx.y;
  const u16* Ab = A + (size_t)bm * 128 * K;
  const u16* Bb = Bt + (size_t)bn * 128 * K;

  floatx4 zf = {0.f, 0.f, 0.f, 0.f};
  floatx4 acc[4][4];
#pragma unroll
  for (int i = 0; i < 4; i++)
#pragma unroll
    for (int j = 0; j < 4; j++) acc[i][j] = zf;

  int kIters = K >> 6;
  for (int kt = 0; kt < kIters; ++kt) {
    __syncthreads();
    const u16* Abase = Ab + kt * 64;
    const u16* Bbase = Bb + kt * 64;
#pragma unroll
    for (int t2 = 0; t2 < 4; ++t2) {
      int chunk = w * 4 + t2;
      int idx = chunk * 512 + lane * 8;
      int r = idx >> 6, cc = idx & 63;
      gload_lds16(Abase + (size_t)r * K + cc, &As[chunk * 512]);
      gload_lds16(Bbase + (size_t)r * K + cc, &Bs[chunk * 512]);
    }
    __syncthreads();
#pragma unroll
    for (int ks = 0; ks < 2; ++ks) {
      short8 af[4], bfr[4];
#pragma unroll
      for (int mt = 0; mt < 4; mt++)
        af[mt] = *(const short8*)&As[(wm * 64 + mt * 16 + c16) * 64 + ks * 32 + quad * 8];
#pragma unroll
      for (int nt = 0; nt < 4; nt++)
        bfr[nt] = *(const short8*)&Bs[(wn * 64 + nt * 16 + c16) * 64 + ks * 32 + quad * 8];
#pragma unroll
      for (int mt = 0; mt < 4; mt++)
#pragma unroll
        for (int nt = 0; nt < 4; nt++)
          acc[mt][nt] = __builtin_amdgcn_mfma_f32_16x16x32_bf16(af[mt], bfr[nt], acc[mt][nt], 0, 0, 0);
    }
  }
  int gm0 = bm * 128 + wm * 64;
  int gn0 = bn * 128 + wn * 64;
#pragma unroll
  for (int nt = 0; nt < 4; nt++) {
    int gn = gn0 + nt * 16 + c16;
    float bia = 0.f;
    if constexpr (EPI != 3) bia = bias[gn];
#pragma unroll
    for (int mt = 0; mt < 4; mt++) {
#pragma unroll
      for (int r = 0; r < 4; r++) {
        int gm = gm0 + mt * 16 + quad * 4 + r;
        float v = acc[mt][nt][r] + bia;
        if constexpr (EPI == 0) {
          void* op = outp;
          int gmo = gm;
          if (gm >= msplit) { op = outp2; gmo = gm - msplit; }
          ((u16*)op)[(size_t)gmo * ldc + gn] = f2bf(v);
        } else if constexpr (EPI == 1) {
          size_t o = (size_t)gm * ldc + gn;
          ((float*)outp)[o] = v + res[o];
        } else if constexpr (EPI == 2) {
          size_t o = (size_t)gm * ldc + gn;
          float g = 0.5f * v * (1.f + tanhf(0.7978845608f * (v + 0.044715f * v * v * v)));
          ((u16*)outp)[o] = f2bf(g);
        } else {
          size_t o = (size_t)gm * ldc + gn;
          ((float*)outp)[o] += v;
        }
      }
    }
  }
}

// ---------------- flash attention v2: pair-tiled, 64-key tiles ----------------
// Ks stride 72 (pad); Vt [d][key ^ (d&56)] xor-swizzle; P stride 72.
// Q pre-scaled by 0.125 (exact), so QK^T comes out pre-scaled.
__device__ __forceinline__ void attn_process(
    const short8& qf0, const short8& qf1,
    float* m_run, float* l_run, floatx4* oacc,
    const u16* __restrict__ Ks, const u16* __restrict__ Vt, u16* __restrict__ pw,
    int kt, int qt, int w, int quad, int c16, bool diag) {
  floatx4 zf = {0.f, 0.f, 0.f, 0.f};
  floatx4 s[4];
#pragma unroll
  for (int n = 0; n < 4; n++) {
    short8 kf0 = *(const short8*)&Ks[(n * 16 + c16) * 72 + quad * 8];
    short8 kf1 = *(const short8*)&Ks[(n * 16 + c16) * 72 + 32 + quad * 8];
    floatx4 a = zf;
    a = __builtin_amdgcn_mfma_f32_16x16x32_bf16(qf0, kf0, a, 0, 0, 0);
    a = __builtin_amdgcn_mfma_f32_16x16x32_bf16(qf1, kf1, a, 0, 0, 0);
    s[n] = a;
  }
  if (diag) {
#pragma unroll
    for (int n = 0; n < 4; n++) {
      int kg = kt * 64 + n * 16 + c16;
#pragma unroll
      for (int r = 0; r < 4; r++) {
        int qg = qt * 64 + w * 16 + quad * 4 + r;
        s[n][r] = (kg > qg) ? -1e30f : s[n][r];
      }
    }
  }
  float mt[4];
#pragma unroll
  for (int r = 0; r < 4; r++)
    mt[r] = fmaxf(fmaxf(s[0][r], s[1][r]), fmaxf(s[2][r], s[3][r]));
#pragma unroll
  for (int off = 1; off < 16; off <<= 1)
#pragma unroll
    for (int r = 0; r < 4; r++) mt[r] = fmaxf(mt[r], __shfl_xor(mt[r], off));
  float alpha[4], lsum[4];
#pragma unroll
  for (int r = 0; r < 4; r++) {
    float mn = fmaxf(m_run[r], mt[r]);
    alpha[r] = __expf(m_run[r] - mn);
    m_run[r] = mn;
    lsum[r] = 0.f;
  }
#pragma unroll
  for (int n = 0; n < 4; n++)
#pragma unroll
    for (int r = 0; r < 4; r++) {
      float p = __expf(s[n][r] - m_run[r]);
      s[n][r] = p;
      lsum[r] += p;
    }
#pragma unroll
  for (int off = 1; off < 16; off <<= 1)
#pragma unroll
    for (int r = 0; r < 4; r++) lsum[r] += __shfl_xor(lsum[r], off);
#pragma unroll
  for (int r = 0; r < 4; r++) l_run[r] = l_run[r] * alpha[r] + lsum[r];
#pragma unroll
  for (int c = 0; c < 4; c++)
#pragma unroll
    for (int r = 0; r < 4; r++) oacc[c][r] *= alpha[r];
  // P (C-layout) -> per-wave LDS, stride 72
#pragma unroll
  for (int n = 0; n < 4; n++)
#pragma unroll
    for (int r = 0; r < 4; r++)
      pw[(quad * 4 + r) * 72 + n * 16 + c16] = f2bf(s[n][r]);
  short8 pf0 = *(const short8*)&pw[c16 * 72 + quad * 8];
  short8 pf1 = *(const short8*)&pw[c16 * 72 + 32 + quad * 8];
#pragma unroll
  for (int c = 0; c < 4; c++) {
    int d = c * 16 + c16;
    short8 vf0 = *(const short8*)&Vt[d * 64 + ((quad * 8) ^ (d & 56))];
    short8 vf1 = *(const short8*)&Vt[d * 64 + ((32 + quad * 8) ^ (d & 56))];
    oacc[c] = __builtin_amdgcn_mfma_f32_16x16x32_bf16(pf0, vf0, oacc[c], 0, 0, 0);
    oacc[c] = __builtin_amdgcn_mfma_f32_16x16x32_bf16(pf1, vf1, oacc[c], 0, 0, 0);
  }
}

// multiply bf16 octet by 0.125 (power of two -> exact)
__device__ __forceinline__ short8 scale8_eighth(short8 v) {
  short8 r;
#pragma unroll
  for (int j = 0; j < 8; j++) {
    unsigned int b = ((unsigned int)(u16)v[j]) << 16;
    float f = __builtin_bit_cast(float, b) * 0.125f;
    r[j] = (short)(u16)(__builtin_bit_cast(unsigned int, f) >> 16);
  }
  return r;
}

// grid (16 pairs, 16 heads, 2 batches), 256 thr; block does q-tiles pr and 31-pr.
// K/V staging is double-buffered: global->reg issued before compute, reg->LDS
// committed into the other buffer after compute; ONE barrier per kv-tile.
__global__ __launch_bounds__(256) void attn_mfma2(const u16* __restrict__ qkv0,
                                                  const u16* __restrict__ qkv1,
                                                  u16* __restrict__ aout) {
  int pr = blockIdx.x, h = blockIdx.y;
  const u16* qkvb = blockIdx.z ? qkv1 : qkv0;
  aout += (size_t)blockIdx.z * 2048 * 1024;
  int qt0 = pr, qt1 = 31 - pr;
  int tid = threadIdx.x, lane = tid & 63, w = tid >> 6;
  int quad = lane >> 4, c16 = lane & 15;
  __shared__ __align__(16) u16 Ks[2][64 * 72];
  __shared__ __align__(16) u16 Vt[2][64 * 64];
  __shared__ __align__(16) u16 Ps[4][16 * 72];

  size_t qoffA = (size_t)(qt0 * 64 + w * 16 + c16) * 3072 + h * 64;
  short8 qfA0 = scale8_eighth(*(const short8*)(qkvb + qoffA + quad * 8));
  short8 qfA1 = scale8_eighth(*(const short8*)(qkvb + qoffA + 32 + quad * 8));
  size_t qoffB = (size_t)(qt1 * 64 + w * 16 + c16) * 3072 + h * 64;
  short8 qfB0 = scale8_eighth(*(const short8*)(qkvb + qoffB + quad * 8));
  short8 qfB1 = scale8_eighth(*(const short8*)(qkvb + qoffB + 32 + quad * 8));

  floatx4 zf = {0.f, 0.f, 0.f, 0.f};
  float mA[4], lA[4], mB[4], lB[4];
  floatx4 oA[4], oB[4];
#pragma unroll
  for (int r = 0; r < 4; r++) { mA[r] = -1e30f; lA[r] = 0.f; mB[r] = -1e30f; lB[r] = 0.f; }
#pragma unroll
  for (int c = 0; c < 4; c++) { oA[c] = zf; oB[c] = zf; }

  // staging geometry: thread covers row srow, d [sd8, sd8+16)
  int srow = (tid * 2) >> 3;          // 0..63
  int sd8 = ((tid * 2) & 7) * 8;      // 0,16,32,48
  short8 kr0, kr1, vr0, vr1;

  auto issue = [&](int kt) {
    size_t gb = (size_t)(kt * 64 + srow) * 3072 + h * 64 + sd8;
    kr0 = *(const short8*)(qkvb + gb + 1024);
    kr1 = *(const short8*)(qkvb + gb + 1024 + 8);
    vr0 = *(const short8*)(qkvb + gb + 2048);
    vr1 = *(const short8*)(qkvb + gb + 2048 + 8);
  };
  auto commit = [&](int b) {
    *(short8*)&Ks[b][srow * 72 + sd8] = kr0;
    *(short8*)&Ks[b][srow * 72 + sd8 + 8] = kr1;
    u16* vt = Vt[b];
#pragma unroll
    for (int j = 0; j < 8; j++) {
      int d = sd8 + j;
      vt[d * 64 + (srow ^ (d & 56))] = (u16)vr0[j];
      int d2 = sd8 + 8 + j;
      vt[d2 * 64 + (srow ^ (d2 & 56))] = (u16)vr1[j];
    }
  };

  u16* pw = &Ps[w][0];
  int last = qt1;
  issue(0);
  commit(0);
  __syncthreads();
  int cur = 0;
  for (int kt = 0; kt <= last; ++kt) {
    if (kt < last) issue(kt + 1);

    attn_process(qfB0, qfB1, mB, lB, oB, Ks[cur], Vt[cur], pw, kt, qt1, w, quad, c16, kt == qt1);
    if (kt <= qt0)
      attn_process(qfA0, qfA1, mA, lA, oA, Ks[cur], Vt[cur], pw, kt, qt0, w, quad, c16, kt == qt0);

    if (kt < last) {
      commit(cur ^ 1);   // other buffer: no hazard with waves still computing on cur
      __syncthreads();   // writes visible before next tile's compute
      cur ^= 1;
    }
  }

  size_t obA = (size_t)(qt0 * 64 + w * 16) * 1024 + h * 64;
  size_t obB = (size_t)(qt1 * 64 + w * 16) * 1024 + h * 64;
#pragma unroll
  for (int r = 0; r < 4; r++) {
    float invA = 1.f / lA[r], invB = 1.f / lB[r];
#pragma unroll
    for (int c = 0; c < 4; c++) {
      aout[obA + (size_t)(quad * 4 + r) * 1024 + c * 16 + c16] = f2bf(oA[c][r] * invA);
      aout[obB + (size_t)(quad * 4 + r) * 1024 + c * 16 + c16] = f2bf(oB[c][r] * invB);
    }
  }
}

extern "C" void kernel_launch(void* const* d_in, const int* in_sizes, int n_in,
                              void* d_out, int out_size, void* d_ws, size_t ws_size,
                              hipStream_t stream) {
  const float* x        = (const float*)d_in[0];
  const float* ln1_w    = (const float*)d_in[1];
  const float* ln1_b    = (const float*)d_in[2];
  const float* c_attn_w = (const float*)d_in[3];
  const float* c_attn_b = (const float*)d_in[4];
  const float* c_proj_w = (const float*)d_in[5];
  const float* c_proj_b = (const float*)d_in[6];
  const float* ln2_w    = (const float*)d_in[7];
  const float* ln2_b    = (const float*)d_in[8];
  const float* fc_w     = (const float*)d_in[9];
  const float* fc_b     = (const float*)d_in[10];
  const float* proj_w   = (const float*)d_in[11];
  const float* proj_b   = (const float*)d_in[12];

  char* ws = (char*)d_ws;
  const size_t MiB = 1u << 20;
  const int BIG = 1 << 30;

  // ---- phase 1 (merged batches; peak ws = 28 MiB + qkv0 parked in d_out) ----
  u16* wt_attn  = (u16*)(ws + 0);          // [3072][1024] bf16, 6 MiB
  u16* wt_cproj = (u16*)(ws + 6 * MiB);    // [1024][1024] bf16, 2 MiB
  u16* ln1b     = (u16*)(ws + 8 * MiB);    // [4096][1024] bf16, 8 MiB
  u16* qkv1     = (u16*)(ws + 16 * MiB);   // batch1 [2048][3072] bf16, 12 MiB
  u16* qkv0     = (u16*)d_out;             // batch0 [2048][3072] bf16 in out buf (dead until c_proj)
  u16* attn_out = (u16*)(ws + 8 * MiB);    // [4096][1024] bf16, reuses ln1b slot
  float* x1     = (float*)d_out;           // [4096][1024] fp32; final out in place

  transpose_f32_bf16<<<dim3(96, 32), 256, 0, stream>>>(c_attn_w, wt_attn, 1024, 3072);
  transpose_f32_bf16<<<dim3(32, 32), 256, 0, stream>>>(c_proj_w, wt_cproj, 1024, 1024);
  ln_f32<<<4096, 256, 0, stream>>>(x, ln1_w, ln1_b, ln1b);
  // one merged qkv GEMM, rows >=2048 routed to qkv1
  gemm_bt<0><<<dim3(24, 32), 256, 0, stream>>>(ln1b, wt_attn, c_attn_b, nullptr,
                                               qkv0, qkv1, 2048, 3072, 1024);
  attn_mfma2<<<dim3(16, 16, 2), 256, 0, stream>>>(qkv0, qkv1, attn_out);
  gemm_bt<1><<<dim3(8, 32), 256, 0, stream>>>(attn_out, wt_cproj, c_proj_b, x,
                                              x1, nullptr, BIG, 1024, 1024);

  // ---- phase 2 (chunk count adapts to workspace) ----
  // needs: 16 MiB (wt_fc+ln2b) + 4096*CN*2 (h) + 1024*CN*2 (projT)
  int NC = (ws_size >= 58720256) ? 1 : (ws_size >= 37748736) ? 2 : 4;
  int CN = 4096 / NC;
  u16* wt_fc = (u16*)(ws + 0);                                 // [4096][1024] bf16, 8 MiB
  u16* ln2b  = (u16*)(ws + 8 * MiB);                           // [4096][1024] bf16, 8 MiB
  u16* h_c   = (u16*)(ws + 16 * MiB);                          // [4096][CN] bf16
  u16* projT = (u16*)(ws + 16 * MiB + (size_t)4096 * CN * 2);  // [1024][CN] bf16

  transpose_f32_bf16<<<dim3(128, 32), 256, 0, stream>>>(fc_w, wt_fc, 1024, 4096);
  ln_f32<<<4096, 256, 0, stream>>>(x1, ln2_w, ln2_b, ln2b);
  for (int c = 0; c < NC; c++) {
    transpose_f32_bf16<<<dim3(32, CN / 32), 256, 0, stream>>>(
        proj_w + (size_t)c * CN * 1024, projT, CN, 1024);
    gemm_bt<2><<<dim3(CN / 128, 32), 256, 0, stream>>>(
        ln2b, wt_fc + (size_t)c * CN * 1024, fc_b + c * CN, nullptr,
        h_c, nullptr, BIG, CN, 1024);
    if (NC == 1)
      gemm_bt<1><<<dim3(8, 32), 256, 0, stream>>>(h_c, projT, proj_b, x1,
                                                  x1, nullptr, BIG, 1024, CN);
    else if (c < NC - 1)
      gemm_bt<3><<<dim3(8, 32), 256, 0, stream>>>(h_c, projT, nullptr, nullptr,
                                                  x1, nullptr, BIG, 1024, CN);
    else
      gemm_bt<4><<<dim3(8, 32), 256, 0, stream>>>(h_c, projT, proj_b, nullptr,
                                                  x1, nullptr, BIG, 1024, CN);
  }
}

// Round 8
// 399.499 us; speedup vs baseline: 1.1320x; 1.1228x over previous
//
#include <hip/hip_runtime.h>

typedef unsigned short u16;
typedef __attribute__((ext_vector_type(8))) short short8;
typedef __attribute__((ext_vector_type(4))) float floatx4;

__device__ __forceinline__ float bf2f(u16 u) {
  unsigned int v = ((unsigned int)u) << 16;
  return __builtin_bit_cast(float, v);
}
__device__ __forceinline__ u16 f2bf(float f) {
  unsigned int u = __builtin_bit_cast(unsigned int, f);
  u += 0x7FFFu + ((u >> 16) & 1u);
  return (u16)(u >> 16);
}
__device__ __forceinline__ void gload_lds16(const void* g, void* l) {
  __builtin_amdgcn_global_load_lds(
      (const __attribute__((address_space(1))) unsigned int*)g,
      (__attribute__((address_space(3))) unsigned int*)l, 16, 0, 0);
}

// ---------- transpose+convert: in fp32 [K][N] -> out bf16 [N][K] ----------
__global__ __launch_bounds__(256) void transpose_f32_bf16(const float* __restrict__ in,
                                                          u16* __restrict__ out,
                                                          int K, int N) {
  __shared__ float tile[32][33];
  int n0 = blockIdx.x * 32, k0 = blockIdx.y * 32;
  int tx = threadIdx.x & 31, ty = threadIdx.x >> 5;  // ty 0..7
#pragma unroll
  for (int i = 0; i < 4; i++) {
    int r = ty + i * 8;
    tile[r][tx] = in[(size_t)(k0 + r) * N + n0 + tx];
  }
  __syncthreads();
#pragma unroll
  for (int i = 0; i < 4; i++) {
    int r = ty + i * 8;
    out[(size_t)(n0 + r) * K + k0 + tx] = f2bf(tile[tx][r]);
  }
}

// ---------------- layernorm (Bessel std, eps added to std) -> bf16 ----------------
__global__ __launch_bounds__(256) void ln_f32(const float* __restrict__ xin,
                                              const float* __restrict__ wgt,
                                              const float* __restrict__ bia,
                                              u16* __restrict__ out) {
  int row = blockIdx.x, t = threadIdx.x;
  const float* xr = xin + (size_t)row * 1024 + t * 4;
  float4 f = *(const float4*)xr;
  float v[4] = {f.x, f.y, f.z, f.w};
  float s1 = v[0] + v[1] + v[2] + v[3];
  float s2 = v[0] * v[0] + v[1] * v[1] + v[2] * v[2] + v[3] * v[3];
#pragma unroll
  for (int off = 32; off; off >>= 1) {
    s1 += __shfl_down(s1, off);
    s2 += __shfl_down(s2, off);
  }
  __shared__ float red[8];
  int lane = t & 63, w = t >> 6;
  if (lane == 0) { red[w] = s1; red[4 + w] = s2; }
  __syncthreads();
  s1 = red[0] + red[1] + red[2] + red[3];
  s2 = red[4] + red[5] + red[6] + red[7];
  float mean = s1 * (1.f / 1024.f);
  float var = (s2 - 1024.f * mean * mean) * (1.f / 1023.f);
  var = var < 0.f ? 0.f : var;
  float inv = 1.f / (sqrtf(var) + 1e-5f);
  float4 wv = *(const float4*)(wgt + t * 4);
  float4 bv = *(const float4*)(bia + t * 4);
  float wa[4] = {wv.x, wv.y, wv.z, wv.w};
  float ba[4] = {bv.x, bv.y, bv.z, bv.w};
#pragma unroll
  for (int j = 0; j < 4; j++)
    out[(size_t)row * 1024 + t * 4 + j] = f2bf(wa[j] * ((v[j] - mean) * inv) + ba[j]);
}

// ------- MFMA GEMM, counted-vmcnt dbuf pipeline: C = A @ Bt^T -------
// A bf16 [M][K], Bt bf16 [N][K]. 128x128 tile, BK=64, 256 thr.
// LDS tiles XOR-swizzled (T2): lds[row][col8 ^ (row&7)] via pre-swizzled
// global source (gload_lds writes linearly) + swizzled read column.
// Sync: [stage(t+1)->slot^1][vmcnt(8)][bar][compute(t)<-slot][bar] (T3/T4-lite).
// XCD-chunked block swizzle (T1); requires gridDim.x*gridDim.y % 8 == 0.
// EPI 0: bf16 out (row-split at msplit)  1: f32 = v+res  2: bf16 gelu(v)
// EPI 3: f32 += v (no bias)  4: f32 += v (with bias)
template <int EPI>
__global__ __launch_bounds__(256) void gemm_bt(const u16* __restrict__ A,
                                               const u16* __restrict__ Bt,
                                               const float* __restrict__ bias,
                                               const float* __restrict__ res,
                                               void* __restrict__ outp,
                                               void* __restrict__ outp2,
                                               int msplit,
                                               int ldc, int K) {
  __shared__ __align__(16) u16 As[2][128 * 64];
  __shared__ __align__(16) u16 Bs[2][128 * 64];
  int tid = threadIdx.x;
  int lane = tid & 63, w = tid >> 6;
  int quad = lane >> 4, c16 = lane & 15;
  int wm = w >> 1, wn = w & 1;
  // T1: XCD-chunked bijective swizzle (nwg % 8 == 0 for all launches here)
  int nbx = gridDim.x;
  int nwg = nbx * gridDim.y;
  int bid = blockIdx.y * nbx + blockIdx.x;
  int swz = (bid & 7) * (nwg >> 3) + (bid >> 3);
  int bn = swz % nbx, bm = swz / nbx;
  const u16* Ab = A + (size_t)bm * 128 * K;
  const u16* Bb = Bt + (size_t)bn * 128 * K;

  // staging geometry: lane covers dest row r = j*32 + (tid>>3), 16B slot tid&7.
  // source column pre-swizzled: slot ^ (row&7)  (row&7 == (tid>>3)&7).
  int rbase = tid >> 3;                                  // 0..31
  int csrc = (((tid & 7) ^ ((tid >> 3) & 7))) * 8;       // u16 col offset
  int dbase = w * 512;                                   // u16 dest base per wave

  floatx4 zf = {0.f, 0.f, 0.f, 0.f};
  floatx4 acc[4][4];
#pragma unroll
  for (int i = 0; i < 4; i++)
#pragma unroll
    for (int j = 0; j < 4; j++) acc[i][j] = zf;

  auto stage = [&](int kt, int sl) {
    const u16* At = Ab + kt * 64;
    const u16* Bt2 = Bb + kt * 64;
#pragma unroll
    for (int j = 0; j < 4; j++) {
      int r = j * 32 + rbase;
      gload_lds16(At + (size_t)r * K + csrc, &As[sl][j * 2048 + dbase]);
      gload_lds16(Bt2 + (size_t)r * K + csrc, &Bs[sl][j * 2048 + dbase]);
    }
  };

  int nt = K >> 6;
  stage(0, 0);
  int sl = 0;
  for (int t = 0; t < nt; ++t) {
    if (t + 1 < nt) {
      stage(t + 1, sl ^ 1);
      asm volatile("s_waitcnt vmcnt(8)" ::: "memory");   // tile t landed; t+1 in flight
    } else {
      asm volatile("s_waitcnt vmcnt(0)" ::: "memory");
    }
    __builtin_amdgcn_s_barrier();
    __builtin_amdgcn_sched_barrier(0);
    const u16* as = As[sl];
    const u16* bs = Bs[sl];
#pragma unroll
    for (int ks = 0; ks < 2; ++ks) {
      int col = (ks * 32 + quad * 8) ^ ((c16 & 7) * 8);  // T2 read swizzle
      short8 af[4], bfr[4];
#pragma unroll
      for (int mt = 0; mt < 4; mt++)
        af[mt] = *(const short8*)&as[(wm * 64 + mt * 16 + c16) * 64 + col];
#pragma unroll
      for (int nt2 = 0; nt2 < 4; nt2++)
        bfr[nt2] = *(const short8*)&bs[(wn * 64 + nt2 * 16 + c16) * 64 + col];
#pragma unroll
      for (int mt = 0; mt < 4; mt++)
#pragma unroll
        for (int nt2 = 0; nt2 < 4; nt2++)
          acc[mt][nt2] = __builtin_amdgcn_mfma_f32_16x16x32_bf16(af[mt], bfr[nt2], acc[mt][nt2], 0, 0, 0);
    }
    __builtin_amdgcn_s_barrier();   // WAR: slot overwritten by next stage
    __builtin_amdgcn_sched_barrier(0);
    sl ^= 1;
  }

  int gm0 = bm * 128 + wm * 64;
  int gn0 = bn * 128 + wn * 64;
#pragma unroll
  for (int nt2 = 0; nt2 < 4; nt2++) {
    int gn = gn0 + nt2 * 16 + c16;
    float bia = 0.f;
    if constexpr (EPI != 3) bia = bias[gn];
#pragma unroll
    for (int mt = 0; mt < 4; mt++) {
#pragma unroll
      for (int r = 0; r < 4; r++) {
        int gm = gm0 + mt * 16 + quad * 4 + r;
        float v = acc[mt][nt2][r] + bia;
        if constexpr (EPI == 0) {
          void* op = outp;
          int gmo = gm;
          if (gm >= msplit) { op = outp2; gmo = gm - msplit; }
          ((u16*)op)[(size_t)gmo * ldc + gn] = f2bf(v);
        } else if constexpr (EPI == 1) {
          size_t o = (size_t)gm * ldc + gn;
          ((float*)outp)[o] = v + res[o];
        } else if constexpr (EPI == 2) {
          size_t o = (size_t)gm * ldc + gn;
          float g = 0.5f * v * (1.f + tanhf(0.7978845608f * (v + 0.044715f * v * v * v)));
          ((u16*)outp)[o] = f2bf(g);
        } else {
          size_t o = (size_t)gm * ldc + gn;
          ((float*)outp)[o] += v;
        }
      }
    }
  }
}

// ---------------- flash attention v2: pair-tiled, 64-key tiles ----------------
// Ks stride 72 (pad); Vt [d][key ^ (d&56)] xor-swizzle; P stride 72.
// Q pre-scaled by 0.125 (exact), so QK^T comes out pre-scaled.
__device__ __forceinline__ void attn_process(
    const short8& qf0, const short8& qf1,
    float* m_run, float* l_run, floatx4* oacc,
    const u16* __restrict__ Ks, const u16* __restrict__ Vt, u16* __restrict__ pw,
    int kt, int qt, int w, int quad, int c16, bool diag) {
  floatx4 zf = {0.f, 0.f, 0.f, 0.f};
  floatx4 s[4];
#pragma unroll
  for (int n = 0; n < 4; n++) {
    short8 kf0 = *(const short8*)&Ks[(n * 16 + c16) * 72 + quad * 8];
    short8 kf1 = *(const short8*)&Ks[(n * 16 + c16) * 72 + 32 + quad * 8];
    floatx4 a = zf;
    a = __builtin_amdgcn_mfma_f32_16x16x32_bf16(qf0, kf0, a, 0, 0, 0);
    a = __builtin_amdgcn_mfma_f32_16x16x32_bf16(qf1, kf1, a, 0, 0, 0);
    s[n] = a;
  }
  if (diag) {
#pragma unroll
    for (int n = 0; n < 4; n++) {
      int kg = kt * 64 + n * 16 + c16;
#pragma unroll
      for (int r = 0; r < 4; r++) {
        int qg = qt * 64 + w * 16 + quad * 4 + r;
        s[n][r] = (kg > qg) ? -1e30f : s[n][r];
      }
    }
  }
  float mt[4];
#pragma unroll
  for (int r = 0; r < 4; r++)
    mt[r] = fmaxf(fmaxf(s[0][r], s[1][r]), fmaxf(s[2][r], s[3][r]));
#pragma unroll
  for (int off = 1; off < 16; off <<= 1)
#pragma unroll
    for (int r = 0; r < 4; r++) mt[r] = fmaxf(mt[r], __shfl_xor(mt[r], off));
  float alpha[4], lsum[4];
#pragma unroll
  for (int r = 0; r < 4; r++) {
    float mn = fmaxf(m_run[r], mt[r]);
    alpha[r] = __expf(m_run[r] - mn);
    m_run[r] = mn;
    lsum[r] = 0.f;
  }
#pragma unroll
  for (int n = 0; n < 4; n++)
#pragma unroll
    for (int r = 0; r < 4; r++) {
      float p = __expf(s[n][r] - m_run[r]);
      s[n][r] = p;
      lsum[r] += p;
    }
#pragma unroll
  for (int off = 1; off < 16; off <<= 1)
#pragma unroll
    for (int r = 0; r < 4; r++) lsum[r] += __shfl_xor(lsum[r], off);
#pragma unroll
  for (int r = 0; r < 4; r++) l_run[r] = l_run[r] * alpha[r] + lsum[r];
#pragma unroll
  for (int c = 0; c < 4; c++)
#pragma unroll
    for (int r = 0; r < 4; r++) oacc[c][r] *= alpha[r];
  // P (C-layout) -> per-wave LDS, stride 72
#pragma unroll
  for (int n = 0; n < 4; n++)
#pragma unroll
    for (int r = 0; r < 4; r++)
      pw[(quad * 4 + r) * 72 + n * 16 + c16] = f2bf(s[n][r]);
  short8 pf0 = *(const short8*)&pw[c16 * 72 + quad * 8];
  short8 pf1 = *(const short8*)&pw[c16 * 72 + 32 + quad * 8];
#pragma unroll
  for (int c = 0; c < 4; c++) {
    int d = c * 16 + c16;
    short8 vf0 = *(const short8*)&Vt[d * 64 + ((quad * 8) ^ (d & 56))];
    short8 vf1 = *(const short8*)&Vt[d * 64 + ((32 + quad * 8) ^ (d & 56))];
    oacc[c] = __builtin_amdgcn_mfma_f32_16x16x32_bf16(pf0, vf0, oacc[c], 0, 0, 0);
    oacc[c] = __builtin_amdgcn_mfma_f32_16x16x32_bf16(pf1, vf1, oacc[c], 0, 0, 0);
  }
}

// multiply bf16 octet by 0.125 (power of two -> exact)
__device__ __forceinline__ short8 scale8_eighth(short8 v) {
  short8 r;
#pragma unroll
  for (int j = 0; j < 8; j++) {
    unsigned int b = ((unsigned int)(u16)v[j]) << 16;
    float f = __builtin_bit_cast(float, b) * 0.125f;
    r[j] = (short)(u16)(__builtin_bit_cast(unsigned int, f) >> 16);
  }
  return r;
}

// grid (16 pairs, 16 heads, 2 batches), 256 thr; block does q-tiles pr and 31-pr.
// K/V staging double-buffered: global->reg issued before compute, reg->LDS
// committed into the other buffer after compute; ONE barrier per kv-tile.
__global__ __launch_bounds__(256) void attn_mfma2(const u16* __restrict__ qkv0,
                                                  const u16* __restrict__ qkv1,
                                                  u16* __restrict__ aout) {
  int pr = blockIdx.x, h = blockIdx.y;
  const u16* qkvb = blockIdx.z ? qkv1 : qkv0;
  aout += (size_t)blockIdx.z * 2048 * 1024;
  int qt0 = pr, qt1 = 31 - pr;
  int tid = threadIdx.x, lane = tid & 63, w = tid >> 6;
  int quad = lane >> 4, c16 = lane & 15;
  __shared__ __align__(16) u16 Ks[2][64 * 72];
  __shared__ __align__(16) u16 Vt[2][64 * 64];
  __shared__ __align__(16) u16 Ps[4][16 * 72];

  size_t qoffA = (size_t)(qt0 * 64 + w * 16 + c16) * 3072 + h * 64;
  short8 qfA0 = scale8_eighth(*(const short8*)(qkvb + qoffA + quad * 8));
  short8 qfA1 = scale8_eighth(*(const short8*)(qkvb + qoffA + 32 + quad * 8));
  size_t qoffB = (size_t)(qt1 * 64 + w * 16 + c16) * 3072 + h * 64;
  short8 qfB0 = scale8_eighth(*(const short8*)(qkvb + qoffB + quad * 8));
  short8 qfB1 = scale8_eighth(*(const short8*)(qkvb + qoffB + 32 + quad * 8));

  floatx4 zf = {0.f, 0.f, 0.f, 0.f};
  float mA[4], lA[4], mB[4], lB[4];
  floatx4 oA[4], oB[4];
#pragma unroll
  for (int r = 0; r < 4; r++) { mA[r] = -1e30f; lA[r] = 0.f; mB[r] = -1e30f; lB[r] = 0.f; }
#pragma unroll
  for (int c = 0; c < 4; c++) { oA[c] = zf; oB[c] = zf; }

  // staging geometry: thread covers row srow, d [sd8, sd8+16)
  int srow = (tid * 2) >> 3;          // 0..63
  int sd8 = ((tid * 2) & 7) * 8;      // 0,16,32,48
  short8 kr0, kr1, vr0, vr1;

  auto issue = [&](int kt) {
    size_t gb = (size_t)(kt * 64 + srow) * 3072 + h * 64 + sd8;
    kr0 = *(const short8*)(qkvb + gb + 1024);
    kr1 = *(const short8*)(qkvb + gb + 1024 + 8);
    vr0 = *(const short8*)(qkvb + gb + 2048);
    vr1 = *(const short8*)(qkvb + gb + 2048 + 8);
  };
  auto commit = [&](int b) {
    *(short8*)&Ks[b][srow * 72 + sd8] = kr0;
    *(short8*)&Ks[b][srow * 72 + sd8 + 8] = kr1;
    u16* vt = Vt[b];
#pragma unroll
    for (int j = 0; j < 8; j++) {
      int d = sd8 + j;
      vt[d * 64 + (srow ^ (d & 56))] = (u16)vr0[j];
      int d2 = sd8 + 8 + j;
      vt[d2 * 64 + (srow ^ (d2 & 56))] = (u16)vr1[j];
    }
  };

  u16* pw = &Ps[w][0];
  int last = qt1;
  issue(0);
  commit(0);
  __syncthreads();
  int cur = 0;
  for (int kt = 0; kt <= last; ++kt) {
    if (kt < last) issue(kt + 1);

    attn_process(qfB0, qfB1, mB, lB, oB, Ks[cur], Vt[cur], pw, kt, qt1, w, quad, c16, kt == qt1);
    if (kt <= qt0)
      attn_process(qfA0, qfA1, mA, lA, oA, Ks[cur], Vt[cur], pw, kt, qt0, w, quad, c16, kt == qt0);

    if (kt < last) {
      commit(cur ^ 1);   // other buffer: no hazard with waves still computing on cur
      __syncthreads();   // writes visible before next tile's compute
      cur ^= 1;
    }
  }

  size_t obA = (size_t)(qt0 * 64 + w * 16) * 1024 + h * 64;
  size_t obB = (size_t)(qt1 * 64 + w * 16) * 1024 + h * 64;
#pragma unroll
  for (int r = 0; r < 4; r++) {
    float invA = 1.f / lA[r], invB = 1.f / lB[r];
#pragma unroll
    for (int c = 0; c < 4; c++) {
      aout[obA + (size_t)(quad * 4 + r) * 1024 + c * 16 + c16] = f2bf(oA[c][r] * invA);
      aout[obB + (size_t)(quad * 4 + r) * 1024 + c * 16 + c16] = f2bf(oB[c][r] * invB);
    }
  }
}

extern "C" void kernel_launch(void* const* d_in, const int* in_sizes, int n_in,
                              void* d_out, int out_size, void* d_ws, size_t ws_size,
                              hipStream_t stream) {
  const float* x        = (const float*)d_in[0];
  const float* ln1_w    = (const float*)d_in[1];
  const float* ln1_b    = (const float*)d_in[2];
  const float* c_attn_w = (const float*)d_in[3];
  const float* c_attn_b = (const float*)d_in[4];
  const float* c_proj_w = (const float*)d_in[5];
  const float* c_proj_b = (const float*)d_in[6];
  const float* ln2_w    = (const float*)d_in[7];
  const float* ln2_b    = (const float*)d_in[8];
  const float* fc_w     = (const float*)d_in[9];
  const float* fc_b     = (const float*)d_in[10];
  const float* proj_w   = (const float*)d_in[11];
  const float* proj_b   = (const float*)d_in[12];

  char* ws = (char*)d_ws;
  const size_t MiB = 1u << 20;
  const int BIG = 1 << 30;

  // ---- phase 1 (merged batches; peak ws = 28 MiB + qkv0 parked in d_out) ----
  u16* wt_attn  = (u16*)(ws + 0);          // [3072][1024] bf16, 6 MiB
  u16* wt_cproj = (u16*)(ws + 6 * MiB);    // [1024][1024] bf16, 2 MiB
  u16* ln1b     = (u16*)(ws + 8 * MiB);    // [4096][1024] bf16, 8 MiB
  u16* qkv1     = (u16*)(ws + 16 * MiB);   // batch1 [2048][3072] bf16, 12 MiB
  u16* qkv0     = (u16*)d_out;             // batch0 [2048][3072] bf16 in out buf (dead until c_proj)
  u16* attn_out = (u16*)(ws + 8 * MiB);    // [4096][1024] bf16, reuses ln1b slot
  float* x1     = (float*)d_out;           // [4096][1024] fp32; final out in place

  transpose_f32_bf16<<<dim3(96, 32), 256, 0, stream>>>(c_attn_w, wt_attn, 1024, 3072);
  transpose_f32_bf16<<<dim3(32, 32), 256, 0, stream>>>(c_proj_w, wt_cproj, 1024, 1024);
  ln_f32<<<4096, 256, 0, stream>>>(x, ln1_w, ln1_b, ln1b);
  // one merged qkv GEMM, rows >=2048 routed to qkv1
  gemm_bt<0><<<dim3(24, 32), 256, 0, stream>>>(ln1b, wt_attn, c_attn_b, nullptr,
                                               qkv0, qkv1, 2048, 3072, 1024);
  attn_mfma2<<<dim3(16, 16, 2), 256, 0, stream>>>(qkv0, qkv1, attn_out);
  gemm_bt<1><<<dim3(8, 32), 256, 0, stream>>>(attn_out, wt_cproj, c_proj_b, x,
                                              x1, nullptr, BIG, 1024, 1024);

  // ---- phase 2 (chunk count adapts to workspace) ----
  // needs: 16 MiB (wt_fc+ln2b) + 4096*CN*2 (h) + 1024*CN*2 (projT)
  int NC = (ws_size >= 58720256) ? 1 : (ws_size >= 37748736) ? 2 : 4;
  int CN = 4096 / NC;
  u16* wt_fc = (u16*)(ws + 0);                                 // [4096][1024] bf16, 8 MiB
  u16* ln2b  = (u16*)(ws + 8 * MiB);                           // [4096][1024] bf16, 8 MiB
  u16* h_c   = (u16*)(ws + 16 * MiB);                          // [4096][CN] bf16
  u16* projT = (u16*)(ws + 16 * MiB + (size_t)4096 * CN * 2);  // [1024][CN] bf16

  transpose_f32_bf16<<<dim3(128, 32), 256, 0, stream>>>(fc_w, wt_fc, 1024, 4096);
  ln_f32<<<4096, 256, 0, stream>>>(x1, ln2_w, ln2_b, ln2b);
  for (int c = 0; c < NC; c++) {
    transpose_f32_bf16<<<dim3(32, CN / 32), 256, 0, stream>>>(
        proj_w + (size_t)c * CN * 1024, projT, CN, 1024);
    gemm_bt<2><<<dim3(CN / 128, 32), 256, 0, stream>>>(
        ln2b, wt_fc + (size_t)c * CN * 1024, fc_b + c * CN, nullptr,
        h_c, nullptr, BIG, CN, 1024);
    if (NC == 1)
      gemm_bt<1><<<dim3(8, 32), 256, 0, stream>>>(h_c, projT, proj_b, x1,
                                                  x1, nullptr, BIG, 1024, CN);
    else if (c < NC - 1)
      gemm_bt<3><<<dim3(8, 32), 256, 0, stream>>>(h_c, projT, nullptr, nullptr,
                                                  x1, nullptr, BIG, 1024, CN);
    else
      gemm_bt<4><<<dim3(8, 32), 256, 0, stream>>>(h_c, projT, proj_b, nullptr,
                                                  x1, nullptr, BIG, 1024, CN);
  }
}

// Round 9
// 392.767 us; speedup vs baseline: 1.1514x; 1.0171x over previous
//
#include <hip/hip_runtime.h>

typedef unsigned short u16;
typedef __attribute__((ext_vector_type(8))) short short8;
typedef __attribute__((ext_vector_type(4))) float floatx4;

__device__ __forceinline__ float bf2f(u16 u) {
  unsigned int v = ((unsigned int)u) << 16;
  return __builtin_bit_cast(float, v);
}
__device__ __forceinline__ u16 f2bf(float f) {
  unsigned int u = __builtin_bit_cast(unsigned int, f);
  u += 0x7FFFu + ((u >> 16) & 1u);
  return (u16)(u >> 16);
}
__device__ __forceinline__ void gload_lds16(const void* g, void* l) {
  __builtin_amdgcn_global_load_lds(
      (const __attribute__((address_space(1))) unsigned int*)g,
      (__attribute__((address_space(3))) unsigned int*)l, 16, 0, 0);
}

// ---------- transpose+convert: in fp32 [K][N] -> out bf16 [N][K] ----------
__global__ __launch_bounds__(256) void transpose_f32_bf16(const float* __restrict__ in,
                                                          u16* __restrict__ out,
                                                          int K, int N) {
  __shared__ float tile[32][33];
  int n0 = blockIdx.x * 32, k0 = blockIdx.y * 32;
  int tx = threadIdx.x & 31, ty = threadIdx.x >> 5;  // ty 0..7
#pragma unroll
  for (int i = 0; i < 4; i++) {
    int r = ty + i * 8;
    tile[r][tx] = in[(size_t)(k0 + r) * N + n0 + tx];
  }
  __syncthreads();
#pragma unroll
  for (int i = 0; i < 4; i++) {
    int r = ty + i * 8;
    out[(size_t)(n0 + r) * K + k0 + tx] = f2bf(tile[tx][r]);
  }
}

// ---------------- layernorm (Bessel std, eps added to std) -> bf16 ----------------
__global__ __launch_bounds__(256) void ln_f32(const float* __restrict__ xin,
                                              const float* __restrict__ wgt,
                                              const float* __restrict__ bia,
                                              u16* __restrict__ out) {
  int row = blockIdx.x, t = threadIdx.x;
  const float* xr = xin + (size_t)row * 1024 + t * 4;
  float4 f = *(const float4*)xr;
  float v[4] = {f.x, f.y, f.z, f.w};
  float s1 = v[0] + v[1] + v[2] + v[3];
  float s2 = v[0] * v[0] + v[1] * v[1] + v[2] * v[2] + v[3] * v[3];
#pragma unroll
  for (int off = 32; off; off >>= 1) {
    s1 += __shfl_down(s1, off);
    s2 += __shfl_down(s2, off);
  }
  __shared__ float red[8];
  int lane = t & 63, w = t >> 6;
  if (lane == 0) { red[w] = s1; red[4 + w] = s2; }
  __syncthreads();
  s1 = red[0] + red[1] + red[2] + red[3];
  s2 = red[4] + red[5] + red[6] + red[7];
  float mean = s1 * (1.f / 1024.f);
  float var = (s2 - 1024.f * mean * mean) * (1.f / 1023.f);
  var = var < 0.f ? 0.f : var;
  float inv = 1.f / (sqrtf(var) + 1e-5f);
  float4 wv = *(const float4*)(wgt + t * 4);
  float4 bv = *(const float4*)(bia + t * 4);
  float wa[4] = {wv.x, wv.y, wv.z, wv.w};
  float ba[4] = {bv.x, bv.y, bv.z, bv.w};
#pragma unroll
  for (int j = 0; j < 4; j++)
    out[(size_t)row * 1024 + t * 4 + j] = f2bf(wa[j] * ((v[j] - mean) * inv) + ba[j]);
}

// ------- MFMA GEMM, counted-vmcnt dbuf pipeline: C = A @ Bt^T -------
// A bf16 [M][K], Bt bf16 [N][K]. 128x128 tile, BK=64, 256 thr.
// LDS tiles XOR-swizzled (T2): lds[row][col8 ^ (row&7)] via pre-swizzled
// global source (gload_lds writes linearly) + swizzled read column.
// Sync: [stage(t+1)->slot^1][vmcnt(8)][bar][compute(t)<-slot][bar] (T3/T4-lite).
// XCD-chunked block swizzle (T1); requires gridDim.x*gridDim.y % 8 == 0.
// EPI 0: bf16 out (row-split at msplit)  1: f32 = v+res  2: bf16 gelu(v)
// EPI 3: f32 += v (no bias)  4: f32 += v (with bias)
template <int EPI>
__global__ __launch_bounds__(256) void gemm_bt(const u16* __restrict__ A,
                                               const u16* __restrict__ Bt,
                                               const float* __restrict__ bias,
                                               const float* __restrict__ res,
                                               void* __restrict__ outp,
                                               void* __restrict__ outp2,
                                               int msplit,
                                               int ldc, int K) {
  __shared__ __align__(16) u16 As[2][128 * 64];
  __shared__ __align__(16) u16 Bs[2][128 * 64];
  int tid = threadIdx.x;
  int lane = tid & 63, w = tid >> 6;
  int quad = lane >> 4, c16 = lane & 15;
  int wm = w >> 1, wn = w & 1;
  // T1: XCD-chunked bijective swizzle (nwg % 8 == 0 for all launches here)
  int nbx = gridDim.x;
  int nwg = nbx * gridDim.y;
  int bid = blockIdx.y * nbx + blockIdx.x;
  int swz = (bid & 7) * (nwg >> 3) + (bid >> 3);
  int bn = swz % nbx, bm = swz / nbx;
  const u16* Ab = A + (size_t)bm * 128 * K;
  const u16* Bb = Bt + (size_t)bn * 128 * K;

  // staging geometry: lane covers dest row r = j*32 + (tid>>3), 16B slot tid&7.
  // source column pre-swizzled: slot ^ (row&7)  (row&7 == (tid>>3)&7).
  int rbase = tid >> 3;                                  // 0..31
  int csrc = (((tid & 7) ^ ((tid >> 3) & 7))) * 8;       // u16 col offset
  int dbase = w * 512;                                   // u16 dest base per wave

  floatx4 zf = {0.f, 0.f, 0.f, 0.f};
  floatx4 acc[4][4];
#pragma unroll
  for (int i = 0; i < 4; i++)
#pragma unroll
    for (int j = 0; j < 4; j++) acc[i][j] = zf;

  auto stage = [&](int kt, int sl) {
    const u16* At = Ab + kt * 64;
    const u16* Bt2 = Bb + kt * 64;
#pragma unroll
    for (int j = 0; j < 4; j++) {
      int r = j * 32 + rbase;
      gload_lds16(At + (size_t)r * K + csrc, &As[sl][j * 2048 + dbase]);
      gload_lds16(Bt2 + (size_t)r * K + csrc, &Bs[sl][j * 2048 + dbase]);
    }
  };

  int nt = K >> 6;
  stage(0, 0);
  int sl = 0;
  for (int t = 0; t < nt; ++t) {
    if (t + 1 < nt) {
      stage(t + 1, sl ^ 1);
      asm volatile("s_waitcnt vmcnt(8)" ::: "memory");   // tile t landed; t+1 in flight
    } else {
      asm volatile("s_waitcnt vmcnt(0)" ::: "memory");
    }
    __builtin_amdgcn_s_barrier();
    __builtin_amdgcn_sched_barrier(0);
    const u16* as = As[sl];
    const u16* bs = Bs[sl];
#pragma unroll
    for (int ks = 0; ks < 2; ++ks) {
      int col = (ks * 32 + quad * 8) ^ ((c16 & 7) * 8);  // T2 read swizzle
      short8 af[4], bfr[4];
#pragma unroll
      for (int mt = 0; mt < 4; mt++)
        af[mt] = *(const short8*)&as[(wm * 64 + mt * 16 + c16) * 64 + col];
#pragma unroll
      for (int nt2 = 0; nt2 < 4; nt2++)
        bfr[nt2] = *(const short8*)&bs[(wn * 64 + nt2 * 16 + c16) * 64 + col];
#pragma unroll
      for (int mt = 0; mt < 4; mt++)
#pragma unroll
        for (int nt2 = 0; nt2 < 4; nt2++)
          acc[mt][nt2] = __builtin_amdgcn_mfma_f32_16x16x32_bf16(af[mt], bfr[nt2], acc[mt][nt2], 0, 0, 0);
    }
    __builtin_amdgcn_s_barrier();   // WAR: slot overwritten by next stage
    __builtin_amdgcn_sched_barrier(0);
    sl ^= 1;
  }

  int gm0 = bm * 128 + wm * 64;
  int gn0 = bn * 128 + wn * 64;
#pragma unroll
  for (int nt2 = 0; nt2 < 4; nt2++) {
    int gn = gn0 + nt2 * 16 + c16;
    float bia = 0.f;
    if constexpr (EPI != 3) bia = bias[gn];
#pragma unroll
    for (int mt = 0; mt < 4; mt++) {
#pragma unroll
      for (int r = 0; r < 4; r++) {
        int gm = gm0 + mt * 16 + quad * 4 + r;
        float v = acc[mt][nt2][r] + bia;
        if constexpr (EPI == 0) {
          void* op = outp;
          int gmo = gm;
          if (gm >= msplit) { op = outp2; gmo = gm - msplit; }
          ((u16*)op)[(size_t)gmo * ldc + gn] = f2bf(v);
        } else if constexpr (EPI == 1) {
          size_t o = (size_t)gm * ldc + gn;
          ((float*)outp)[o] = v + res[o];
        } else if constexpr (EPI == 2) {
          size_t o = (size_t)gm * ldc + gn;
          float g = 0.5f * v * (1.f + tanhf(0.7978845608f * (v + 0.044715f * v * v * v)));
          ((u16*)outp)[o] = f2bf(g);
        } else {
          size_t o = (size_t)gm * ldc + gn;
          ((float*)outp)[o] += v;
        }
      }
    }
  }
}

// ---------------- flash attention v2: wave-split pair, 64-key tiles ----------------
// Ks stride 72 (pad); Vt [d][key ^ (d&56)] xor-swizzle; P stride 72.
// Q pre-scaled by 0.125 (exact), so QK^T comes out pre-scaled.
__device__ __forceinline__ void attn_process(
    const short8& qf0, const short8& qf1,
    float* m_run, float* l_run, floatx4* oacc,
    const u16* __restrict__ Ks, const u16* __restrict__ Vt, u16* __restrict__ pw,
    int kt, int qt, int wrow, int quad, int c16, bool diag) {
  floatx4 zf = {0.f, 0.f, 0.f, 0.f};
  floatx4 s[4];
#pragma unroll
  for (int n = 0; n < 4; n++) {
    short8 kf0 = *(const short8*)&Ks[(n * 16 + c16) * 72 + quad * 8];
    short8 kf1 = *(const short8*)&Ks[(n * 16 + c16) * 72 + 32 + quad * 8];
    floatx4 a = zf;
    a = __builtin_amdgcn_mfma_f32_16x16x32_bf16(qf0, kf0, a, 0, 0, 0);
    a = __builtin_amdgcn_mfma_f32_16x16x32_bf16(qf1, kf1, a, 0, 0, 0);
    s[n] = a;
  }
  if (diag) {
#pragma unroll
    for (int n = 0; n < 4; n++) {
      int kg = kt * 64 + n * 16 + c16;
#pragma unroll
      for (int r = 0; r < 4; r++) {
        int qg = qt * 64 + wrow * 16 + quad * 4 + r;
        s[n][r] = (kg > qg) ? -1e30f : s[n][r];
      }
    }
  }
  float mt[4];
#pragma unroll
  for (int r = 0; r < 4; r++)
    mt[r] = fmaxf(fmaxf(s[0][r], s[1][r]), fmaxf(s[2][r], s[3][r]));
#pragma unroll
  for (int off = 1; off < 16; off <<= 1)
#pragma unroll
    for (int r = 0; r < 4; r++) mt[r] = fmaxf(mt[r], __shfl_xor(mt[r], off));
  float alpha[4], lsum[4];
#pragma unroll
  for (int r = 0; r < 4; r++) {
    float mn = fmaxf(m_run[r], mt[r]);
    alpha[r] = __expf(m_run[r] - mn);
    m_run[r] = mn;
    lsum[r] = 0.f;
  }
#pragma unroll
  for (int n = 0; n < 4; n++)
#pragma unroll
    for (int r = 0; r < 4; r++) {
      float p = __expf(s[n][r] - m_run[r]);
      s[n][r] = p;
      lsum[r] += p;
    }
#pragma unroll
  for (int off = 1; off < 16; off <<= 1)
#pragma unroll
    for (int r = 0; r < 4; r++) lsum[r] += __shfl_xor(lsum[r], off);
#pragma unroll
  for (int r = 0; r < 4; r++) l_run[r] = l_run[r] * alpha[r] + lsum[r];
#pragma unroll
  for (int c = 0; c < 4; c++)
#pragma unroll
    for (int r = 0; r < 4; r++) oacc[c][r] *= alpha[r];
  // P (C-layout) -> per-wave LDS, stride 72
#pragma unroll
  for (int n = 0; n < 4; n++)
#pragma unroll
    for (int r = 0; r < 4; r++)
      pw[(quad * 4 + r) * 72 + n * 16 + c16] = f2bf(s[n][r]);
  short8 pf0 = *(const short8*)&pw[c16 * 72 + quad * 8];
  short8 pf1 = *(const short8*)&pw[c16 * 72 + 32 + quad * 8];
#pragma unroll
  for (int c = 0; c < 4; c++) {
    int d = c * 16 + c16;
    short8 vf0 = *(const short8*)&Vt[d * 64 + ((quad * 8) ^ (d & 56))];
    short8 vf1 = *(const short8*)&Vt[d * 64 + ((32 + quad * 8) ^ (d & 56))];
    oacc[c] = __builtin_amdgcn_mfma_f32_16x16x32_bf16(pf0, vf0, oacc[c], 0, 0, 0);
    oacc[c] = __builtin_amdgcn_mfma_f32_16x16x32_bf16(pf1, vf1, oacc[c], 0, 0, 0);
  }
}

// multiply bf16 octet by 0.125 (power of two -> exact)
__device__ __forceinline__ short8 scale8_eighth(short8 v) {
  short8 r;
#pragma unroll
  for (int j = 0; j < 8; j++) {
    unsigned int b = ((unsigned int)(u16)v[j]) << 16;
    float f = __builtin_bit_cast(float, b) * 0.125f;
    r[j] = (short)(u16)(__builtin_bit_cast(unsigned int, f) >> 16);
  }
  return r;
}

// grid (16 pairs, 16 heads, 2 batches), 512 thr.
// Waves 0-3 own q-tile qt1=31-pr, waves 4-7 own q-tile qt0=pr; both tiles
// share the K/V staging, and run CONCURRENTLY on different waves.
// K/V staging double-buffered: global->reg before compute, reg->LDS into the
// other buffer after compute; one barrier per kv-tile.
__global__ __launch_bounds__(512) void attn_mfma2(const u16* __restrict__ qkv0,
                                                  const u16* __restrict__ qkv1,
                                                  u16* __restrict__ aout) {
  int pr = blockIdx.x, h = blockIdx.y;
  const u16* qkvb = blockIdx.z ? qkv1 : qkv0;
  aout += (size_t)blockIdx.z * 2048 * 1024;
  int qt0 = pr, qt1 = 31 - pr;
  int tid = threadIdx.x, lane = tid & 63, w = tid >> 6;  // w 0..7
  int quad = lane >> 4, c16 = lane & 15;
  int wrow = w & 3, tb = w >> 2;          // tb 0: tile qt1, 1: tile qt0
  int qt_my = tb ? qt0 : qt1;
  __shared__ __align__(16) u16 Ks[2][64 * 72];
  __shared__ __align__(16) u16 Vt[2][64 * 64];
  __shared__ __align__(16) u16 Ps[8][16 * 72];

  size_t qoff = (size_t)(qt_my * 64 + wrow * 16 + c16) * 3072 + h * 64;
  short8 qf0 = scale8_eighth(*(const short8*)(qkvb + qoff + quad * 8));
  short8 qf1 = scale8_eighth(*(const short8*)(qkvb + qoff + 32 + quad * 8));

  floatx4 zf = {0.f, 0.f, 0.f, 0.f};
  float m[4], l[4];
  floatx4 o[4];
#pragma unroll
  for (int r = 0; r < 4; r++) { m[r] = -1e30f; l[r] = 0.f; }
#pragma unroll
  for (int c = 0; c < 4; c++) o[c] = zf;

  // staging geometry: thread covers row srow (0..63), d [sd8, sd8+8)
  int srow = tid >> 3;
  int sd8 = (tid & 7) * 8;
  short8 kr, vr;

  auto issue = [&](int kt) {
    size_t gb = (size_t)(kt * 64 + srow) * 3072 + h * 64 + sd8;
    kr = *(const short8*)(qkvb + gb + 1024);
    vr = *(const short8*)(qkvb + gb + 2048);
  };
  auto commit = [&](int b) {
    *(short8*)&Ks[b][srow * 72 + sd8] = kr;
    u16* vt = Vt[b];
#pragma unroll
    for (int j = 0; j < 8; j++) {
      int d = sd8 + j;
      vt[d * 64 + (srow ^ (d & 56))] = (u16)vr[j];
    }
  };

  u16* pw = &Ps[w][0];
  issue(0);
  commit(0);
  __syncthreads();
  int cur = 0;
  for (int kt = 0; kt <= qt1; ++kt) {
    if (kt < qt1) issue(kt + 1);

    if (tb == 0 || kt <= qt0)   // wave-uniform branch; barriers stay outside
      attn_process(qf0, qf1, m, l, o, Ks[cur], Vt[cur], pw, kt, qt_my, wrow,
                   quad, c16, kt == qt_my);

    if (kt < qt1) {
      commit(cur ^ 1);   // other buffer: no hazard with waves computing on cur
      __syncthreads();   // writes visible before next tile's compute
      cur ^= 1;
    }
  }

  size_t ob = (size_t)(qt_my * 64 + wrow * 16) * 1024 + h * 64;
#pragma unroll
  for (int r = 0; r < 4; r++) {
    float inv = 1.f / l[r];
#pragma unroll
    for (int c = 0; c < 4; c++)
      aout[ob + (size_t)(quad * 4 + r) * 1024 + c * 16 + c16] = f2bf(o[c][r] * inv);
  }
}

extern "C" void kernel_launch(void* const* d_in, const int* in_sizes, int n_in,
                              void* d_out, int out_size, void* d_ws, size_t ws_size,
                              hipStream_t stream) {
  const float* x        = (const float*)d_in[0];
  const float* ln1_w    = (const float*)d_in[1];
  const float* ln1_b    = (const float*)d_in[2];
  const float* c_attn_w = (const float*)d_in[3];
  const float* c_attn_b = (const float*)d_in[4];
  const float* c_proj_w = (const float*)d_in[5];
  const float* c_proj_b = (const float*)d_in[6];
  const float* ln2_w    = (const float*)d_in[7];
  const float* ln2_b    = (const float*)d_in[8];
  const float* fc_w     = (const float*)d_in[9];
  const float* fc_b     = (const float*)d_in[10];
  const float* proj_w   = (const float*)d_in[11];
  const float* proj_b   = (const float*)d_in[12];

  char* ws = (char*)d_ws;
  const size_t MiB = 1u << 20;
  const int BIG = 1 << 30;

  // ---- phase 1 (merged batches; peak ws = 28 MiB + qkv0 parked in d_out) ----
  u16* wt_attn  = (u16*)(ws + 0);          // [3072][1024] bf16, 6 MiB
  u16* wt_cproj = (u16*)(ws + 6 * MiB);    // [1024][1024] bf16, 2 MiB
  u16* ln1b     = (u16*)(ws + 8 * MiB);    // [4096][1024] bf16, 8 MiB
  u16* qkv1     = (u16*)(ws + 16 * MiB);   // batch1 [2048][3072] bf16, 12 MiB
  u16* qkv0     = (u16*)d_out;             // batch0 [2048][3072] bf16 in out buf (dead until c_proj)
  u16* attn_out = (u16*)(ws + 8 * MiB);    // [4096][1024] bf16, reuses ln1b slot
  float* x1     = (float*)d_out;           // [4096][1024] fp32; final out in place

  transpose_f32_bf16<<<dim3(96, 32), 256, 0, stream>>>(c_attn_w, wt_attn, 1024, 3072);
  transpose_f32_bf16<<<dim3(32, 32), 256, 0, stream>>>(c_proj_w, wt_cproj, 1024, 1024);
  ln_f32<<<4096, 256, 0, stream>>>(x, ln1_w, ln1_b, ln1b);
  // one merged qkv GEMM, rows >=2048 routed to qkv1
  gemm_bt<0><<<dim3(24, 32), 256, 0, stream>>>(ln1b, wt_attn, c_attn_b, nullptr,
                                               qkv0, qkv1, 2048, 3072, 1024);
  attn_mfma2<<<dim3(16, 16, 2), 512, 0, stream>>>(qkv0, qkv1, attn_out);
  gemm_bt<1><<<dim3(8, 32), 256, 0, stream>>>(attn_out, wt_cproj, c_proj_b, x,
                                              x1, nullptr, BIG, 1024, 1024);

  // ---- phase 2 (chunk count adapts to workspace) ----
  // needs: 16 MiB (wt_fc+ln2b) + 4096*CN*2 (h) + 1024*CN*2 (projT)
  int NC = (ws_size >= 58720256) ? 1 : (ws_size >= 37748736) ? 2 : 4;
  int CN = 4096 / NC;
  u16* wt_fc = (u16*)(ws + 0);                                 // [4096][1024] bf16, 8 MiB
  u16* ln2b  = (u16*)(ws + 8 * MiB);                           // [4096][1024] bf16, 8 MiB
  u16* h_c   = (u16*)(ws + 16 * MiB);                          // [4096][CN] bf16
  u16* projT = (u16*)(ws + 16 * MiB + (size_t)4096 * CN * 2);  // [1024][CN] bf16

  transpose_f32_bf16<<<dim3(128, 32), 256, 0, stream>>>(fc_w, wt_fc, 1024, 4096);
  ln_f32<<<4096, 256, 0, stream>>>(x1, ln2_w, ln2_b, ln2b);
  for (int c = 0; c < NC; c++) {
    transpose_f32_bf16<<<dim3(32, CN / 32), 256, 0, stream>>>(
        proj_w + (size_t)c * CN * 1024, projT, CN, 1024);
    gemm_bt<2><<<dim3(CN / 128, 32), 256, 0, stream>>>(
        ln2b, wt_fc + (size_t)c * CN * 1024, fc_b + c * CN, nullptr,
        h_c, nullptr, BIG, CN, 1024);
    if (NC == 1)
      gemm_bt<1><<<dim3(8, 32), 256, 0, stream>>>(h_c, projT, proj_b, x1,
                                                  x1, nullptr, BIG, 1024, CN);
    else if (c < NC - 1)
      gemm_bt<3><<<dim3(8, 32), 256, 0, stream>>>(h_c, projT, nullptr, nullptr,
                                                  x1, nullptr, BIG, 1024, CN);
    else
      gemm_bt<4><<<dim3(8, 32), 256, 0, stream>>>(h_c, projT, proj_b, nullptr,
                                                  x1, nullptr, BIG, 1024, CN);
  }
}

// Round 12
// 386.398 us; speedup vs baseline: 1.1704x; 1.0165x over previous
//
#include <hip/hip_runtime.h>

typedef unsigned short u16;
typedef __attribute__((ext_vector_type(8))) short short8;
typedef __attribute__((ext_vector_type(4))) float floatx4;

__device__ __forceinline__ float bf2f(u16 u) {
  unsigned int v = ((unsigned int)u) << 16;
  return __builtin_bit_cast(float, v);
}
__device__ __forceinline__ u16 f2bf(float f) {
  unsigned int u = __builtin_bit_cast(unsigned int, f);
  u += 0x7FFFu + ((u >> 16) & 1u);
  return (u16)(u >> 16);
}
__device__ __forceinline__ void gload_lds16(const void* g, void* l) {
  __builtin_amdgcn_global_load_lds(
      (const __attribute__((address_space(1))) unsigned int*)g,
      (__attribute__((address_space(3))) unsigned int*)l, 16, 0, 0);
}

// ---------- transpose+convert: in fp32 [K][N] -> out bf16 [N][K] ----------
__global__ __launch_bounds__(256) void transpose_f32_bf16(const float* __restrict__ in,
                                                          u16* __restrict__ out,
                                                          int K, int N) {
  __shared__ float tile[32][33];
  int n0 = blockIdx.x * 32, k0 = blockIdx.y * 32;
  int tx = threadIdx.x & 31, ty = threadIdx.x >> 5;  // ty 0..7
#pragma unroll
  for (int i = 0; i < 4; i++) {
    int r = ty + i * 8;
    tile[r][tx] = in[(size_t)(k0 + r) * N + n0 + tx];
  }
  __syncthreads();
#pragma unroll
  for (int i = 0; i < 4; i++) {
    int r = ty + i * 8;
    out[(size_t)(n0 + r) * K + k0 + tx] = f2bf(tile[tx][r]);
  }
}

// ---------------- layernorm (Bessel std, eps added to std) -> bf16 ----------------
__global__ __launch_bounds__(256) void ln_f32(const float* __restrict__ xin,
                                              const float* __restrict__ wgt,
                                              const float* __restrict__ bia,
                                              u16* __restrict__ out) {
  int row = blockIdx.x, t = threadIdx.x;
  const float* xr = xin + (size_t)row * 1024 + t * 4;
  float4 f = *(const float4*)xr;
  float v[4] = {f.x, f.y, f.z, f.w};
  float s1 = v[0] + v[1] + v[2] + v[3];
  float s2 = v[0] * v[0] + v[1] * v[1] + v[2] * v[2] + v[3] * v[3];
#pragma unroll
  for (int off = 32; off; off >>= 1) {
    s1 += __shfl_down(s1, off);
    s2 += __shfl_down(s2, off);
  }
  __shared__ float red[8];
  int lane = t & 63, w = t >> 6;
  if (lane == 0) { red[w] = s1; red[4 + w] = s2; }
  __syncthreads();
  s1 = red[0] + red[1] + red[2] + red[3];
  s2 = red[4] + red[5] + red[6] + red[7];
  float mean = s1 * (1.f / 1024.f);
  float var = (s2 - 1024.f * mean * mean) * (1.f / 1023.f);
  var = var < 0.f ? 0.f : var;
  float inv = 1.f / (sqrtf(var) + 1e-5f);
  float4 wv = *(const float4*)(wgt + t * 4);
  float4 bv = *(const float4*)(bia + t * 4);
  float wa[4] = {wv.x, wv.y, wv.z, wv.w};
  float ba[4] = {bv.x, bv.y, bv.z, bv.w};
#pragma unroll
  for (int j = 0; j < 4; j++)
    out[(size_t)row * 1024 + t * 4 + j] = f2bf(wa[j] * ((v[j] - mean) * inv) + ba[j]);
}

// ------- MFMA GEMM, counted-vmcnt dbuf pipeline: C = A @ Bt^T -------
// A bf16 [M][K], Bt bf16 [N][K]. 128x128 tile, BK=64, 256 thr.
// LDS tiles XOR-swizzled (T2, measured: bank conflicts 12.6M -> 0).
// Sync: [stage(t+1)->slot^1][vmcnt(8)][bar][compute(t)<-slot][bar].
// T5 setprio(1) around the MFMA nest (2 independent blocks/CU = role split).
// XCD-chunked block swizzle (T1); requires gridDim.x*gridDim.y % 8 == 0.
// EPI 0: bf16 out (row-split at msplit)  1: f32 = v+res  2: bf16 gelu(v)
// EPI 3: f32 += v (no bias)  4: f32 += v (with bias)
template <int EPI>
__global__ __launch_bounds__(256) void gemm_bt(const u16* __restrict__ A,
                                               const u16* __restrict__ Bt,
                                               const float* __restrict__ bias,
                                               const float* __restrict__ res,
                                               void* __restrict__ outp,
                                               void* __restrict__ outp2,
                                               int msplit,
                                               int ldc, int K) {
  __shared__ __align__(16) u16 As[2][128 * 64];
  __shared__ __align__(16) u16 Bs[2][128 * 64];
  int tid = threadIdx.x;
  int lane = tid & 63, w = tid >> 6;
  int quad = lane >> 4, c16 = lane & 15;
  int wm = w >> 1, wn = w & 1;
  // T1: XCD-chunked bijective swizzle (nwg % 8 == 0 for all launches here)
  int nbx = gridDim.x;
  int nwg = nbx * gridDim.y;
  int bid = blockIdx.y * nbx + blockIdx.x;
  int swz = (bid & 7) * (nwg >> 3) + (bid >> 3);
  int bn = swz % nbx, bm = swz / nbx;
  const u16* Ab = A + (size_t)bm * 128 * K;
  const u16* Bb = Bt + (size_t)bn * 128 * K;

  // staging geometry: lane covers dest row r = j*32 + (tid>>3), 16B slot tid&7.
  // source column pre-swizzled: slot ^ (row&7)  (row&7 == (tid>>3)&7).
  int rbase = tid >> 3;                                  // 0..31
  int csrc = (((tid & 7) ^ ((tid >> 3) & 7))) * 8;       // u16 col offset
  int dbase = w * 512;                                   // u16 dest base per wave

  floatx4 zf = {0.f, 0.f, 0.f, 0.f};
  floatx4 acc[4][4];
#pragma unroll
  for (int i = 0; i < 4; i++)
#pragma unroll
    for (int j = 0; j < 4; j++) acc[i][j] = zf;

  auto stage = [&](int kt, int sl) {
    const u16* At = Ab + kt * 64;
    const u16* Bt2 = Bb + kt * 64;
#pragma unroll
    for (int j = 0; j < 4; j++) {
      int r = j * 32 + rbase;
      gload_lds16(At + (size_t)r * K + csrc, &As[sl][j * 2048 + dbase]);
      gload_lds16(Bt2 + (size_t)r * K + csrc, &Bs[sl][j * 2048 + dbase]);
    }
  };

  int nt = K >> 6;
  stage(0, 0);
  int sl = 0;
  for (int t = 0; t < nt; ++t) {
    if (t + 1 < nt) {
      stage(t + 1, sl ^ 1);
      asm volatile("s_waitcnt vmcnt(8)" ::: "memory");   // tile t landed; t+1 in flight
    } else {
      asm volatile("s_waitcnt vmcnt(0)" ::: "memory");
    }
    __builtin_amdgcn_s_barrier();
    __builtin_amdgcn_sched_barrier(0);
    const u16* as = As[sl];
    const u16* bs = Bs[sl];
#pragma unroll
    for (int ks = 0; ks < 2; ++ks) {
      int col = (ks * 32 + quad * 8) ^ ((c16 & 7) * 8);  // T2 read swizzle
      short8 af[4], bfr[4];
#pragma unroll
      for (int mt = 0; mt < 4; mt++)
        af[mt] = *(const short8*)&as[(wm * 64 + mt * 16 + c16) * 64 + col];
#pragma unroll
      for (int nt2 = 0; nt2 < 4; nt2++)
        bfr[nt2] = *(const short8*)&bs[(wn * 64 + nt2 * 16 + c16) * 64 + col];
      __builtin_amdgcn_s_setprio(1);
#pragma unroll
      for (int mt = 0; mt < 4; mt++)
#pragma unroll
        for (int nt2 = 0; nt2 < 4; nt2++)
          acc[mt][nt2] = __builtin_amdgcn_mfma_f32_16x16x32_bf16(af[mt], bfr[nt2], acc[mt][nt2], 0, 0, 0);
      __builtin_amdgcn_s_setprio(0);
    }
    __builtin_amdgcn_s_barrier();   // WAR: slot overwritten by next stage
    __builtin_amdgcn_sched_barrier(0);
    sl ^= 1;
  }

  int gm0 = bm * 128 + wm * 64;
  int gn0 = bn * 128 + wn * 64;
#pragma unroll
  for (int nt2 = 0; nt2 < 4; nt2++) {
    int gn = gn0 + nt2 * 16 + c16;
    float bia = 0.f;
    if constexpr (EPI != 3) bia = bias[gn];
#pragma unroll
    for (int mt = 0; mt < 4; mt++) {
#pragma unroll
      for (int r = 0; r < 4; r++) {
        int gm = gm0 + mt * 16 + quad * 4 + r;
        float v = acc[mt][nt2][r] + bia;
        if constexpr (EPI == 0) {
          void* op = outp;
          int gmo = gm;
          if (gm >= msplit) { op = outp2; gmo = gm - msplit; }
          ((u16*)op)[(size_t)gmo * ldc + gn] = f2bf(v);
        } else if constexpr (EPI == 1) {
          size_t o = (size_t)gm * ldc + gn;
          ((float*)outp)[o] = v + res[o];
        } else if constexpr (EPI == 2) {
          size_t o = (size_t)gm * ldc + gn;
          // gelu: 0.5v(1+tanh(y)) == v*sigmoid(2y); one __expf vs libm tanhf
          float y = 0.7978845608f * (v + 0.044715f * v * v * v);
          float g = v / (1.f + __expf(-2.f * y));
          ((u16*)outp)[o] = f2bf(g);
        } else {
          size_t o = (size_t)gm * ldc + gn;
          ((float*)outp)[o] += v;
        }
      }
    }
  }
}

// ---------------- flash attention v2: wave-split pair, 64-key tiles ----------------
// Ks stride 72 (pad); Vt [d][key ^ (d&56)] xor-swizzle; P stride 72.
// Q pre-scaled by 0.125 (exact), so QK^T comes out pre-scaled.
__device__ __forceinline__ void attn_process(
    const short8& qf0, const short8& qf1,
    float* m_run, float* l_run, floatx4* oacc,
    const u16* __restrict__ Ks, const u16* __restrict__ Vt, u16* __restrict__ pw,
    int kt, int qt, int wrow, int quad, int c16, bool diag) {
  floatx4 zf = {0.f, 0.f, 0.f, 0.f};
  floatx4 s[4];
#pragma unroll
  for (int n = 0; n < 4; n++) {
    short8 kf0 = *(const short8*)&Ks[(n * 16 + c16) * 72 + quad * 8];
    short8 kf1 = *(const short8*)&Ks[(n * 16 + c16) * 72 + 32 + quad * 8];
    floatx4 a = zf;
    a = __builtin_amdgcn_mfma_f32_16x16x32_bf16(qf0, kf0, a, 0, 0, 0);
    a = __builtin_amdgcn_mfma_f32_16x16x32_bf16(qf1, kf1, a, 0, 0, 0);
    s[n] = a;
  }
  if (diag) {
#pragma unroll
    for (int n = 0; n < 4; n++) {
      int kg = kt * 64 + n * 16 + c16;
#pragma unroll
      for (int r = 0; r < 4; r++) {
        int qg = qt * 64 + wrow * 16 + quad * 4 + r;
        s[n][r] = (kg > qg) ? -1e30f : s[n][r];
      }
    }
  }
  float mt[4];
#pragma unroll
  for (int r = 0; r < 4; r++)
    mt[r] = fmaxf(fmaxf(s[0][r], s[1][r]), fmaxf(s[2][r], s[3][r]));
#pragma unroll
  for (int off = 1; off < 16; off <<= 1)
#pragma unroll
    for (int r = 0; r < 4; r++) mt[r] = fmaxf(mt[r], __shfl_xor(mt[r], off));
  float alpha[4], lsum[4];
#pragma unroll
  for (int r = 0; r < 4; r++) {
    float mn = fmaxf(m_run[r], mt[r]);
    alpha[r] = __expf(m_run[r] - mn);
    m_run[r] = mn;
    lsum[r] = 0.f;
  }
#pragma unroll
  for (int n = 0; n < 4; n++)
#pragma unroll
    for (int r = 0; r < 4; r++) {
      float p = __expf(s[n][r] - m_run[r]);
      s[n][r] = p;
      lsum[r] += p;
    }
#pragma unroll
  for (int off = 1; off < 16; off <<= 1)
#pragma unroll
    for (int r = 0; r < 4; r++) lsum[r] += __shfl_xor(lsum[r], off);
#pragma unroll
  for (int r = 0; r < 4; r++) l_run[r] = l_run[r] * alpha[r] + lsum[r];
#pragma unroll
  for (int c = 0; c < 4; c++)
#pragma unroll
    for (int r = 0; r < 4; r++) oacc[c][r] *= alpha[r];
  // P (C-layout) -> per-wave LDS, stride 72
#pragma unroll
  for (int n = 0; n < 4; n++)
#pragma unroll
    for (int r = 0; r < 4; r++)
      pw[(quad * 4 + r) * 72 + n * 16 + c16] = f2bf(s[n][r]);
  short8 pf0 = *(const short8*)&pw[c16 * 72 + quad * 8];
  short8 pf1 = *(const short8*)&pw[c16 * 72 + 32 + quad * 8];
#pragma unroll
  for (int c = 0; c < 4; c++) {
    int d = c * 16 + c16;
    short8 vf0 = *(const short8*)&Vt[d * 64 + ((quad * 8) ^ (d & 56))];
    short8 vf1 = *(const short8*)&Vt[d * 64 + ((32 + quad * 8) ^ (d & 56))];
    oacc[c] = __builtin_amdgcn_mfma_f32_16x16x32_bf16(pf0, vf0, oacc[c], 0, 0, 0);
    oacc[c] = __builtin_amdgcn_mfma_f32_16x16x32_bf16(pf1, vf1, oacc[c], 0, 0, 0);
  }
}

// multiply bf16 octet by 0.125 (power of two -> exact)
__device__ __forceinline__ short8 scale8_eighth(short8 v) {
  short8 r;
#pragma unroll
  for (int j = 0; j < 8; j++) {
    unsigned int b = ((unsigned int)(u16)v[j]) << 16;
    float f = __builtin_bit_cast(float, b) * 0.125f;
    r[j] = (short)(u16)(__builtin_bit_cast(unsigned int, f) >> 16);
  }
  return r;
}

// grid (16 pairs, 16 heads, 2 batches), 512 thr.
// Waves 0-3 own q-tile qt1=31-pr, waves 4-7 own q-tile qt0=pr; both tiles
// share the K/V staging, and run CONCURRENTLY on different waves.
__global__ __launch_bounds__(512) void attn_mfma2(const u16* __restrict__ qkv0,
                                                  const u16* __restrict__ qkv1,
                                                  u16* __restrict__ aout) {
  int pr = blockIdx.x, h = blockIdx.y;
  const u16* qkvb = blockIdx.z ? qkv1 : qkv0;
  aout += (size_t)blockIdx.z * 2048 * 1024;
  int qt0 = pr, qt1 = 31 - pr;
  int tid = threadIdx.x, lane = tid & 63, w = tid >> 6;  // w 0..7
  int quad = lane >> 4, c16 = lane & 15;
  int wrow = w & 3, tb = w >> 2;          // tb 0: tile qt1, 1: tile qt0
  int qt_my = tb ? qt0 : qt1;
  __shared__ __align__(16) u16 Ks[2][64 * 72];
  __shared__ __align__(16) u16 Vt[2][64 * 64];
  __shared__ __align__(16) u16 Ps[8][16 * 72];

  size_t qoff = (size_t)(qt_my * 64 + wrow * 16 + c16) * 3072 + h * 64;
  short8 qf0 = scale8_eighth(*(const short8*)(qkvb + qoff + quad * 8));
  short8 qf1 = scale8_eighth(*(const short8*)(qkvb + qoff + 32 + quad * 8));

  floatx4 zf = {0.f, 0.f, 0.f, 0.f};
  float m[4], l[4];
  floatx4 o[4];
#pragma unroll
  for (int r = 0; r < 4; r++) { m[r] = -1e30f; l[r] = 0.f; }
#pragma unroll
  for (int c = 0; c < 4; c++) o[c] = zf;

  // staging geometry: thread covers row srow (0..63), d [sd8, sd8+8)
  int srow = tid >> 3;
  int sd8 = (tid & 7) * 8;
  short8 kr, vr;

  auto issue = [&](int kt) {
    size_t gb = (size_t)(kt * 64 + srow) * 3072 + h * 64 + sd8;
    kr = *(const short8*)(qkvb + gb + 1024);
    vr = *(const short8*)(qkvb + gb + 2048);
  };
  auto commit = [&](int b) {
    *(short8*)&Ks[b][srow * 72 + sd8] = kr;
    u16* vt = Vt[b];
#pragma unroll
    for (int j = 0; j < 8; j++) {
      int d = sd8 + j;
      vt[d * 64 + (srow ^ (d & 56))] = (u16)vr[j];
    }
  };

  u16* pw = &Ps[w][0];
  issue(0);
  commit(0);
  __syncthreads();
  int cur = 0;
  for (int kt = 0; kt <= qt1; ++kt) {
    if (kt < qt1) issue(kt + 1);

    if (tb == 0 || kt <= qt0)   // wave-uniform branch; barriers stay outside
      attn_process(qf0, qf1, m, l, o, Ks[cur], Vt[cur], pw, kt, qt_my, wrow,
                   quad, c16, kt == qt_my);

    if (kt < qt1) {
      commit(cur ^ 1);   // other buffer: no hazard with waves computing on cur
      __syncthreads();   // writes visible before next tile's compute
      cur ^= 1;
    }
  }

  size_t ob = (size_t)(qt_my * 64 + wrow * 16) * 1024 + h * 64;
#pragma unroll
  for (int r = 0; r < 4; r++) {
    float inv = 1.f / l[r];
#pragma unroll
    for (int c = 0; c < 4; c++)
      aout[ob + (size_t)(quad * 4 + r) * 1024 + c * 16 + c16] = f2bf(o[c][r] * inv);
  }
}

extern "C" void kernel_launch(void* const* d_in, const int* in_sizes, int n_in,
                              void* d_out, int out_size, void* d_ws, size_t ws_size,
                              hipStream_t stream) {
  const float* x        = (const float*)d_in[0];
  const float* ln1_w    = (const float*)d_in[1];
  const float* ln1_b    = (const float*)d_in[2];
  const float* c_attn_w = (const float*)d_in[3];
  const float* c_attn_b = (const float*)d_in[4];
  const float* c_proj_w = (const float*)d_in[5];
  const float* c_proj_b = (const float*)d_in[6];
  const float* ln2_w    = (const float*)d_in[7];
  const float* ln2_b    = (const float*)d_in[8];
  const float* fc_w     = (const float*)d_in[9];
  const float* fc_b     = (const float*)d_in[10];
  const float* proj_w   = (const float*)d_in[11];
  const float* proj_b   = (const float*)d_in[12];

  char* ws = (char*)d_ws;
  const size_t MiB = 1u << 20;
  const int BIG = 1 << 30;

  // ---- phase 1 (merged batches; peak ws = 28 MiB + qkv0 parked in d_out) ----
  u16* wt_attn  = (u16*)(ws + 0);          // [3072][1024] bf16, 6 MiB
  u16* wt_cproj = (u16*)(ws + 6 * MiB);    // [1024][1024] bf16, 2 MiB
  u16* ln1b     = (u16*)(ws + 8 * MiB);    // [4096][1024] bf16, 8 MiB
  u16* qkv1     = (u16*)(ws + 16 * MiB);   // batch1 [2048][3072] bf16, 12 MiB
  u16* qkv0     = (u16*)d_out;             // batch0 [2048][3072] bf16 in out buf (dead until c_proj)
  u16* attn_out = (u16*)(ws + 8 * MiB);    // [4096][1024] bf16, reuses ln1b slot
  float* x1     = (float*)d_out;           // [4096][1024] fp32; final out in place

  transpose_f32_bf16<<<dim3(96, 32), 256, 0, stream>>>(c_attn_w, wt_attn, 1024, 3072);
  transpose_f32_bf16<<<dim3(32, 32), 256, 0, stream>>>(c_proj_w, wt_cproj, 1024, 1024);
  ln_f32<<<4096, 256, 0, stream>>>(x, ln1_w, ln1_b, ln1b);
  // one merged qkv GEMM, rows >=2048 routed to qkv1
  gemm_bt<0><<<dim3(24, 32), 256, 0, stream>>>(ln1b, wt_attn, c_attn_b, nullptr,
                                               qkv0, qkv1, 2048, 3072, 1024);
  attn_mfma2<<<dim3(16, 16, 2), 512, 0, stream>>>(qkv0, qkv1, attn_out);
  gemm_bt<1><<<dim3(8, 32), 256, 0, stream>>>(attn_out, wt_cproj, c_proj_b, x,
                                              x1, nullptr, BIG, 1024, 1024);

  // ---- phase 2 (chunk count adapts to workspace) ----
  // needs: 16 MiB (wt_fc+ln2b) + 4096*CN*2 (h) + 1024*CN*2 (projT)
  int NC = (ws_size >= 58720256) ? 1 : (ws_size >= 37748736) ? 2 : 4;
  int CN = 4096 / NC;
  u16* wt_fc = (u16*)(ws + 0);                                 // [4096][1024] bf16, 8 MiB
  u16* ln2b  = (u16*)(ws + 8 * MiB);                           // [4096][1024] bf16, 8 MiB
  u16* h_c   = (u16*)(ws + 16 * MiB);                          // [4096][CN] bf16
  u16* projT = (u16*)(ws + 16 * MiB + (size_t)4096 * CN * 2);  // [1024][CN] bf16

  transpose_f32_bf16<<<dim3(128, 32), 256, 0, stream>>>(fc_w, wt_fc, 1024, 4096);
  ln_f32<<<4096, 256, 0, stream>>>(x1, ln2_w, ln2_b, ln2b);
  for (int c = 0; c < NC; c++) {
    transpose_f32_bf16<<<dim3(32, CN / 32), 256, 0, stream>>>(
        proj_w + (size_t)c * CN * 1024, projT, CN, 1024);
    gemm_bt<2><<<dim3(CN / 128, 32), 256, 0, stream>>>(
        ln2b, wt_fc + (size_t)c * CN * 1024, fc_b + c * CN, nullptr,
        h_c, nullptr, BIG, CN, 1024);
    if (NC == 1)
      gemm_bt<1><<<dim3(8, 32), 256, 0, stream>>>(h_c, projT, proj_b, x1,
                                                  x1, nullptr, BIG, 1024, CN);
    else if (c < NC - 1)
      gemm_bt<3><<<dim3(8, 32), 256, 0, stream>>>(h_c, projT, nullptr, nullptr,
                                                  x1, nullptr, BIG, 1024, CN);
    else
      gemm_bt<4><<<dim3(8, 32), 256, 0, stream>>>(h_c, projT, proj_b, nullptr,
                                                  x1, nullptr, BIG, 1024, CN);
  }
}

// Round 13
// 377.749 us; speedup vs baseline: 1.1972x; 1.0229x over previous
//
#include <hip/hip_runtime.h>

typedef unsigned short u16;
typedef __attribute__((ext_vector_type(8))) short short8;
typedef __attribute__((ext_vector_type(4))) float floatx4;

__device__ __forceinline__ float bf2f(u16 u) {
  unsigned int v = ((unsigned int)u) << 16;
  return __builtin_bit_cast(float, v);
}
__device__ __forceinline__ u16 f2bf(float f) {
  unsigned int u = __builtin_bit_cast(unsigned int, f);
  u += 0x7FFFu + ((u >> 16) & 1u);
  return (u16)(u >> 16);
}
__device__ __forceinline__ void gload_lds16(const void* g, void* l) {
  __builtin_amdgcn_global_load_lds(
      (const __attribute__((address_space(1))) unsigned int*)g,
      (__attribute__((address_space(3))) unsigned int*)l, 16, 0, 0);
}

// ---------- transpose+convert: in fp32 [K][N] -> out bf16 [N][K] ----------
__global__ __launch_bounds__(256) void transpose_f32_bf16(const float* __restrict__ in,
                                                          u16* __restrict__ out,
                                                          int K, int N) {
  __shared__ float tile[32][33];
  int n0 = blockIdx.x * 32, k0 = blockIdx.y * 32;
  int tx = threadIdx.x & 31, ty = threadIdx.x >> 5;  // ty 0..7
#pragma unroll
  for (int i = 0; i < 4; i++) {
    int r = ty + i * 8;
    tile[r][tx] = in[(size_t)(k0 + r) * N + n0 + tx];
  }
  __syncthreads();
#pragma unroll
  for (int i = 0; i < 4; i++) {
    int r = ty + i * 8;
    out[(size_t)(n0 + r) * K + k0 + tx] = f2bf(tile[tx][r]);
  }
}

// ---------------- layernorm (Bessel std, eps added to std) -> bf16 ----------------
__global__ __launch_bounds__(256) void ln_f32(const float* __restrict__ xin,
                                              const float* __restrict__ wgt,
                                              const float* __restrict__ bia,
                                              u16* __restrict__ out) {
  int row = blockIdx.x, t = threadIdx.x;
  const float* xr = xin + (size_t)row * 1024 + t * 4;
  float4 f = *(const float4*)xr;
  float v[4] = {f.x, f.y, f.z, f.w};
  float s1 = v[0] + v[1] + v[2] + v[3];
  float s2 = v[0] * v[0] + v[1] * v[1] + v[2] * v[2] + v[3] * v[3];
#pragma unroll
  for (int off = 32; off; off >>= 1) {
    s1 += __shfl_down(s1, off);
    s2 += __shfl_down(s2, off);
  }
  __shared__ float red[8];
  int lane = t & 63, w = t >> 6;
  if (lane == 0) { red[w] = s1; red[4 + w] = s2; }
  __syncthreads();
  s1 = red[0] + red[1] + red[2] + red[3];
  s2 = red[4] + red[5] + red[6] + red[7];
  float mean = s1 * (1.f / 1024.f);
  float var = (s2 - 1024.f * mean * mean) * (1.f / 1023.f);
  var = var < 0.f ? 0.f : var;
  float inv = 1.f / (sqrtf(var) + 1e-5f);
  float4 wv = *(const float4*)(wgt + t * 4);
  float4 bv = *(const float4*)(bia + t * 4);
  float wa[4] = {wv.x, wv.y, wv.z, wv.w};
  float ba[4] = {bv.x, bv.y, bv.z, bv.w};
#pragma unroll
  for (int j = 0; j < 4; j++)
    out[(size_t)row * 1024 + t * 4 + j] = f2bf(wa[j] * ((v[j] - mean) * inv) + ba[j]);
}

// ------- MFMA GEMM, counted-vmcnt dbuf pipeline: C = A @ Bt^T -------
// A bf16 [M][K], Bt bf16 [N][K]. 128x128 tile, BK=64, 256 thr.
// LDS tiles XOR-swizzled (T2, measured: bank conflicts 12.6M -> 0).
// Sync: [stage(t+1)->slot^1][vmcnt(8)][bar][compute(t)<-slot][bar].
// (T5 setprio removed: measured ~20us aggregate regression in lockstep loop, m190-consistent.)
// XCD-chunked block swizzle (T1); requires gridDim.x*gridDim.y % 8 == 0.
// EPI 0: bf16 out (row-split at msplit)  1: f32 = v+res  2: bf16 gelu(v)
// EPI 3: f32 += v (no bias)  4: f32 += v (with bias)
template <int EPI>
__global__ __launch_bounds__(256) void gemm_bt(const u16* __restrict__ A,
                                               const u16* __restrict__ Bt,
                                               const float* __restrict__ bias,
                                               const float* __restrict__ res,
                                               void* __restrict__ outp,
                                               void* __restrict__ outp2,
                                               int msplit,
                                               int ldc, int K) {
  __shared__ __align__(16) u16 As[2][128 * 64];
  __shared__ __align__(16) u16 Bs[2][128 * 64];
  int tid = threadIdx.x;
  int lane = tid & 63, w = tid >> 6;
  int quad = lane >> 4, c16 = lane & 15;
  int wm = w >> 1, wn = w & 1;
  // T1: XCD-chunked bijective swizzle (nwg % 8 == 0 for all launches here)
  int nbx = gridDim.x;
  int nwg = nbx * gridDim.y;
  int bid = blockIdx.y * nbx + blockIdx.x;
  int swz = (bid & 7) * (nwg >> 3) + (bid >> 3);
  int bn = swz % nbx, bm = swz / nbx;
  const u16* Ab = A + (size_t)bm * 128 * K;
  const u16* Bb = Bt + (size_t)bn * 128 * K;

  // staging geometry: lane covers dest row r = j*32 + (tid>>3), 16B slot tid&7.
  // source column pre-swizzled: slot ^ (row&7)  (row&7 == (tid>>3)&7).
  int rbase = tid >> 3;                                  // 0..31
  int csrc = (((tid & 7) ^ ((tid >> 3) & 7))) * 8;       // u16 col offset
  int dbase = w * 512;                                   // u16 dest base per wave

  floatx4 zf = {0.f, 0.f, 0.f, 0.f};
  floatx4 acc[4][4];
#pragma unroll
  for (int i = 0; i < 4; i++)
#pragma unroll
    for (int j = 0; j < 4; j++) acc[i][j] = zf;

  auto stage = [&](int kt, int sl) {
    const u16* At = Ab + kt * 64;
    const u16* Bt2 = Bb + kt * 64;
#pragma unroll
    for (int j = 0; j < 4; j++) {
      int r = j * 32 + rbase;
      gload_lds16(At + (size_t)r * K + csrc, &As[sl][j * 2048 + dbase]);
      gload_lds16(Bt2 + (size_t)r * K + csrc, &Bs[sl][j * 2048 + dbase]);
    }
  };

  int nt = K >> 6;
  stage(0, 0);
  int sl = 0;
  for (int t = 0; t < nt; ++t) {
    if (t + 1 < nt) {
      stage(t + 1, sl ^ 1);
      asm volatile("s_waitcnt vmcnt(8)" ::: "memory");   // tile t landed; t+1 in flight
    } else {
      asm volatile("s_waitcnt vmcnt(0)" ::: "memory");
    }
    __builtin_amdgcn_s_barrier();
    __builtin_amdgcn_sched_barrier(0);
    const u16* as = As[sl];
    const u16* bs = Bs[sl];
#pragma unroll
    for (int ks = 0; ks < 2; ++ks) {
      int col = (ks * 32 + quad * 8) ^ ((c16 & 7) * 8);  // T2 read swizzle
      short8 af[4], bfr[4];
#pragma unroll
      for (int mt = 0; mt < 4; mt++)
        af[mt] = *(const short8*)&as[(wm * 64 + mt * 16 + c16) * 64 + col];
#pragma unroll
      for (int nt2 = 0; nt2 < 4; nt2++)
        bfr[nt2] = *(const short8*)&bs[(wn * 64 + nt2 * 16 + c16) * 64 + col];
#pragma unroll
      for (int mt = 0; mt < 4; mt++)
#pragma unroll
        for (int nt2 = 0; nt2 < 4; nt2++)
          acc[mt][nt2] = __builtin_amdgcn_mfma_f32_16x16x32_bf16(af[mt], bfr[nt2], acc[mt][nt2], 0, 0, 0);
    }
    __builtin_amdgcn_s_barrier();   // WAR: slot overwritten by next stage
    __builtin_amdgcn_sched_barrier(0);
    sl ^= 1;
  }

  int gm0 = bm * 128 + wm * 64;
  int gn0 = bn * 128 + wn * 64;
#pragma unroll
  for (int nt2 = 0; nt2 < 4; nt2++) {
    int gn = gn0 + nt2 * 16 + c16;
    float bia = 0.f;
    if constexpr (EPI != 3) bia = bias[gn];
#pragma unroll
    for (int mt = 0; mt < 4; mt++) {
#pragma unroll
      for (int r = 0; r < 4; r++) {
        int gm = gm0 + mt * 16 + quad * 4 + r;
        float v = acc[mt][nt2][r] + bia;
        if constexpr (EPI == 0) {
          void* op = outp;
          int gmo = gm;
          if (gm >= msplit) { op = outp2; gmo = gm - msplit; }
          ((u16*)op)[(size_t)gmo * ldc + gn] = f2bf(v);
        } else if constexpr (EPI == 1) {
          size_t o = (size_t)gm * ldc + gn;
          ((float*)outp)[o] = v + res[o];
        } else if constexpr (EPI == 2) {
          size_t o = (size_t)gm * ldc + gn;
          // gelu: 0.5v(1+tanh(y)) == v*sigmoid(2y); one __expf vs libm tanhf
          float y = 0.7978845608f * (v + 0.044715f * v * v * v);
          float g = v / (1.f + __expf(-2.f * y));
          ((u16*)outp)[o] = f2bf(g);
        } else {
          size_t o = (size_t)gm * ldc + gn;
          ((float*)outp)[o] += v;
        }
      }
    }
  }
}

// ---------------- flash attention v2: wave-split pair, 64-key tiles ----------------
// Ks stride 72 (pad); Vt [d][key ^ (d&56) ^ ((d&7)<<3)] full xor-swizzle
// (low-d bits added so a wave's 64 b128 V-reads tile all 8 bank groups
// uniformly; old (d&56)-only key hit 4 of 8 groups = 2x serialization,
// measured as ~68 extra LDS cycles per process call). P stride 72.
// Q pre-scaled by 0.125 (exact), so QK^T comes out pre-scaled.
__device__ __forceinline__ void attn_process(
    const short8& qf0, const short8& qf1,
    float* m_run, float* l_run, floatx4* oacc,
    const u16* __restrict__ Ks, const u16* __restrict__ Vt, u16* __restrict__ pw,
    int kt, int qt, int wrow, int quad, int c16, bool diag) {
  floatx4 zf = {0.f, 0.f, 0.f, 0.f};
  floatx4 s[4];
#pragma unroll
  for (int n = 0; n < 4; n++) {
    short8 kf0 = *(const short8*)&Ks[(n * 16 + c16) * 72 + quad * 8];
    short8 kf1 = *(const short8*)&Ks[(n * 16 + c16) * 72 + 32 + quad * 8];
    floatx4 a = zf;
    a = __builtin_amdgcn_mfma_f32_16x16x32_bf16(qf0, kf0, a, 0, 0, 0);
    a = __builtin_amdgcn_mfma_f32_16x16x32_bf16(qf1, kf1, a, 0, 0, 0);
    s[n] = a;
  }
  if (diag) {
#pragma unroll
    for (int n = 0; n < 4; n++) {
      int kg = kt * 64 + n * 16 + c16;
#pragma unroll
      for (int r = 0; r < 4; r++) {
        int qg = qt * 64 + wrow * 16 + quad * 4 + r;
        s[n][r] = (kg > qg) ? -1e30f : s[n][r];
      }
    }
  }
  float mt[4];
#pragma unroll
  for (int r = 0; r < 4; r++)
    mt[r] = fmaxf(fmaxf(s[0][r], s[1][r]), fmaxf(s[2][r], s[3][r]));
#pragma unroll
  for (int off = 1; off < 16; off <<= 1)
#pragma unroll
    for (int r = 0; r < 4; r++) mt[r] = fmaxf(mt[r], __shfl_xor(mt[r], off));
  float alpha[4], lsum[4];
#pragma unroll
  for (int r = 0; r < 4; r++) {
    float mn = fmaxf(m_run[r], mt[r]);
    alpha[r] = __expf(m_run[r] - mn);
    m_run[r] = mn;
    lsum[r] = 0.f;
  }
#pragma unroll
  for (int n = 0; n < 4; n++)
#pragma unroll
    for (int r = 0; r < 4; r++) {
      float p = __expf(s[n][r] - m_run[r]);
      s[n][r] = p;
      lsum[r] += p;
    }
#pragma unroll
  for (int off = 1; off < 16; off <<= 1)
#pragma unroll
    for (int r = 0; r < 4; r++) lsum[r] += __shfl_xor(lsum[r], off);
#pragma unroll
  for (int r = 0; r < 4; r++) l_run[r] = l_run[r] * alpha[r] + lsum[r];
#pragma unroll
  for (int c = 0; c < 4; c++)
#pragma unroll
    for (int r = 0; r < 4; r++) oacc[c][r] *= alpha[r];
  // P (C-layout) -> per-wave LDS, stride 72
#pragma unroll
  for (int n = 0; n < 4; n++)
#pragma unroll
    for (int r = 0; r < 4; r++)
      pw[(quad * 4 + r) * 72 + n * 16 + c16] = f2bf(s[n][r]);
  short8 pf0 = *(const short8*)&pw[c16 * 72 + quad * 8];
  short8 pf1 = *(const short8*)&pw[c16 * 72 + 32 + quad * 8];
#pragma unroll
  for (int c = 0; c < 4; c++) {
    int d = c * 16 + c16;
    int cd = (d & 56) ^ ((d & 7) << 3);
    short8 vf0 = *(const short8*)&Vt[d * 64 + ((quad * 8) ^ cd)];
    short8 vf1 = *(const short8*)&Vt[d * 64 + ((32 + quad * 8) ^ cd)];
    oacc[c] = __builtin_amdgcn_mfma_f32_16x16x32_bf16(pf0, vf0, oacc[c], 0, 0, 0);
    oacc[c] = __builtin_amdgcn_mfma_f32_16x16x32_bf16(pf1, vf1, oacc[c], 0, 0, 0);
  }
}

// multiply bf16 octet by 0.125 (power of two -> exact)
__device__ __forceinline__ short8 scale8_eighth(short8 v) {
  short8 r;
#pragma unroll
  for (int j = 0; j < 8; j++) {
    unsigned int b = ((unsigned int)(u16)v[j]) << 16;
    float f = __builtin_bit_cast(float, b) * 0.125f;
    r[j] = (short)(u16)(__builtin_bit_cast(unsigned int, f) >> 16);
  }
  return r;
}

// grid (16 pairs, 16 heads, 2 batches), 512 thr.
// Waves 0-3 own q-tile qt1=31-pr, waves 4-7 own q-tile qt0=pr; both tiles
// share the K/V staging, and run CONCURRENTLY on different waves.
__global__ __launch_bounds__(512) void attn_mfma2(const u16* __restrict__ qkv0,
                                                  const u16* __restrict__ qkv1,
                                                  u16* __restrict__ aout) {
  int pr = blockIdx.x, h = blockIdx.y;
  const u16* qkvb = blockIdx.z ? qkv1 : qkv0;
  aout += (size_t)blockIdx.z * 2048 * 1024;
  int qt0 = pr, qt1 = 31 - pr;
  int tid = threadIdx.x, lane = tid & 63, w = tid >> 6;  // w 0..7
  int quad = lane >> 4, c16 = lane & 15;
  int wrow = w & 3, tb = w >> 2;          // tb 0: tile qt1, 1: tile qt0
  int qt_my = tb ? qt0 : qt1;
  __shared__ __align__(16) u16 Ks[2][64 * 72];
  __shared__ __align__(16) u16 Vt[2][64 * 64];
  __shared__ __align__(16) u16 Ps[8][16 * 72];

  size_t qoff = (size_t)(qt_my * 64 + wrow * 16 + c16) * 3072 + h * 64;
  short8 qf0 = scale8_eighth(*(const short8*)(qkvb + qoff + quad * 8));
  short8 qf1 = scale8_eighth(*(const short8*)(qkvb + qoff + 32 + quad * 8));

  floatx4 zf = {0.f, 0.f, 0.f, 0.f};
  float m[4], l[4];
  floatx4 o[4];
#pragma unroll
  for (int r = 0; r < 4; r++) { m[r] = -1e30f; l[r] = 0.f; }
#pragma unroll
  for (int c = 0; c < 4; c++) o[c] = zf;

  // staging geometry: thread covers row srow (0..63), d [sd8, sd8+8)
  int srow = tid >> 3;
  int sd8 = (tid & 7) * 8;
  short8 kr, vr;

  auto issue = [&](int kt) {
    size_t gb = (size_t)(kt * 64 + srow) * 3072 + h * 64 + sd8;
    kr = *(const short8*)(qkvb + gb + 1024);
    vr = *(const short8*)(qkvb + gb + 2048);
  };
  auto commit = [&](int b) {
    *(short8*)&Ks[b][srow * 72 + sd8] = kr;
    u16* vt = Vt[b];
#pragma unroll
    for (int j = 0; j < 8; j++) {
      int d = sd8 + j;
      vt[d * 64 + (srow ^ (d & 56) ^ ((d & 7) << 3))] = (u16)vr[j];
    }
  };

  u16* pw = &Ps[w][0];
  issue(0);
  commit(0);
  __syncthreads();
  int cur = 0;
  for (int kt = 0; kt <= qt1; ++kt) {
    if (kt < qt1) issue(kt + 1);

    if (tb == 0 || kt <= qt0)   // wave-uniform branch; barriers stay outside
      attn_process(qf0, qf1, m, l, o, Ks[cur], Vt[cur], pw, kt, qt_my, wrow,
                   quad, c16, kt == qt_my);

    if (kt < qt1) {
      commit(cur ^ 1);   // other buffer: no hazard with waves computing on cur
      __syncthreads();   // writes visible before next tile's compute
      cur ^= 1;
    }
  }

  size_t ob = (size_t)(qt_my * 64 + wrow * 16) * 1024 + h * 64;
#pragma unroll
  for (int r = 0; r < 4; r++) {
    float inv = 1.f / l[r];
#pragma unroll
    for (int c = 0; c < 4; c++)
      aout[ob + (size_t)(quad * 4 + r) * 1024 + c * 16 + c16] = f2bf(o[c][r] * inv);
  }
}

extern "C" void kernel_launch(void* const* d_in, const int* in_sizes, int n_in,
                              void* d_out, int out_size, void* d_ws, size_t ws_size,
                              hipStream_t stream) {
  const float* x        = (const float*)d_in[0];
  const float* ln1_w    = (const float*)d_in[1];
  const float* ln1_b    = (const float*)d_in[2];
  const float* c_attn_w = (const float*)d_in[3];
  const float* c_attn_b = (const float*)d_in[4];
  const float* c_proj_w = (const float*)d_in[5];
  const float* c_proj_b = (const float*)d_in[6];
  const float* ln2_w    = (const float*)d_in[7];
  const float* ln2_b    = (const float*)d_in[8];
  const float* fc_w     = (const float*)d_in[9];
  const float* fc_b     = (const float*)d_in[10];
  const float* proj_w   = (const float*)d_in[11];
  const float* proj_b   = (const float*)d_in[12];

  char* ws = (char*)d_ws;
  const size_t MiB = 1u << 20;
  const int BIG = 1 << 30;

  // ---- phase 1 (merged batches; peak ws = 28 MiB + qkv0 parked in d_out) ----
  u16* wt_attn  = (u16*)(ws + 0);          // [3072][1024] bf16, 6 MiB
  u16* wt_cproj = (u16*)(ws + 6 * MiB);    // [1024][1024] bf16, 2 MiB
  u16* ln1b     = (u16*)(ws + 8 * MiB);    // [4096][1024] bf16, 8 MiB
  u16* qkv1     = (u16*)(ws + 16 * MiB);   // batch1 [2048][3072] bf16, 12 MiB
  u16* qkv0     = (u16*)d_out;             // batch0 [2048][3072] bf16 in out buf (dead until c_proj)
  u16* attn_out = (u16*)(ws + 8 * MiB);    // [4096][1024] bf16, reuses ln1b slot
  float* x1     = (float*)d_out;           // [4096][1024] fp32; final out in place

  transpose_f32_bf16<<<dim3(96, 32), 256, 0, stream>>>(c_attn_w, wt_attn, 1024, 3072);
  transpose_f32_bf16<<<dim3(32, 32), 256, 0, stream>>>(c_proj_w, wt_cproj, 1024, 1024);
  ln_f32<<<4096, 256, 0, stream>>>(x, ln1_w, ln1_b, ln1b);
  // one merged qkv GEMM, rows >=2048 routed to qkv1
  gemm_bt<0><<<dim3(24, 32), 256, 0, stream>>>(ln1b, wt_attn, c_attn_b, nullptr,
                                               qkv0, qkv1, 2048, 3072, 1024);
  attn_mfma2<<<dim3(16, 16, 2), 512, 0, stream>>>(qkv0, qkv1, attn_out);
  gemm_bt<1><<<dim3(8, 32), 256, 0, stream>>>(attn_out, wt_cproj, c_proj_b, x,
                                              x1, nullptr, BIG, 1024, 1024);

  // ---- phase 2 (chunk count adapts to workspace) ----
  // needs: 16 MiB (wt_fc+ln2b) + 4096*CN*2 (h) + 1024*CN*2 (projT)
  int NC = (ws_size >= 58720256) ? 1 : (ws_size >= 37748736) ? 2 : 4;
  int CN = 4096 / NC;
  u16* wt_fc = (u16*)(ws + 0);                                 // [4096][1024] bf16, 8 MiB
  u16* ln2b  = (u16*)(ws + 8 * MiB);                           // [4096][1024] bf16, 8 MiB
  u16* h_c   = (u16*)(ws + 16 * MiB);                          // [4096][CN] bf16
  u16* projT = (u16*)(ws + 16 * MiB + (size_t)4096 * CN * 2);  // [1024][CN] bf16

  transpose_f32_bf16<<<dim3(128, 32), 256, 0, stream>>>(fc_w, wt_fc, 1024, 4096);
  ln_f32<<<4096, 256, 0, stream>>>(x1, ln2_w, ln2_b, ln2b);
  for (int c = 0; c < NC; c++) {
    transpose_f32_bf16<<<dim3(32, CN / 32), 256, 0, stream>>>(
        proj_w + (size_t)c * CN * 1024, projT, CN, 1024);
    gemm_bt<2><<<dim3(CN / 128, 32), 256, 0, stream>>>(
        ln2b, wt_fc + (size_t)c * CN * 1024, fc_b + c * CN, nullptr,
        h_c, nullptr, BIG, CN, 1024);
    if (NC == 1)
      gemm_bt<1><<<dim3(8, 32), 256, 0, stream>>>(h_c, projT, proj_b, x1,
                                                  x1, nullptr, BIG, 1024, CN);
    else if (c < NC - 1)
      gemm_bt<3><<<dim3(8, 32), 256, 0, stream>>>(h_c, projT, nullptr, nullptr,
                                                  x1, nullptr, BIG, 1024, CN);
    else
      gemm_bt<4><<<dim3(8, 32), 256, 0, stream>>>(h_c, projT, proj_b, nullptr,
                                                  x1, nullptr, BIG, 1024, CN);
  }
}

// Round 14
// 375.509 us; speedup vs baseline: 1.2044x; 1.0060x over previous
//
#include <hip/hip_runtime.h>

typedef unsigned short u16;
typedef __attribute__((ext_vector_type(8))) short short8;
typedef __attribute__((ext_vector_type(4))) float floatx4;

__device__ __forceinline__ float bf2f(u16 u) {
  unsigned int v = ((unsigned int)u) << 16;
  return __builtin_bit_cast(float, v);
}
__device__ __forceinline__ u16 f2bf(float f) {
  unsigned int u = __builtin_bit_cast(unsigned int, f);
  u += 0x7FFFu + ((u >> 16) & 1u);
  return (u16)(u >> 16);
}
__device__ __forceinline__ void gload_lds16(const void* g, void* l) {
  __builtin_amdgcn_global_load_lds(
      (const __attribute__((address_space(1))) unsigned int*)g,
      (__attribute__((address_space(3))) unsigned int*)l, 16, 0, 0);
}

// ---------- transpose+convert: in fp32 [K][N] -> out bf16 [N][K] ----------
__global__ __launch_bounds__(256) void transpose_f32_bf16(const float* __restrict__ in,
                                                          u16* __restrict__ out,
                                                          int K, int N) {
  __shared__ float tile[32][33];
  int n0 = blockIdx.x * 32, k0 = blockIdx.y * 32;
  int tx = threadIdx.x & 31, ty = threadIdx.x >> 5;  // ty 0..7
#pragma unroll
  for (int i = 0; i < 4; i++) {
    int r = ty + i * 8;
    tile[r][tx] = in[(size_t)(k0 + r) * N + n0 + tx];
  }
  __syncthreads();
#pragma unroll
  for (int i = 0; i < 4; i++) {
    int r = ty + i * 8;
    out[(size_t)(n0 + r) * K + k0 + tx] = f2bf(tile[tx][r]);
  }
}

// ---------------- layernorm (Bessel std, eps added to std) -> bf16 ----------------
__global__ __launch_bounds__(256) void ln_f32(const float* __restrict__ xin,
                                              const float* __restrict__ wgt,
                                              const float* __restrict__ bia,
                                              u16* __restrict__ out) {
  int row = blockIdx.x, t = threadIdx.x;
  const float* xr = xin + (size_t)row * 1024 + t * 4;
  float4 f = *(const float4*)xr;
  float v[4] = {f.x, f.y, f.z, f.w};
  float s1 = v[0] + v[1] + v[2] + v[3];
  float s2 = v[0] * v[0] + v[1] * v[1] + v[2] * v[2] + v[3] * v[3];
#pragma unroll
  for (int off = 32; off; off >>= 1) {
    s1 += __shfl_down(s1, off);
    s2 += __shfl_down(s2, off);
  }
  __shared__ float red[8];
  int lane = t & 63, w = t >> 6;
  if (lane == 0) { red[w] = s1; red[4 + w] = s2; }
  __syncthreads();
  s1 = red[0] + red[1] + red[2] + red[3];
  s2 = red[4] + red[5] + red[6] + red[7];
  float mean = s1 * (1.f / 1024.f);
  float var = (s2 - 1024.f * mean * mean) * (1.f / 1023.f);
  var = var < 0.f ? 0.f : var;
  float inv = 1.f / (sqrtf(var) + 1e-5f);
  float4 wv = *(const float4*)(wgt + t * 4);
  float4 bv = *(const float4*)(bia + t * 4);
  float wa[4] = {wv.x, wv.y, wv.z, wv.w};
  float ba[4] = {bv.x, bv.y, bv.z, bv.w};
#pragma unroll
  for (int j = 0; j < 4; j++)
    out[(size_t)row * 1024 + t * 4 + j] = f2bf(wa[j] * ((v[j] - mean) * inv) + ba[j]);
}

// ------- MFMA GEMM, m97 single-buffer 2-barrier structure: C = A @ Bt^T -------
// A bf16 [M][K], Bt bf16 [N][K]. 128x128 tile, BK=64, 256 thr.
// 32 KiB LDS -> 4-5 blocks/CU (m132 lesson: the Round-4 64 KiB dbuf halved
// occupancy to 2 blocks/CU; multi-block overlap is what hides the barrier
// drain at this structure, per m114/m99/m100).
// LDS tiles XOR-swizzled (T2, measured: bank conflicts 12.6M -> 0).
// XCD-chunked block swizzle (T1); requires gridDim.x*gridDim.y % 8 == 0.
// EPI 0: bf16 out (row-split at msplit)  1: f32 = v+res  2: bf16 gelu(v)
// EPI 3: f32 += v (no bias)  4: f32 += v (with bias)
template <int EPI>
__global__ __launch_bounds__(256) void gemm_bt(const u16* __restrict__ A,
                                               const u16* __restrict__ Bt,
                                               const float* __restrict__ bias,
                                               const float* __restrict__ res,
                                               void* __restrict__ outp,
                                               void* __restrict__ outp2,
                                               int msplit,
                                               int ldc, int K) {
  __shared__ __align__(16) u16 As[128 * 64];
  __shared__ __align__(16) u16 Bs[128 * 64];
  int tid = threadIdx.x;
  int lane = tid & 63, w = tid >> 6;
  int quad = lane >> 4, c16 = lane & 15;
  int wm = w >> 1, wn = w & 1;
  // T1: XCD-chunked bijective swizzle (nwg % 8 == 0 for all launches here)
  int nbx = gridDim.x;
  int nwg = nbx * gridDim.y;
  int bid = blockIdx.y * nbx + blockIdx.x;
  int swz = (bid & 7) * (nwg >> 3) + (bid >> 3);
  int bn = swz % nbx, bm = swz / nbx;
  const u16* Ab = A + (size_t)bm * 128 * K;
  const u16* Bb = Bt + (size_t)bn * 128 * K;

  // staging geometry: lane covers dest row r = j*32 + (tid>>3), 16B slot tid&7.
  // source column pre-swizzled: slot ^ (row&7)  (row&7 == (tid>>3)&7).
  int rbase = tid >> 3;                                  // 0..31
  int csrc = (((tid & 7) ^ ((tid >> 3) & 7))) * 8;       // u16 col offset
  int dbase = w * 512;                                   // u16 dest base per wave

  floatx4 zf = {0.f, 0.f, 0.f, 0.f};
  floatx4 acc[4][4];
#pragma unroll
  for (int i = 0; i < 4; i++)
#pragma unroll
    for (int j = 0; j < 4; j++) acc[i][j] = zf;

  auto stage = [&](int kt) {
    const u16* At = Ab + kt * 64;
    const u16* Bt2 = Bb + kt * 64;
#pragma unroll
    for (int j = 0; j < 4; j++) {
      int r = j * 32 + rbase;
      gload_lds16(At + (size_t)r * K + csrc, &As[j * 2048 + dbase]);
      gload_lds16(Bt2 + (size_t)r * K + csrc, &Bs[j * 2048 + dbase]);
    }
  };

  int nt = K >> 6;
  for (int t = 0; t < nt; ++t) {
    stage(t);
    asm volatile("s_waitcnt vmcnt(0)" ::: "memory");
    __builtin_amdgcn_s_barrier();
    __builtin_amdgcn_sched_barrier(0);
#pragma unroll
    for (int ks = 0; ks < 2; ++ks) {
      int col = (ks * 32 + quad * 8) ^ ((c16 & 7) * 8);  // T2 read swizzle
      short8 af[4], bfr[4];
#pragma unroll
      for (int mt = 0; mt < 4; mt++)
        af[mt] = *(const short8*)&As[(wm * 64 + mt * 16 + c16) * 64 + col];
#pragma unroll
      for (int nt2 = 0; nt2 < 4; nt2++)
        bfr[nt2] = *(const short8*)&Bs[(wn * 64 + nt2 * 16 + c16) * 64 + col];
#pragma unroll
      for (int mt = 0; mt < 4; mt++)
#pragma unroll
        for (int nt2 = 0; nt2 < 4; nt2++)
          acc[mt][nt2] = __builtin_amdgcn_mfma_f32_16x16x32_bf16(af[mt], bfr[nt2], acc[mt][nt2], 0, 0, 0);
    }
    __builtin_amdgcn_s_barrier();   // WAR: buffer overwritten by next stage
    __builtin_amdgcn_sched_barrier(0);
  }

  int gm0 = bm * 128 + wm * 64;
  int gn0 = bn * 128 + wn * 64;
#pragma unroll
  for (int nt2 = 0; nt2 < 4; nt2++) {
    int gn = gn0 + nt2 * 16 + c16;
    float bia = 0.f;
    if constexpr (EPI != 3) bia = bias[gn];
#pragma unroll
    for (int mt = 0; mt < 4; mt++) {
#pragma unroll
      for (int r = 0; r < 4; r++) {
        int gm = gm0 + mt * 16 + quad * 4 + r;
        float v = acc[mt][nt2][r] + bia;
        if constexpr (EPI == 0) {
          void* op = outp;
          int gmo = gm;
          if (gm >= msplit) { op = outp2; gmo = gm - msplit; }
          ((u16*)op)[(size_t)gmo * ldc + gn] = f2bf(v);
        } else if constexpr (EPI == 1) {
          size_t o = (size_t)gm * ldc + gn;
          ((float*)outp)[o] = v + res[o];
        } else if constexpr (EPI == 2) {
          size_t o = (size_t)gm * ldc + gn;
          // gelu: 0.5v(1+tanh(y)) == v*sigmoid(2y); one __expf vs libm tanhf
          float y = 0.7978845608f * (v + 0.044715f * v * v * v);
          float g = v / (1.f + __expf(-2.f * y));
          ((u16*)outp)[o] = f2bf(g);
        } else {
          size_t o = (size_t)gm * ldc + gn;
          ((float*)outp)[o] += v;
        }
      }
    }
  }
}

// ---------------- flash attention v2: wave-split pair, 64-key tiles ----------------
// Ks stride 72 (pad); Vt [d][key ^ (d&56) ^ ((d&7)<<3)] full xor-swizzle
// (uniform 8-lane/bank-group tiling for b128 V-reads). P stride 72.
// Q pre-scaled by 0.125 (exact), so QK^T comes out pre-scaled.
__device__ __forceinline__ void attn_process(
    const short8& qf0, const short8& qf1,
    float* m_run, float* l_run, floatx4* oacc,
    const u16* __restrict__ Ks, const u16* __restrict__ Vt, u16* __restrict__ pw,
    int kt, int qt, int wrow, int quad, int c16, bool diag) {
  floatx4 zf = {0.f, 0.f, 0.f, 0.f};
  floatx4 s[4];
#pragma unroll
  for (int n = 0; n < 4; n++) {
    short8 kf0 = *(const short8*)&Ks[(n * 16 + c16) * 72 + quad * 8];
    short8 kf1 = *(const short8*)&Ks[(n * 16 + c16) * 72 + 32 + quad * 8];
    floatx4 a = zf;
    a = __builtin_amdgcn_mfma_f32_16x16x32_bf16(qf0, kf0, a, 0, 0, 0);
    a = __builtin_amdgcn_mfma_f32_16x16x32_bf16(qf1, kf1, a, 0, 0, 0);
    s[n] = a;
  }
  if (diag) {
#pragma unroll
    for (int n = 0; n < 4; n++) {
      int kg = kt * 64 + n * 16 + c16;
#pragma unroll
      for (int r = 0; r < 4; r++) {
        int qg = qt * 64 + wrow * 16 + quad * 4 + r;
        s[n][r] = (kg > qg) ? -1e30f : s[n][r];
      }
    }
  }
  float mt[4];
#pragma unroll
  for (int r = 0; r < 4; r++)
    mt[r] = fmaxf(fmaxf(s[0][r], s[1][r]), fmaxf(s[2][r], s[3][r]));
#pragma unroll
  for (int off = 1; off < 16; off <<= 1)
#pragma unroll
    for (int r = 0; r < 4; r++) mt[r] = fmaxf(mt[r], __shfl_xor(mt[r], off));
  float alpha[4], lsum[4];
#pragma unroll
  for (int r = 0; r < 4; r++) {
    float mn = fmaxf(m_run[r], mt[r]);
    alpha[r] = __expf(m_run[r] - mn);
    m_run[r] = mn;
    lsum[r] = 0.f;
  }
#pragma unroll
  for (int n = 0; n < 4; n++)
#pragma unroll
    for (int r = 0; r < 4; r++) {
      float p = __expf(s[n][r] - m_run[r]);
      s[n][r] = p;
      lsum[r] += p;
    }
#pragma unroll
  for (int off = 1; off < 16; off <<= 1)
#pragma unroll
    for (int r = 0; r < 4; r++) lsum[r] += __shfl_xor(lsum[r], off);
#pragma unroll
  for (int r = 0; r < 4; r++) l_run[r] = l_run[r] * alpha[r] + lsum[r];
#pragma unroll
  for (int c = 0; c < 4; c++)
#pragma unroll
    for (int r = 0; r < 4; r++) oacc[c][r] *= alpha[r];
  // P (C-layout) -> per-wave LDS, stride 72
#pragma unroll
  for (int n = 0; n < 4; n++)
#pragma unroll
    for (int r = 0; r < 4; r++)
      pw[(quad * 4 + r) * 72 + n * 16 + c16] = f2bf(s[n][r]);
  short8 pf0 = *(const short8*)&pw[c16 * 72 + quad * 8];
  short8 pf1 = *(const short8*)&pw[c16 * 72 + 32 + quad * 8];
#pragma unroll
  for (int c = 0; c < 4; c++) {
    int d = c * 16 + c16;
    int cd = (d & 56) ^ ((d & 7) << 3);
    short8 vf0 = *(const short8*)&Vt[d * 64 + ((quad * 8) ^ cd)];
    short8 vf1 = *(const short8*)&Vt[d * 64 + ((32 + quad * 8) ^ cd)];
    oacc[c] = __builtin_amdgcn_mfma_f32_16x16x32_bf16(pf0, vf0, oacc[c], 0, 0, 0);
    oacc[c] = __builtin_amdgcn_mfma_f32_16x16x32_bf16(pf1, vf1, oacc[c], 0, 0, 0);
  }
}

// multiply bf16 octet by 0.125 (power of two -> exact)
__device__ __forceinline__ short8 scale8_eighth(short8 v) {
  short8 r;
#pragma unroll
  for (int j = 0; j < 8; j++) {
    unsigned int b = ((unsigned int)(u16)v[j]) << 16;
    float f = __builtin_bit_cast(float, b) * 0.125f;
    r[j] = (short)(u16)(__builtin_bit_cast(unsigned int, f) >> 16);
  }
  return r;
}

// grid (16 pairs, 16 heads, 2 batches), 512 thr.
// Waves 0-3 own q-tile qt1=31-pr, waves 4-7 own q-tile qt0=pr; both tiles
// share the K/V staging, and run CONCURRENTLY on different waves.
__global__ __launch_bounds__(512) void attn_mfma2(const u16* __restrict__ qkv0,
                                                  const u16* __restrict__ qkv1,
                                                  u16* __restrict__ aout) {
  int pr = blockIdx.x, h = blockIdx.y;
  const u16* qkvb = blockIdx.z ? qkv1 : qkv0;
  aout += (size_t)blockIdx.z * 2048 * 1024;
  int qt0 = pr, qt1 = 31 - pr;
  int tid = threadIdx.x, lane = tid & 63, w = tid >> 6;  // w 0..7
  int quad = lane >> 4, c16 = lane & 15;
  int wrow = w & 3, tb = w >> 2;          // tb 0: tile qt1, 1: tile qt0
  int qt_my = tb ? qt0 : qt1;
  __shared__ __align__(16) u16 Ks[2][64 * 72];
  __shared__ __align__(16) u16 Vt[2][64 * 64];
  __shared__ __align__(16) u16 Ps[8][16 * 72];

  size_t qoff = (size_t)(qt_my * 64 + wrow * 16 + c16) * 3072 + h * 64;
  short8 qf0 = scale8_eighth(*(const short8*)(qkvb + qoff + quad * 8));
  short8 qf1 = scale8_eighth(*(const short8*)(qkvb + qoff + 32 + quad * 8));

  floatx4 zf = {0.f, 0.f, 0.f, 0.f};
  float m[4], l[4];
  floatx4 o[4];
#pragma unroll
  for (int r = 0; r < 4; r++) { m[r] = -1e30f; l[r] = 0.f; }
#pragma unroll
  for (int c = 0; c < 4; c++) o[c] = zf;

  // staging geometry: thread covers row srow (0..63), d [sd8, sd8+8)
  int srow = tid >> 3;
  int sd8 = (tid & 7) * 8;
  short8 kr, vr;

  auto issue = [&](int kt) {
    size_t gb = (size_t)(kt * 64 + srow) * 3072 + h * 64 + sd8;
    kr = *(const short8*)(qkvb + gb + 1024);
    vr = *(const short8*)(qkvb + gb + 2048);
  };
  auto commit = [&](int b) {
    *(short8*)&Ks[b][srow * 72 + sd8] = kr;
    u16* vt = Vt[b];
#pragma unroll
    for (int j = 0; j < 8; j++) {
      int d = sd8 + j;
      vt[d * 64 + (srow ^ (d & 56) ^ ((d & 7) << 3))] = (u16)vr[j];
    }
  };

  u16* pw = &Ps[w][0];
  issue(0);
  commit(0);
  __syncthreads();
  int cur = 0;
  for (int kt = 0; kt <= qt1; ++kt) {
    if (kt < qt1) issue(kt + 1);

    if (tb == 0 || kt <= qt0)   // wave-uniform branch; barriers stay outside
      attn_process(qf0, qf1, m, l, o, Ks[cur], Vt[cur], pw, kt, qt_my, wrow,
                   quad, c16, kt == qt_my);

    if (kt < qt1) {
      commit(cur ^ 1);   // other buffer: no hazard with waves computing on cur
      __syncthreads();   // writes visible before next tile's compute
      cur ^= 1;
    }
  }

  size_t ob = (size_t)(qt_my * 64 + wrow * 16) * 1024 + h * 64;
#pragma unroll
  for (int r = 0; r < 4; r++) {
    float inv = 1.f / l[r];
#pragma unroll
    for (int c = 0; c < 4; c++)
      aout[ob + (size_t)(quad * 4 + r) * 1024 + c * 16 + c16] = f2bf(o[c][r] * inv);
  }
}

extern "C" void kernel_launch(void* const* d_in, const int* in_sizes, int n_in,
                              void* d_out, int out_size, void* d_ws, size_t ws_size,
                              hipStream_t stream) {
  const float* x        = (const float*)d_in[0];
  const float* ln1_w    = (const float*)d_in[1];
  const float* ln1_b    = (const float*)d_in[2];
  const float* c_attn_w = (const float*)d_in[3];
  const float* c_attn_b = (const float*)d_in[4];
  const float* c_proj_w = (const float*)d_in[5];
  const float* c_proj_b = (const float*)d_in[6];
  const float* ln2_w    = (const float*)d_in[7];
  const float* ln2_b    = (const float*)d_in[8];
  const float* fc_w     = (const float*)d_in[9];
  const float* fc_b     = (const float*)d_in[10];
  const float* proj_w   = (const float*)d_in[11];
  const float* proj_b   = (const float*)d_in[12];

  char* ws = (char*)d_ws;
  const size_t MiB = 1u << 20;
  const int BIG = 1 << 30;

  // ---- phase 1 (merged batches; peak ws = 28 MiB + qkv0 parked in d_out) ----
  u16* wt_attn  = (u16*)(ws + 0);          // [3072][1024] bf16, 6 MiB
  u16* wt_cproj = (u16*)(ws + 6 * MiB);    // [1024][1024] bf16, 2 MiB
  u16* ln1b     = (u16*)(ws + 8 * MiB);    // [4096][1024] bf16, 8 MiB
  u16* qkv1     = (u16*)(ws + 16 * MiB);   // batch1 [2048][3072] bf16, 12 MiB
  u16* qkv0     = (u16*)d_out;             // batch0 [2048][3072] bf16 in out buf (dead until c_proj)
  u16* attn_out = (u16*)(ws + 8 * MiB);    // [4096][1024] bf16, reuses ln1b slot
  float* x1     = (float*)d_out;           // [4096][1024] fp32; final out in place

  transpose_f32_bf16<<<dim3(96, 32), 256, 0, stream>>>(c_attn_w, wt_attn, 1024, 3072);
  transpose_f32_bf16<<<dim3(32, 32), 256, 0, stream>>>(c_proj_w, wt_cproj, 1024, 1024);
  ln_f32<<<4096, 256, 0, stream>>>(x, ln1_w, ln1_b, ln1b);
  // one merged qkv GEMM, rows >=2048 routed to qkv1
  gemm_bt<0><<<dim3(24, 32), 256, 0, stream>>>(ln1b, wt_attn, c_attn_b, nullptr,
                                               qkv0, qkv1, 2048, 3072, 1024);
  attn_mfma2<<<dim3(16, 16, 2), 512, 0, stream>>>(qkv0, qkv1, attn_out);
  gemm_bt<1><<<dim3(8, 32), 256, 0, stream>>>(attn_out, wt_cproj, c_proj_b, x,
                                              x1, nullptr, BIG, 1024, 1024);

  // ---- phase 2 (chunk count adapts to workspace) ----
  // needs: 16 MiB (wt_fc+ln2b) + 4096*CN*2 (h) + 1024*CN*2 (projT)
  int NC = (ws_size >= 58720256) ? 1 : (ws_size >= 37748736) ? 2 : 4;
  int CN = 4096 / NC;
  u16* wt_fc = (u16*)(ws + 0);                                 // [4096][1024] bf16, 8 MiB
  u16* ln2b  = (u16*)(ws + 8 * MiB);                           // [4096][1024] bf16, 8 MiB
  u16* h_c   = (u16*)(ws + 16 * MiB);                          // [4096][CN] bf16
  u16* projT = (u16*)(ws + 16 * MiB + (size_t)4096 * CN * 2);  // [1024][CN] bf16

  transpose_f32_bf16<<<dim3(128, 32), 256, 0, stream>>>(fc_w, wt_fc, 1024, 4096);
  ln_f32<<<4096, 256, 0, stream>>>(x1, ln2_w, ln2_b, ln2b);
  for (int c = 0; c < NC; c++) {
    transpose_f32_bf16<<<dim3(32, CN / 32), 256, 0, stream>>>(
        proj_w + (size_t)c * CN * 1024, projT, CN, 1024);
    gemm_bt<2><<<dim3(CN / 128, 32), 256, 0, stream>>>(
        ln2b, wt_fc + (size_t)c * CN * 1024, fc_b + c * CN, nullptr,
        h_c, nullptr, BIG, CN, 1024);
    if (NC == 1)
      gemm_bt<1><<<dim3(8, 32), 256, 0, stream>>>(h_c, projT, proj_b, x1,
                                                  x1, nullptr, BIG, 1024, CN);
    else if (c < NC - 1)
      gemm_bt<3><<<dim3(8, 32), 256, 0, stream>>>(h_c, projT, nullptr, nullptr,
                                                  x1, nullptr, BIG, 1024, CN);
    else
      gemm_bt<4><<<dim3(8, 32), 256, 0, stream>>>(h_c, projT, proj_b, nullptr,
                                                  x1, nullptr, BIG, 1024, CN);
  }
}

// Round 15
// 357.390 us; speedup vs baseline: 1.2654x; 1.0507x over previous
//
#include <hip/hip_runtime.h>

typedef unsigned short u16;
typedef __attribute__((ext_vector_type(8))) short short8;
typedef __attribute__((ext_vector_type(4))) float floatx4;

__device__ __forceinline__ float bf2f(u16 u) {
  unsigned int v = ((unsigned int)u) << 16;
  return __builtin_bit_cast(float, v);
}
__device__ __forceinline__ u16 f2bf(float f) {
  unsigned int u = __builtin_bit_cast(unsigned int, f);
  u += 0x7FFFu + ((u >> 16) & 1u);
  return (u16)(u >> 16);
}
__device__ __forceinline__ void gload_lds16(const void* g, void* l) {
  __builtin_amdgcn_global_load_lds(
      (const __attribute__((address_space(1))) unsigned int*)g,
      (__attribute__((address_space(3))) unsigned int*)l, 16, 0, 0);
}

// ---------- transpose+convert: in fp32 [K][N] -> out bf16 [N][K] ----------
__global__ __launch_bounds__(256) void transpose_f32_bf16(const float* __restrict__ in,
                                                          u16* __restrict__ out,
                                                          int K, int N) {
  __shared__ float tile[32][33];
  int n0 = blockIdx.x * 32, k0 = blockIdx.y * 32;
  int tx = threadIdx.x & 31, ty = threadIdx.x >> 5;  // ty 0..7
#pragma unroll
  for (int i = 0; i < 4; i++) {
    int r = ty + i * 8;
    tile[r][tx] = in[(size_t)(k0 + r) * N + n0 + tx];
  }
  __syncthreads();
#pragma unroll
  for (int i = 0; i < 4; i++) {
    int r = ty + i * 8;
    out[(size_t)(n0 + r) * K + k0 + tx] = f2bf(tile[tx][r]);
  }
}

// ---------------- layernorm (Bessel std, eps added to std) -> bf16 ----------------
__global__ __launch_bounds__(256) void ln_f32(const float* __restrict__ xin,
                                              const float* __restrict__ wgt,
                                              const float* __restrict__ bia,
                                              u16* __restrict__ out) {
  int row = blockIdx.x, t = threadIdx.x;
  const float* xr = xin + (size_t)row * 1024 + t * 4;
  float4 f = *(const float4*)xr;
  float v[4] = {f.x, f.y, f.z, f.w};
  float s1 = v[0] + v[1] + v[2] + v[3];
  float s2 = v[0] * v[0] + v[1] * v[1] + v[2] * v[2] + v[3] * v[3];
#pragma unroll
  for (int off = 32; off; off >>= 1) {
    s1 += __shfl_down(s1, off);
    s2 += __shfl_down(s2, off);
  }
  __shared__ float red[8];
  int lane = t & 63, w = t >> 6;
  if (lane == 0) { red[w] = s1; red[4 + w] = s2; }
  __syncthreads();
  s1 = red[0] + red[1] + red[2] + red[3];
  s2 = red[4] + red[5] + red[6] + red[7];
  float mean = s1 * (1.f / 1024.f);
  float var = (s2 - 1024.f * mean * mean) * (1.f / 1023.f);
  var = var < 0.f ? 0.f : var;
  float inv = 1.f / (sqrtf(var) + 1e-5f);
  float4 wv = *(const float4*)(wgt + t * 4);
  float4 bv = *(const float4*)(bia + t * 4);
  float wa[4] = {wv.x, wv.y, wv.z, wv.w};
  float ba[4] = {bv.x, bv.y, bv.z, bv.w};
#pragma unroll
  for (int j = 0; j < 4; j++)
    out[(size_t)row * 1024 + t * 4 + j] = f2bf(wa[j] * ((v[j] - mean) * inv) + ba[j]);
}

// ------- MFMA GEMM, m97 single-buffer 2-barrier structure: C = A @ Bt^T -------
// 128x128 tile, BK=64, 256 thr. Used for N=1024 outputs (cproj/proj grids).
// LDS tiles XOR-swizzled (T2, measured: bank conflicts 12.6M -> 0).
// XCD-chunked block swizzle (T1); requires gridDim.x*gridDim.y % 8 == 0.
// EPI 0: bf16 out (row-split at msplit)  1: f32 = v+res  2: bf16 gelu(v)
// EPI 3: f32 += v (no bias)  4: f32 += v (with bias)
template <int EPI>
__global__ __launch_bounds__(256) void gemm_bt(const u16* __restrict__ A,
                                               const u16* __restrict__ Bt,
                                               const float* __restrict__ bias,
                                               const float* __restrict__ res,
                                               void* __restrict__ outp,
                                               void* __restrict__ outp2,
                                               int msplit,
                                               int ldc, int K) {
  __shared__ __align__(16) u16 As[128 * 64];
  __shared__ __align__(16) u16 Bs[128 * 64];
  int tid = threadIdx.x;
  int lane = tid & 63, w = tid >> 6;
  int quad = lane >> 4, c16 = lane & 15;
  int wm = w >> 1, wn = w & 1;
  int nbx = gridDim.x;
  int nwg = nbx * gridDim.y;
  int bid = blockIdx.y * nbx + blockIdx.x;
  int swz = (bid & 7) * (nwg >> 3) + (bid >> 3);
  int bn = swz % nbx, bm = swz / nbx;
  const u16* Ab = A + (size_t)bm * 128 * K;
  const u16* Bb = Bt + (size_t)bn * 128 * K;

  int rbase = tid >> 3;                                  // 0..31
  int csrc = (((tid & 7) ^ ((tid >> 3) & 7))) * 8;       // u16 col offset
  int dbase = w * 512;                                   // u16 dest base per wave

  floatx4 zf = {0.f, 0.f, 0.f, 0.f};
  floatx4 acc[4][4];
#pragma unroll
  for (int i = 0; i < 4; i++)
#pragma unroll
    for (int j = 0; j < 4; j++) acc[i][j] = zf;

  auto stage = [&](int kt) {
    const u16* At = Ab + kt * 64;
    const u16* Bt2 = Bb + kt * 64;
#pragma unroll
    for (int j = 0; j < 4; j++) {
      int r = j * 32 + rbase;
      gload_lds16(At + (size_t)r * K + csrc, &As[j * 2048 + dbase]);
      gload_lds16(Bt2 + (size_t)r * K + csrc, &Bs[j * 2048 + dbase]);
    }
  };

  int nt = K >> 6;
  for (int t = 0; t < nt; ++t) {
    stage(t);
    asm volatile("s_waitcnt vmcnt(0)" ::: "memory");
    __builtin_amdgcn_s_barrier();
    __builtin_amdgcn_sched_barrier(0);
#pragma unroll
    for (int ks = 0; ks < 2; ++ks) {
      int col = (ks * 32 + quad * 8) ^ ((c16 & 7) * 8);  // T2 read swizzle
      short8 af[4], bfr[4];
#pragma unroll
      for (int mt = 0; mt < 4; mt++)
        af[mt] = *(const short8*)&As[(wm * 64 + mt * 16 + c16) * 64 + col];
#pragma unroll
      for (int nt2 = 0; nt2 < 4; nt2++)
        bfr[nt2] = *(const short8*)&Bs[(wn * 64 + nt2 * 16 + c16) * 64 + col];
#pragma unroll
      for (int mt = 0; mt < 4; mt++)
#pragma unroll
        for (int nt2 = 0; nt2 < 4; nt2++)
          acc[mt][nt2] = __builtin_amdgcn_mfma_f32_16x16x32_bf16(af[mt], bfr[nt2], acc[mt][nt2], 0, 0, 0);
    }
    __builtin_amdgcn_s_barrier();   // WAR: buffer overwritten by next stage
    __builtin_amdgcn_sched_barrier(0);
  }

  int gm0 = bm * 128 + wm * 64;
  int gn0 = bn * 128 + wn * 64;
#pragma unroll
  for (int nt2 = 0; nt2 < 4; nt2++) {
    int gn = gn0 + nt2 * 16 + c16;
    float bia = 0.f;
    if constexpr (EPI != 3) bia = bias[gn];
#pragma unroll
    for (int mt = 0; mt < 4; mt++) {
#pragma unroll
      for (int r = 0; r < 4; r++) {
        int gm = gm0 + mt * 16 + quad * 4 + r;
        float v = acc[mt][nt2][r] + bia;
        if constexpr (EPI == 0) {
          void* op = outp;
          int gmo = gm;
          if (gm >= msplit) { op = outp2; gmo = gm - msplit; }
          ((u16*)op)[(size_t)gmo * ldc + gn] = f2bf(v);
        } else if constexpr (EPI == 1) {
          size_t o = (size_t)gm * ldc + gn;
          ((float*)outp)[o] = v + res[o];
        } else if constexpr (EPI == 2) {
          size_t o = (size_t)gm * ldc + gn;
          float y = 0.7978845608f * (v + 0.044715f * v * v * v);
          float g = v / (1.f + __expf(-2.f * y));
          ((u16*)outp)[o] = f2bf(g);
        } else {
          size_t o = (size_t)gm * ldc + gn;
          ((float*)outp)[o] += v;
        }
      }
    }
  }
}

// ------- MFMA GEMM, 256x128 tile, 512 thr (8 waves, 4M x 2N) -------
// Same verified sync (stage -> vmcnt(0) -> bar -> compute -> bar) and the same
// T2 swizzle involution as gemm_bt; per-wave inner loop identical (acc[4][4]).
// Intensity: 87 FLOP/staged-byte vs 128^2's 64 (A-panel amortized over 2x rows);
// half the barrier-drain events per CU for the same MFMA work.
// Used for N>=2048 outputs (qkv, fc). 48 KiB LDS.
template <int EPI>
__global__ __launch_bounds__(512) void gemm_bt2(const u16* __restrict__ A,
                                                const u16* __restrict__ Bt,
                                                const float* __restrict__ bias,
                                                const float* __restrict__ res,
                                                void* __restrict__ outp,
                                                void* __restrict__ outp2,
                                                int msplit,
                                                int ldc, int K) {
  __shared__ __align__(16) u16 As[256 * 64];
  __shared__ __align__(16) u16 Bs[128 * 64];
  int tid = threadIdx.x;
  int lane = tid & 63, w = tid >> 6;       // 8 waves
  int quad = lane >> 4, c16 = lane & 15;
  int wm = w >> 1, wn = w & 1;             // 4M x 2N -> per-wave 64x64
  int nbx = gridDim.x;
  int nwg = nbx * gridDim.y;
  int bid = blockIdx.y * nbx + blockIdx.x;
  int swz = (bid & 7) * (nwg >> 3) + (bid >> 3);
  int bn = swz % nbx, bm = swz / nbx;
  const u16* Ab = A + (size_t)bm * 256 * K;
  const u16* Bb = Bt + (size_t)bn * 128 * K;

  // staging: row r = j*64 + (tid>>3), 16B slot tid&7; source col pre-swizzled
  // slot ^ (row&7) (row&7 == (tid>>3)&7 since 64 ≡ 0 mod 8). Dest base is
  // wave-uniform j*4096 + w*512 (lane offset applied by gload_lds HW).
  int rbase = tid >> 3;                                  // 0..63
  int csrc = (((tid & 7) ^ ((tid >> 3) & 7))) * 8;       // u16 col offset
  int dbase = w * 512;

  floatx4 zf = {0.f, 0.f, 0.f, 0.f};
  floatx4 acc[4][4];
#pragma unroll
  for (int i = 0; i < 4; i++)
#pragma unroll
    for (int j = 0; j < 4; j++) acc[i][j] = zf;

  auto stage = [&](int kt) {
    const u16* At = Ab + kt * 64;
    const u16* Bt2 = Bb + kt * 64;
#pragma unroll
    for (int j = 0; j < 4; j++)
      gload_lds16(At + (size_t)(j * 64 + rbase) * K + csrc, &As[j * 4096 + dbase]);
#pragma unroll
    for (int j = 0; j < 2; j++)
      gload_lds16(Bt2 + (size_t)(j * 64 + rbase) * K + csrc, &Bs[j * 4096 + dbase]);
  };

  int nt = K >> 6;
  for (int t = 0; t < nt; ++t) {
    stage(t);
    asm volatile("s_waitcnt vmcnt(0)" ::: "memory");
    __builtin_amdgcn_s_barrier();
    __builtin_amdgcn_sched_barrier(0);
#pragma unroll
    for (int ks = 0; ks < 2; ++ks) {
      int col = (ks * 32 + quad * 8) ^ ((c16 & 7) * 8);  // T2 read swizzle
      short8 af[4], bfr[4];
#pragma unroll
      for (int mt = 0; mt < 4; mt++)
        af[mt] = *(const short8*)&As[(wm * 64 + mt * 16 + c16) * 64 + col];
#pragma unroll
      for (int nt2 = 0; nt2 < 4; nt2++)
        bfr[nt2] = *(const short8*)&Bs[(wn * 64 + nt2 * 16 + c16) * 64 + col];
#pragma unroll
      for (int mt = 0; mt < 4; mt++)
#pragma unroll
        for (int nt2 = 0; nt2 < 4; nt2++)
          acc[mt][nt2] = __builtin_amdgcn_mfma_f32_16x16x32_bf16(af[mt], bfr[nt2], acc[mt][nt2], 0, 0, 0);
    }
    __builtin_amdgcn_s_barrier();
    __builtin_amdgcn_sched_barrier(0);
  }

  int gm0 = bm * 256 + wm * 64;
  int gn0 = bn * 128 + wn * 64;
#pragma unroll
  for (int nt2 = 0; nt2 < 4; nt2++) {
    int gn = gn0 + nt2 * 16 + c16;
    float bia = 0.f;
    if constexpr (EPI != 3) bia = bias[gn];
#pragma unroll
    for (int mt = 0; mt < 4; mt++) {
#pragma unroll
      for (int r = 0; r < 4; r++) {
        int gm = gm0 + mt * 16 + quad * 4 + r;
        float v = acc[mt][nt2][r] + bia;
        if constexpr (EPI == 0) {
          void* op = outp;
          int gmo = gm;
          if (gm >= msplit) { op = outp2; gmo = gm - msplit; }
          ((u16*)op)[(size_t)gmo * ldc + gn] = f2bf(v);
        } else if constexpr (EPI == 1) {
          size_t o = (size_t)gm * ldc + gn;
          ((float*)outp)[o] = v + res[o];
        } else if constexpr (EPI == 2) {
          size_t o = (size_t)gm * ldc + gn;
          float y = 0.7978845608f * (v + 0.044715f * v * v * v);
          float g = v / (1.f + __expf(-2.f * y));
          ((u16*)outp)[o] = f2bf(g);
        } else {
          size_t o = (size_t)gm * ldc + gn;
          ((float*)outp)[o] += v;
        }
      }
    }
  }
}

// ---------------- flash attention v2: wave-split pair, 64-key tiles ----------------
// Ks stride 72 (pad); Vt [d][key ^ (d&56) ^ ((d&7)<<3)] full xor-swizzle
// (uniform 8-lane/bank-group tiling for b128 V-reads). P stride 72.
// Q pre-scaled by 0.125 (exact), so QK^T comes out pre-scaled.
__device__ __forceinline__ void attn_process(
    const short8& qf0, const short8& qf1,
    float* m_run, float* l_run, floatx4* oacc,
    const u16* __restrict__ Ks, const u16* __restrict__ Vt, u16* __restrict__ pw,
    int kt, int qt, int wrow, int quad, int c16, bool diag) {
  floatx4 zf = {0.f, 0.f, 0.f, 0.f};
  floatx4 s[4];
#pragma unroll
  for (int n = 0; n < 4; n++) {
    short8 kf0 = *(const short8*)&Ks[(n * 16 + c16) * 72 + quad * 8];
    short8 kf1 = *(const short8*)&Ks[(n * 16 + c16) * 72 + 32 + quad * 8];
    floatx4 a = zf;
    a = __builtin_amdgcn_mfma_f32_16x16x32_bf16(qf0, kf0, a, 0, 0, 0);
    a = __builtin_amdgcn_mfma_f32_16x16x32_bf16(qf1, kf1, a, 0, 0, 0);
    s[n] = a;
  }
  if (diag) {
#pragma unroll
    for (int n = 0; n < 4; n++) {
      int kg = kt * 64 + n * 16 + c16;
#pragma unroll
      for (int r = 0; r < 4; r++) {
        int qg = qt * 64 + wrow * 16 + quad * 4 + r;
        s[n][r] = (kg > qg) ? -1e30f : s[n][r];
      }
    }
  }
  float mt[4];
#pragma unroll
  for (int r = 0; r < 4; r++)
    mt[r] = fmaxf(fmaxf(s[0][r], s[1][r]), fmaxf(s[2][r], s[3][r]));
#pragma unroll
  for (int off = 1; off < 16; off <<= 1)
#pragma unroll
    for (int r = 0; r < 4; r++) mt[r] = fmaxf(mt[r], __shfl_xor(mt[r], off));
  float alpha[4], lsum[4];
#pragma unroll
  for (int r = 0; r < 4; r++) {
    float mn = fmaxf(m_run[r], mt[r]);
    alpha[r] = __expf(m_run[r] - mn);
    m_run[r] = mn;
    lsum[r] = 0.f;
  }
#pragma unroll
  for (int n = 0; n < 4; n++)
#pragma unroll
    for (int r = 0; r < 4; r++) {
      float p = __expf(s[n][r] - m_run[r]);
      s[n][r] = p;
      lsum[r] += p;
    }
#pragma unroll
  for (int off = 1; off < 16; off <<= 1)
#pragma unroll
    for (int r = 0; r < 4; r++) lsum[r] += __shfl_xor(lsum[r], off);
#pragma unroll
  for (int r = 0; r < 4; r++) l_run[r] = l_run[r] * alpha[r] + lsum[r];
#pragma unroll
  for (int c = 0; c < 4; c++)
#pragma unroll
    for (int r = 0; r < 4; r++) oacc[c][r] *= alpha[r];
  // P (C-layout) -> per-wave LDS, stride 72
#pragma unroll
  for (int n = 0; n < 4; n++)
#pragma unroll
    for (int r = 0; r < 4; r++)
      pw[(quad * 4 + r) * 72 + n * 16 + c16] = f2bf(s[n][r]);
  short8 pf0 = *(const short8*)&pw[c16 * 72 + quad * 8];
  short8 pf1 = *(const short8*)&pw[c16 * 72 + 32 + quad * 8];
#pragma unroll
  for (int c = 0; c < 4; c++) {
    int d = c * 16 + c16;
    int cd = (d & 56) ^ ((d & 7) << 3);
    short8 vf0 = *(const short8*)&Vt[d * 64 + ((quad * 8) ^ cd)];
    short8 vf1 = *(const short8*)&Vt[d * 64 + ((32 + quad * 8) ^ cd)];
    oacc[c] = __builtin_amdgcn_mfma_f32_16x16x32_bf16(pf0, vf0, oacc[c], 0, 0, 0);
    oacc[c] = __builtin_amdgcn_mfma_f32_16x16x32_bf16(pf1, vf1, oacc[c], 0, 0, 0);
  }
}

// multiply bf16 octet by 0.125 (power of two -> exact)
__device__ __forceinline__ short8 scale8_eighth(short8 v) {
  short8 r;
#pragma unroll
  for (int j = 0; j < 8; j++) {
    unsigned int b = ((unsigned int)(u16)v[j]) << 16;
    float f = __builtin_bit_cast(float, b) * 0.125f;
    r[j] = (short)(u16)(__builtin_bit_cast(unsigned int, f) >> 16);
  }
  return r;
}

// grid (16 pairs, 16 heads, 2 batches), 512 thr.
// Waves 0-3 own q-tile qt1=31-pr, waves 4-7 own q-tile qt0=pr; both tiles
// share the K/V staging, and run CONCURRENTLY on different waves.
__global__ __launch_bounds__(512) void attn_mfma2(const u16* __restrict__ qkv0,
                                                  const u16* __restrict__ qkv1,
                                                  u16* __restrict__ aout) {
  int pr = blockIdx.x, h = blockIdx.y;
  const u16* qkvb = blockIdx.z ? qkv1 : qkv0;
  aout += (size_t)blockIdx.z * 2048 * 1024;
  int qt0 = pr, qt1 = 31 - pr;
  int tid = threadIdx.x, lane = tid & 63, w = tid >> 6;  // w 0..7
  int quad = lane >> 4, c16 = lane & 15;
  int wrow = w & 3, tb = w >> 2;          // tb 0: tile qt1, 1: tile qt0
  int qt_my = tb ? qt0 : qt1;
  __shared__ __align__(16) u16 Ks[2][64 * 72];
  __shared__ __align__(16) u16 Vt[2][64 * 64];
  __shared__ __align__(16) u16 Ps[8][16 * 72];

  size_t qoff = (size_t)(qt_my * 64 + wrow * 16 + c16) * 3072 + h * 64;
  short8 qf0 = scale8_eighth(*(const short8*)(qkvb + qoff + quad * 8));
  short8 qf1 = scale8_eighth(*(const short8*)(qkvb + qoff + 32 + quad * 8));

  floatx4 zf = {0.f, 0.f, 0.f, 0.f};
  float m[4], l[4];
  floatx4 o[4];
#pragma unroll
  for (int r = 0; r < 4; r++) { m[r] = -1e30f; l[r] = 0.f; }
#pragma unroll
  for (int c = 0; c < 4; c++) o[c] = zf;

  // staging geometry: thread covers row srow (0..63), d [sd8, sd8+8)
  int srow = tid >> 3;
  int sd8 = (tid & 7) * 8;
  short8 kr, vr;

  auto issue = [&](int kt) {
    size_t gb = (size_t)(kt * 64 + srow) * 3072 + h * 64 + sd8;
    kr = *(const short8*)(qkvb + gb + 1024);
    vr = *(const short8*)(qkvb + gb + 2048);
  };
  auto commit = [&](int b) {
    *(short8*)&Ks[b][srow * 72 + sd8] = kr;
    u16* vt = Vt[b];
#pragma unroll
    for (int j = 0; j < 8; j++) {
      int d = sd8 + j;
      vt[d * 64 + (srow ^ (d & 56) ^ ((d & 7) << 3))] = (u16)vr[j];
    }
  };

  u16* pw = &Ps[w][0];
  issue(0);
  commit(0);
  __syncthreads();
  int cur = 0;
  for (int kt = 0; kt <= qt1; ++kt) {
    if (kt < qt1) issue(kt + 1);

    if (tb == 0 || kt <= qt0)   // wave-uniform branch; barriers stay outside
      attn_process(qf0, qf1, m, l, o, Ks[cur], Vt[cur], pw, kt, qt_my, wrow,
                   quad, c16, kt == qt_my);

    if (kt < qt1) {
      commit(cur ^ 1);   // other buffer: no hazard with waves computing on cur
      __syncthreads();   // writes visible before next tile's compute
      cur ^= 1;
    }
  }

  size_t ob = (size_t)(qt_my * 64 + wrow * 16) * 1024 + h * 64;
#pragma unroll
  for (int r = 0; r < 4; r++) {
    float inv = 1.f / l[r];
#pragma unroll
    for (int c = 0; c < 4; c++)
      aout[ob + (size_t)(quad * 4 + r) * 1024 + c * 16 + c16] = f2bf(o[c][r] * inv);
  }
}

extern "C" void kernel_launch(void* const* d_in, const int* in_sizes, int n_in,
                              void* d_out, int out_size, void* d_ws, size_t ws_size,
                              hipStream_t stream) {
  const float* x        = (const float*)d_in[0];
  const float* ln1_w    = (const float*)d_in[1];
  const float* ln1_b    = (const float*)d_in[2];
  const float* c_attn_w = (const float*)d_in[3];
  const float* c_attn_b = (const float*)d_in[4];
  const float* c_proj_w = (const float*)d_in[5];
  const float* c_proj_b = (const float*)d_in[6];
  const float* ln2_w    = (const float*)d_in[7];
  const float* ln2_b    = (const float*)d_in[8];
  const float* fc_w     = (const float*)d_in[9];
  const float* fc_b     = (const float*)d_in[10];
  const float* proj_w   = (const float*)d_in[11];
  const float* proj_b   = (const float*)d_in[12];

  char* ws = (char*)d_ws;
  const size_t MiB = 1u << 20;
  const int BIG = 1 << 30;

  // ---- phase 1 (merged batches; peak ws = 28 MiB + qkv0 parked in d_out) ----
  u16* wt_attn  = (u16*)(ws + 0);          // [3072][1024] bf16, 6 MiB
  u16* wt_cproj = (u16*)(ws + 6 * MiB);    // [1024][1024] bf16, 2 MiB
  u16* ln1b     = (u16*)(ws + 8 * MiB);    // [4096][1024] bf16, 8 MiB
  u16* qkv1     = (u16*)(ws + 16 * MiB);   // batch1 [2048][3072] bf16, 12 MiB
  u16* qkv0     = (u16*)d_out;             // batch0 [2048][3072] bf16 in out buf (dead until c_proj)
  u16* attn_out = (u16*)(ws + 8 * MiB);    // [4096][1024] bf16, reuses ln1b slot
  float* x1     = (float*)d_out;           // [4096][1024] fp32; final out in place

  transpose_f32_bf16<<<dim3(96, 32), 256, 0, stream>>>(c_attn_w, wt_attn, 1024, 3072);
  transpose_f32_bf16<<<dim3(32, 32), 256, 0, stream>>>(c_proj_w, wt_cproj, 1024, 1024);
  ln_f32<<<4096, 256, 0, stream>>>(x, ln1_w, ln1_b, ln1b);
  // one merged qkv GEMM (256x128 tiles), rows >=2048 routed to qkv1
  gemm_bt2<0><<<dim3(24, 16), 512, 0, stream>>>(ln1b, wt_attn, c_attn_b, nullptr,
                                                qkv0, qkv1, 2048, 3072, 1024);
  attn_mfma2<<<dim3(16, 16, 2), 512, 0, stream>>>(qkv0, qkv1, attn_out);
  gemm_bt<1><<<dim3(8, 32), 256, 0, stream>>>(attn_out, wt_cproj, c_proj_b, x,
                                              x1, nullptr, BIG, 1024, 1024);

  // ---- phase 2 (chunk count adapts to workspace) ----
  // needs: 16 MiB (wt_fc+ln2b) + 4096*CN*2 (h) + 1024*CN*2 (projT)
  int NC = (ws_size >= 58720256) ? 1 : (ws_size >= 37748736) ? 2 : 4;
  int CN = 4096 / NC;
  u16* wt_fc = (u16*)(ws + 0);                                 // [4096][1024] bf16, 8 MiB
  u16* ln2b  = (u16*)(ws + 8 * MiB);                           // [4096][1024] bf16, 8 MiB
  u16* h_c   = (u16*)(ws + 16 * MiB);                          // [4096][CN] bf16
  u16* projT = (u16*)(ws + 16 * MiB + (size_t)4096 * CN * 2);  // [1024][CN] bf16

  transpose_f32_bf16<<<dim3(128, 32), 256, 0, stream>>>(fc_w, wt_fc, 1024, 4096);
  ln_f32<<<4096, 256, 0, stream>>>(x1, ln2_w, ln2_b, ln2b);
  for (int c = 0; c < NC; c++) {
    transpose_f32_bf16<<<dim3(32, CN / 32), 256, 0, stream>>>(
        proj_w + (size_t)c * CN * 1024, projT, CN, 1024);
    if (CN >= 2048)   // 256x128 tiles (grid = CN/128 x 16, %8==0)
      gemm_bt2<2><<<dim3(CN / 128, 16), 512, 0, stream>>>(
          ln2b, wt_fc + (size_t)c * CN * 1024, fc_b + c * CN, nullptr,
          h_c, nullptr, BIG, CN, 1024);
    else
      gemm_bt<2><<<dim3(CN / 128, 32), 256, 0, stream>>>(
          ln2b, wt_fc + (size_t)c * CN * 1024, fc_b + c * CN, nullptr,
          h_c, nullptr, BIG, CN, 1024);
    if (NC == 1)
      gemm_bt<1><<<dim3(8, 32), 256, 0, stream>>>(h_c, projT, proj_b, x1,
                                                  x1, nullptr, BIG, 1024, CN);
    else if (c < NC - 1)
      gemm_bt<3><<<dim3(8, 32), 256, 0, stream>>>(h_c, projT, nullptr, nullptr,
                                                  x1, nullptr, BIG, 1024, CN);
    else
      gemm_bt<4><<<dim3(8, 32), 256, 0, stream>>>(h_c, projT, proj_b, nullptr,
                                                  x1, nullptr, BIG, 1024, CN);
  }
}

// Round 16
// 351.198 us; speedup vs baseline: 1.2877x; 1.0176x over previous
//
#include <hip/hip_runtime.h>

typedef unsigned short u16;
typedef __attribute__((ext_vector_type(8))) short short8;
typedef __attribute__((ext_vector_type(4))) float floatx4;

__device__ __forceinline__ float bf2f(u16 u) {
  unsigned int v = ((unsigned int)u) << 16;
  return __builtin_bit_cast(float, v);
}
__device__ __forceinline__ u16 f2bf(float f) {
  unsigned int u = __builtin_bit_cast(unsigned int, f);
  u += 0x7FFFu + ((u >> 16) & 1u);
  return (u16)(u >> 16);
}
__device__ __forceinline__ void gload_lds16(const void* g, void* l) {
  __builtin_amdgcn_global_load_lds(
      (const __attribute__((address_space(1))) unsigned int*)g,
      (__attribute__((address_space(3))) unsigned int*)l, 16, 0, 0);
}

// ---------- transpose+convert: in fp32 [K][N] -> out bf16 [N][K] ----------
__global__ __launch_bounds__(256) void transpose_f32_bf16(const float* __restrict__ in,
                                                          u16* __restrict__ out,
                                                          int K, int N) {
  __shared__ float tile[32][33];
  int n0 = blockIdx.x * 32, k0 = blockIdx.y * 32;
  int tx = threadIdx.x & 31, ty = threadIdx.x >> 5;  // ty 0..7
#pragma unroll
  for (int i = 0; i < 4; i++) {
    int r = ty + i * 8;
    tile[r][tx] = in[(size_t)(k0 + r) * N + n0 + tx];
  }
  __syncthreads();
#pragma unroll
  for (int i = 0; i < 4; i++) {
    int r = ty + i * 8;
    out[(size_t)(n0 + r) * K + k0 + tx] = f2bf(tile[tx][r]);
  }
}

// ---------------- layernorm (Bessel std, eps added to std) -> bf16 ----------------
__global__ __launch_bounds__(256) void ln_f32(const float* __restrict__ xin,
                                              const float* __restrict__ wgt,
                                              const float* __restrict__ bia,
                                              u16* __restrict__ out) {
  int row = blockIdx.x, t = threadIdx.x;
  const float* xr = xin + (size_t)row * 1024 + t * 4;
  float4 f = *(const float4*)xr;
  float v[4] = {f.x, f.y, f.z, f.w};
  float s1 = v[0] + v[1] + v[2] + v[3];
  float s2 = v[0] * v[0] + v[1] * v[1] + v[2] * v[2] + v[3] * v[3];
#pragma unroll
  for (int off = 32; off; off >>= 1) {
    s1 += __shfl_down(s1, off);
    s2 += __shfl_down(s2, off);
  }
  __shared__ float red[8];
  int lane = t & 63, w = t >> 6;
  if (lane == 0) { red[w] = s1; red[4 + w] = s2; }
  __syncthreads();
  s1 = red[0] + red[1] + red[2] + red[3];
  s2 = red[4] + red[5] + red[6] + red[7];
  float mean = s1 * (1.f / 1024.f);
  float var = (s2 - 1024.f * mean * mean) * (1.f / 1023.f);
  var = var < 0.f ? 0.f : var;
  float inv = 1.f / (sqrtf(var) + 1e-5f);
  float4 wv = *(const float4*)(wgt + t * 4);
  float4 bv = *(const float4*)(bia + t * 4);
  float wa[4] = {wv.x, wv.y, wv.z, wv.w};
  float ba[4] = {bv.x, bv.y, bv.z, bv.w};
#pragma unroll
  for (int j = 0; j < 4; j++)
    out[(size_t)row * 1024 + t * 4 + j] = f2bf(wa[j] * ((v[j] - mean) * inv) + ba[j]);
}

// ------- MFMA GEMM, m97 single-buffer 2-barrier structure: C = A @ Bt^T -------
// 128x128 tile, BK=64, 256 thr. Used for N=1024 outputs (cproj/proj grids).
// LDS tiles XOR-swizzled (T2, measured: bank conflicts 12.6M -> 0).
// XCD-chunked block swizzle (T1); requires gridDim.x*gridDim.y % 8 == 0.
// EPI 0: bf16 out (row-split at msplit)  1: f32 = v+res  2: bf16 gelu(v)
// EPI 3: f32 += v (no bias)  4: f32 += v (with bias)
template <int EPI>
__global__ __launch_bounds__(256) void gemm_bt(const u16* __restrict__ A,
                                               const u16* __restrict__ Bt,
                                               const float* __restrict__ bias,
                                               const float* __restrict__ res,
                                               void* __restrict__ outp,
                                               void* __restrict__ outp2,
                                               int msplit,
                                               int ldc, int K) {
  __shared__ __align__(16) u16 As[128 * 64];
  __shared__ __align__(16) u16 Bs[128 * 64];
  int tid = threadIdx.x;
  int lane = tid & 63, w = tid >> 6;
  int quad = lane >> 4, c16 = lane & 15;
  int wm = w >> 1, wn = w & 1;
  int nbx = gridDim.x;
  int nwg = nbx * gridDim.y;
  int bid = blockIdx.y * nbx + blockIdx.x;
  int swz = (bid & 7) * (nwg >> 3) + (bid >> 3);
  int bn = swz % nbx, bm = swz / nbx;
  const u16* Ab = A + (size_t)bm * 128 * K;
  const u16* Bb = Bt + (size_t)bn * 128 * K;

  int rbase = tid >> 3;                                  // 0..31
  int csrc = (((tid & 7) ^ ((tid >> 3) & 7))) * 8;       // u16 col offset
  int dbase = w * 512;                                   // u16 dest base per wave

  floatx4 zf = {0.f, 0.f, 0.f, 0.f};
  floatx4 acc[4][4];
#pragma unroll
  for (int i = 0; i < 4; i++)
#pragma unroll
    for (int j = 0; j < 4; j++) acc[i][j] = zf;

  auto stage = [&](int kt) {
    const u16* At = Ab + kt * 64;
    const u16* Bt2 = Bb + kt * 64;
#pragma unroll
    for (int j = 0; j < 4; j++) {
      int r = j * 32 + rbase;
      gload_lds16(At + (size_t)r * K + csrc, &As[j * 2048 + dbase]);
      gload_lds16(Bt2 + (size_t)r * K + csrc, &Bs[j * 2048 + dbase]);
    }
  };

  int nt = K >> 6;
  for (int t = 0; t < nt; ++t) {
    stage(t);
    asm volatile("s_waitcnt vmcnt(0)" ::: "memory");
    __builtin_amdgcn_s_barrier();
    __builtin_amdgcn_sched_barrier(0);
#pragma unroll
    for (int ks = 0; ks < 2; ++ks) {
      int col = (ks * 32 + quad * 8) ^ ((c16 & 7) * 8);  // T2 read swizzle
      short8 af[4], bfr[4];
#pragma unroll
      for (int mt = 0; mt < 4; mt++)
        af[mt] = *(const short8*)&As[(wm * 64 + mt * 16 + c16) * 64 + col];
#pragma unroll
      for (int nt2 = 0; nt2 < 4; nt2++)
        bfr[nt2] = *(const short8*)&Bs[(wn * 64 + nt2 * 16 + c16) * 64 + col];
#pragma unroll
      for (int mt = 0; mt < 4; mt++)
#pragma unroll
        for (int nt2 = 0; nt2 < 4; nt2++)
          acc[mt][nt2] = __builtin_amdgcn_mfma_f32_16x16x32_bf16(af[mt], bfr[nt2], acc[mt][nt2], 0, 0, 0);
    }
    __builtin_amdgcn_s_barrier();   // WAR: buffer overwritten by next stage
    __builtin_amdgcn_sched_barrier(0);
  }

  int gm0 = bm * 128 + wm * 64;
  int gn0 = bn * 128 + wn * 64;
#pragma unroll
  for (int nt2 = 0; nt2 < 4; nt2++) {
    int gn = gn0 + nt2 * 16 + c16;
    float bia = 0.f;
    if constexpr (EPI != 3) bia = bias[gn];
#pragma unroll
    for (int mt = 0; mt < 4; mt++) {
#pragma unroll
      for (int r = 0; r < 4; r++) {
        int gm = gm0 + mt * 16 + quad * 4 + r;
        float v = acc[mt][nt2][r] + bia;
        if constexpr (EPI == 0) {
          void* op = outp;
          int gmo = gm;
          if (gm >= msplit) { op = outp2; gmo = gm - msplit; }
          ((u16*)op)[(size_t)gmo * ldc + gn] = f2bf(v);
        } else if constexpr (EPI == 1) {
          size_t o = (size_t)gm * ldc + gn;
          ((float*)outp)[o] = v + res[o];
        } else if constexpr (EPI == 2) {
          size_t o = (size_t)gm * ldc + gn;
          float y = 0.7978845608f * (v + 0.044715f * v * v * v);
          float g = v / (1.f + __expf(-2.f * y));
          ((u16*)outp)[o] = f2bf(g);
        } else {
          size_t o = (size_t)gm * ldc + gn;
          ((float*)outp)[o] += v;
        }
      }
    }
  }
}

// ------- MFMA GEMM, 256x128 tile, 512 thr (8 waves, 4M x 2N) -------
// Same verified sync and T2 swizzle involution as gemm_bt; per-wave inner
// loop identical. 87 FLOP/staged-byte vs 128^2's 64. N>=2048 outputs. 48 KiB LDS.
template <int EPI>
__global__ __launch_bounds__(512) void gemm_bt2(const u16* __restrict__ A,
                                                const u16* __restrict__ Bt,
                                                const float* __restrict__ bias,
                                                const float* __restrict__ res,
                                                void* __restrict__ outp,
                                                void* __restrict__ outp2,
                                                int msplit,
                                                int ldc, int K) {
  __shared__ __align__(16) u16 As[256 * 64];
  __shared__ __align__(16) u16 Bs[128 * 64];
  int tid = threadIdx.x;
  int lane = tid & 63, w = tid >> 6;       // 8 waves
  int quad = lane >> 4, c16 = lane & 15;
  int wm = w >> 1, wn = w & 1;             // 4M x 2N -> per-wave 64x64
  int nbx = gridDim.x;
  int nwg = nbx * gridDim.y;
  int bid = blockIdx.y * nbx + blockIdx.x;
  int swz = (bid & 7) * (nwg >> 3) + (bid >> 3);
  int bn = swz % nbx, bm = swz / nbx;
  const u16* Ab = A + (size_t)bm * 256 * K;
  const u16* Bb = Bt + (size_t)bn * 128 * K;

  int rbase = tid >> 3;                                  // 0..63
  int csrc = (((tid & 7) ^ ((tid >> 3) & 7))) * 8;       // u16 col offset
  int dbase = w * 512;

  floatx4 zf = {0.f, 0.f, 0.f, 0.f};
  floatx4 acc[4][4];
#pragma unroll
  for (int i = 0; i < 4; i++)
#pragma unroll
    for (int j = 0; j < 4; j++) acc[i][j] = zf;

  auto stage = [&](int kt) {
    const u16* At = Ab + kt * 64;
    const u16* Bt2 = Bb + kt * 64;
#pragma unroll
    for (int j = 0; j < 4; j++)
      gload_lds16(At + (size_t)(j * 64 + rbase) * K + csrc, &As[j * 4096 + dbase]);
#pragma unroll
    for (int j = 0; j < 2; j++)
      gload_lds16(Bt2 + (size_t)(j * 64 + rbase) * K + csrc, &Bs[j * 4096 + dbase]);
  };

  int nt = K >> 6;
  for (int t = 0; t < nt; ++t) {
    stage(t);
    asm volatile("s_waitcnt vmcnt(0)" ::: "memory");
    __builtin_amdgcn_s_barrier();
    __builtin_amdgcn_sched_barrier(0);
#pragma unroll
    for (int ks = 0; ks < 2; ++ks) {
      int col = (ks * 32 + quad * 8) ^ ((c16 & 7) * 8);  // T2 read swizzle
      short8 af[4], bfr[4];
#pragma unroll
      for (int mt = 0; mt < 4; mt++)
        af[mt] = *(const short8*)&As[(wm * 64 + mt * 16 + c16) * 64 + col];
#pragma unroll
      for (int nt2 = 0; nt2 < 4; nt2++)
        bfr[nt2] = *(const short8*)&Bs[(wn * 64 + nt2 * 16 + c16) * 64 + col];
#pragma unroll
      for (int mt = 0; mt < 4; mt++)
#pragma unroll
        for (int nt2 = 0; nt2 < 4; nt2++)
          acc[mt][nt2] = __builtin_amdgcn_mfma_f32_16x16x32_bf16(af[mt], bfr[nt2], acc[mt][nt2], 0, 0, 0);
    }
    __builtin_amdgcn_s_barrier();
    __builtin_amdgcn_sched_barrier(0);
  }

  int gm0 = bm * 256 + wm * 64;
  int gn0 = bn * 128 + wn * 64;
#pragma unroll
  for (int nt2 = 0; nt2 < 4; nt2++) {
    int gn = gn0 + nt2 * 16 + c16;
    float bia = 0.f;
    if constexpr (EPI != 3) bia = bias[gn];
#pragma unroll
    for (int mt = 0; mt < 4; mt++) {
#pragma unroll
      for (int r = 0; r < 4; r++) {
        int gm = gm0 + mt * 16 + quad * 4 + r;
        float v = acc[mt][nt2][r] + bia;
        if constexpr (EPI == 0) {
          void* op = outp;
          int gmo = gm;
          if (gm >= msplit) { op = outp2; gmo = gm - msplit; }
          ((u16*)op)[(size_t)gmo * ldc + gn] = f2bf(v);
        } else if constexpr (EPI == 1) {
          size_t o = (size_t)gm * ldc + gn;
          ((float*)outp)[o] = v + res[o];
        } else if constexpr (EPI == 2) {
          size_t o = (size_t)gm * ldc + gn;
          float y = 0.7978845608f * (v + 0.044715f * v * v * v);
          float g = v / (1.f + __expf(-2.f * y));
          ((u16*)outp)[o] = f2bf(g);
        } else {
          size_t o = (size_t)gm * ldc + gn;
          ((float*)outp)[o] += v;
        }
      }
    }
  }
}

// ---------------- flash attention v2: wave-split pair, 64-key tiles ----------------
// Ks stride 72 (pad); Vt [d][key ^ (d&56) ^ ((d&7)<<3)] full xor-swizzle.
// Q pre-scaled by 0.125 (exact). Softmax row-sum computed via MFMA against a
// ones B-operand (l = P.1, replicated over lanes) -- kills 16 shfl_xor + 16
// adds per call on the VALU path; 2 extra MFMAs on the 9%-utilized matrix
// pipe. T13 defer-max: skip the rescale pass while max grows < 8 (P bounded
// by e^8; f32 accumulators absorb it; first call always rescales).
__device__ __forceinline__ void attn_process(
    const short8& qf0, const short8& qf1,
    float* m_run, floatx4& lacc, floatx4* oacc,
    const u16* __restrict__ Ks, const u16* __restrict__ Vt, u16* __restrict__ pw,
    int kt, int qt, int wrow, int quad, int c16, bool diag) {
  floatx4 zf = {0.f, 0.f, 0.f, 0.f};
  floatx4 s[4];
#pragma unroll
  for (int n = 0; n < 4; n++) {
    short8 kf0 = *(const short8*)&Ks[(n * 16 + c16) * 72 + quad * 8];
    short8 kf1 = *(const short8*)&Ks[(n * 16 + c16) * 72 + 32 + quad * 8];
    floatx4 a = zf;
    a = __builtin_amdgcn_mfma_f32_16x16x32_bf16(qf0, kf0, a, 0, 0, 0);
    a = __builtin_amdgcn_mfma_f32_16x16x32_bf16(qf1, kf1, a, 0, 0, 0);
    s[n] = a;
  }
  if (diag) {
#pragma unroll
    for (int n = 0; n < 4; n++) {
      int kg = kt * 64 + n * 16 + c16;
#pragma unroll
      for (int r = 0; r < 4; r++) {
        int qg = qt * 64 + wrow * 16 + quad * 4 + r;
        s[n][r] = (kg > qg) ? -1e30f : s[n][r];
      }
    }
  }
  float mt[4];
#pragma unroll
  for (int r = 0; r < 4; r++)
    mt[r] = fmaxf(fmaxf(s[0][r], s[1][r]), fmaxf(s[2][r], s[3][r]));
#pragma unroll
  for (int off = 1; off < 16; off <<= 1)
#pragma unroll
    for (int r = 0; r < 4; r++) mt[r] = fmaxf(mt[r], __shfl_xor(mt[r], off));
  // T13 defer-max: rescale only if some row's max grew beyond threshold
  bool need = false;
#pragma unroll
  for (int r = 0; r < 4; r++) need |= (mt[r] > m_run[r] + 8.f);
  if (__any(need)) {
#pragma unroll
    for (int r = 0; r < 4; r++) {
      float mn = fmaxf(m_run[r], mt[r]);
      float alpha = __expf(m_run[r] - mn);
      m_run[r] = mn;
      lacc[r] *= alpha;
#pragma unroll
      for (int c = 0; c < 4; c++) oacc[c][r] *= alpha;
    }
  }
#pragma unroll
  for (int n = 0; n < 4; n++)
#pragma unroll
    for (int r = 0; r < 4; r++)
      s[n][r] = __expf(s[n][r] - m_run[r]);
  // P (C-layout) -> per-wave LDS, stride 72
#pragma unroll
  for (int n = 0; n < 4; n++)
#pragma unroll
    for (int r = 0; r < 4; r++)
      pw[(quad * 4 + r) * 72 + n * 16 + c16] = f2bf(s[n][r]);
  short8 pf0 = *(const short8*)&pw[c16 * 72 + quad * 8];
  short8 pf1 = *(const short8*)&pw[c16 * 72 + 32 + quad * 8];
  // l += P.1 via MFMA (bf16 1.0 = 0x3F80)
  short8 ones;
#pragma unroll
  for (int j = 0; j < 8; j++) ones[j] = (short)0x3F80;
  lacc = __builtin_amdgcn_mfma_f32_16x16x32_bf16(pf0, ones, lacc, 0, 0, 0);
  lacc = __builtin_amdgcn_mfma_f32_16x16x32_bf16(pf1, ones, lacc, 0, 0, 0);
#pragma unroll
  for (int c = 0; c < 4; c++) {
    int d = c * 16 + c16;
    int cd = (d & 56) ^ ((d & 7) << 3);
    short8 vf0 = *(const short8*)&Vt[d * 64 + ((quad * 8) ^ cd)];
    short8 vf1 = *(const short8*)&Vt[d * 64 + ((32 + quad * 8) ^ cd)];
    oacc[c] = __builtin_amdgcn_mfma_f32_16x16x32_bf16(pf0, vf0, oacc[c], 0, 0, 0);
    oacc[c] = __builtin_amdgcn_mfma_f32_16x16x32_bf16(pf1, vf1, oacc[c], 0, 0, 0);
  }
}

// multiply bf16 octet by 0.125 (power of two -> exact)
__device__ __forceinline__ short8 scale8_eighth(short8 v) {
  short8 r;
#pragma unroll
  for (int j = 0; j < 8; j++) {
    unsigned int b = ((unsigned int)(u16)v[j]) << 16;
    float f = __builtin_bit_cast(float, b) * 0.125f;
    r[j] = (short)(u16)(__builtin_bit_cast(unsigned int, f) >> 16);
  }
  return r;
}

// grid (16 pairs, 16 heads, 2 batches), 512 thr.
// Waves 0-3 own q-tile qt1=31-pr, waves 4-7 own q-tile qt0=pr; both tiles
// share the K/V staging, and run CONCURRENTLY on different waves.
__global__ __launch_bounds__(512) void attn_mfma2(const u16* __restrict__ qkv0,
                                                  const u16* __restrict__ qkv1,
                                                  u16* __restrict__ aout) {
  int pr = blockIdx.x, h = blockIdx.y;
  const u16* qkvb = blockIdx.z ? qkv1 : qkv0;
  aout += (size_t)blockIdx.z * 2048 * 1024;
  int qt0 = pr, qt1 = 31 - pr;
  int tid = threadIdx.x, lane = tid & 63, w = tid >> 6;  // w 0..7
  int quad = lane >> 4, c16 = lane & 15;
  int wrow = w & 3, tb = w >> 2;          // tb 0: tile qt1, 1: tile qt0
  int qt_my = tb ? qt0 : qt1;
  __shared__ __align__(16) u16 Ks[2][64 * 72];
  __shared__ __align__(16) u16 Vt[2][64 * 64];
  __shared__ __align__(16) u16 Ps[8][16 * 72];

  size_t qoff = (size_t)(qt_my * 64 + wrow * 16 + c16) * 3072 + h * 64;
  short8 qf0 = scale8_eighth(*(const short8*)(qkvb + qoff + quad * 8));
  short8 qf1 = scale8_eighth(*(const short8*)(qkvb + qoff + 32 + quad * 8));

  floatx4 zf = {0.f, 0.f, 0.f, 0.f};
  float m[4];
  floatx4 lacc;
  floatx4 o[4];
#pragma unroll
  for (int r = 0; r < 4; r++) m[r] = -1e30f;
  lacc = zf;
#pragma unroll
  for (int c = 0; c < 4; c++) o[c] = zf;

  // staging geometry: thread covers row srow (0..63), d [sd8, sd8+8)
  int srow = tid >> 3;
  int sd8 = (tid & 7) * 8;
  short8 kr, vr;

  auto issue = [&](int kt) {
    size_t gb = (size_t)(kt * 64 + srow) * 3072 + h * 64 + sd8;
    kr = *(const short8*)(qkvb + gb + 1024);
    vr = *(const short8*)(qkvb + gb + 2048);
  };
  auto commit = [&](int b) {
    *(short8*)&Ks[b][srow * 72 + sd8] = kr;
    u16* vt = Vt[b];
#pragma unroll
    for (int j = 0; j < 8; j++) {
      int d = sd8 + j;
      vt[d * 64 + (srow ^ (d & 56) ^ ((d & 7) << 3))] = (u16)vr[j];
    }
  };

  u16* pw = &Ps[w][0];
  issue(0);
  commit(0);
  __syncthreads();
  int cur = 0;
  for (int kt = 0; kt <= qt1; ++kt) {
    if (kt < qt1) issue(kt + 1);

    if (tb == 0 || kt <= qt0)   // wave-uniform branch; barriers stay outside
      attn_process(qf0, qf1, m, lacc, o, Ks[cur], Vt[cur], pw, kt, qt_my, wrow,
                   quad, c16, kt == qt_my);

    if (kt < qt1) {
      commit(cur ^ 1);   // other buffer: no hazard with waves computing on cur
      __syncthreads();   // writes visible before next tile's compute
      cur ^= 1;
    }
  }

  size_t ob = (size_t)(qt_my * 64 + wrow * 16) * 1024 + h * 64;
#pragma unroll
  for (int r = 0; r < 4; r++) {
    float inv = 1.f / lacc[r];
#pragma unroll
    for (int c = 0; c < 4; c++)
      aout[ob + (size_t)(quad * 4 + r) * 1024 + c * 16 + c16] = f2bf(o[c][r] * inv);
  }
}

extern "C" void kernel_launch(void* const* d_in, const int* in_sizes, int n_in,
                              void* d_out, int out_size, void* d_ws, size_t ws_size,
                              hipStream_t stream) {
  const float* x        = (const float*)d_in[0];
  const float* ln1_w    = (const float*)d_in[1];
  const float* ln1_b    = (const float*)d_in[2];
  const float* c_attn_w = (const float*)d_in[3];
  const float* c_attn_b = (const float*)d_in[4];
  const float* c_proj_w = (const float*)d_in[5];
  const float* c_proj_b = (const float*)d_in[6];
  const float* ln2_w    = (const float*)d_in[7];
  const float* ln2_b    = (const float*)d_in[8];
  const float* fc_w     = (const float*)d_in[9];
  const float* fc_b     = (const float*)d_in[10];
  const float* proj_w   = (const float*)d_in[11];
  const float* proj_b   = (const float*)d_in[12];

  char* ws = (char*)d_ws;
  const size_t MiB = 1u << 20;
  const int BIG = 1 << 30;

  // ---- phase 1 (merged batches; peak ws = 28 MiB + qkv0 parked in d_out) ----
  u16* wt_attn  = (u16*)(ws + 0);          // [3072][1024] bf16, 6 MiB
  u16* wt_cproj = (u16*)(ws + 6 * MiB);    // [1024][1024] bf16, 2 MiB
  u16* ln1b     = (u16*)(ws + 8 * MiB);    // [4096][1024] bf16, 8 MiB
  u16* qkv1     = (u16*)(ws + 16 * MiB);   // batch1 [2048][3072] bf16, 12 MiB
  u16* qkv0     = (u16*)d_out;             // batch0 [2048][3072] bf16 in out buf (dead until c_proj)
  u16* attn_out = (u16*)(ws + 8 * MiB);    // [4096][1024] bf16, reuses ln1b slot
  float* x1     = (float*)d_out;           // [4096][1024] fp32; final out in place

  transpose_f32_bf16<<<dim3(96, 32), 256, 0, stream>>>(c_attn_w, wt_attn, 1024, 3072);
  transpose_f32_bf16<<<dim3(32, 32), 256, 0, stream>>>(c_proj_w, wt_cproj, 1024, 1024);
  ln_f32<<<4096, 256, 0, stream>>>(x, ln1_w, ln1_b, ln1b);
  // one merged qkv GEMM (256x128 tiles), rows >=2048 routed to qkv1
  gemm_bt2<0><<<dim3(24, 16), 512, 0, stream>>>(ln1b, wt_attn, c_attn_b, nullptr,
                                                qkv0, qkv1, 2048, 3072, 1024);
  attn_mfma2<<<dim3(16, 16, 2), 512, 0, stream>>>(qkv0, qkv1, attn_out);
  gemm_bt<1><<<dim3(8, 32), 256, 0, stream>>>(attn_out, wt_cproj, c_proj_b, x,
                                              x1, nullptr, BIG, 1024, 1024);

  // ---- phase 2 (chunk count adapts to workspace) ----
  // needs: 16 MiB (wt_fc+ln2b) + 4096*CN*2 (h) + 1024*CN*2 (projT)
  int NC = (ws_size >= 58720256) ? 1 : (ws_size >= 37748736) ? 2 : 4;
  int CN = 4096 / NC;
  u16* wt_fc = (u16*)(ws + 0);                                 // [4096][1024] bf16, 8 MiB
  u16* ln2b  = (u16*)(ws + 8 * MiB);                           // [4096][1024] bf16, 8 MiB
  u16* h_c   = (u16*)(ws + 16 * MiB);                          // [4096][CN] bf16
  u16* projT = (u16*)(ws + 16 * MiB + (size_t)4096 * CN * 2);  // [1024][CN] bf16

  transpose_f32_bf16<<<dim3(128, 32), 256, 0, stream>>>(fc_w, wt_fc, 1024, 4096);
  ln_f32<<<4096, 256, 0, stream>>>(x1, ln2_w, ln2_b, ln2b);
  for (int c = 0; c < NC; c++) {
    transpose_f32_bf16<<<dim3(32, CN / 32), 256, 0, stream>>>(
        proj_w + (size_t)c * CN * 1024, projT, CN, 1024);
    if (CN >= 2048)   // 256x128 tiles (grid = CN/128 x 16, %8==0)
      gemm_bt2<2><<<dim3(CN / 128, 16), 512, 0, stream>>>(
          ln2b, wt_fc + (size_t)c * CN * 1024, fc_b + c * CN, nullptr,
          h_c, nullptr, BIG, CN, 1024);
    else
      gemm_bt<2><<<dim3(CN / 128, 32), 256, 0, stream>>>(
          ln2b, wt_fc + (size_t)c * CN * 1024, fc_b + c * CN, nullptr,
          h_c, nullptr, BIG, CN, 1024);
    if (NC == 1)
      gemm_bt<1><<<dim3(8, 32), 256, 0, stream>>>(h_c, projT, proj_b, x1,
                                                  x1, nullptr, BIG, 1024, CN);
    else if (c < NC - 1)
      gemm_bt<3><<<dim3(8, 32), 256, 0, stream>>>(h_c, projT, nullptr, nullptr,
                                                  x1, nullptr, BIG, 1024, CN);
    else
      gemm_bt<4><<<dim3(8, 32), 256, 0, stream>>>(h_c, projT, proj_b, nullptr,
                                                  x1, nullptr, BIG, 1024, CN);
  }
}

// Round 17
// 343.529 us; speedup vs baseline: 1.3165x; 1.0223x over previous
//
#include <hip/hip_runtime.h>

typedef unsigned short u16;
typedef __attribute__((ext_vector_type(8))) short short8;
typedef __attribute__((ext_vector_type(4))) float floatx4;

__device__ __forceinline__ float bf2f(u16 u) {
  unsigned int v = ((unsigned int)u) << 16;
  return __builtin_bit_cast(float, v);
}
__device__ __forceinline__ u16 f2bf(float f) {
  unsigned int u = __builtin_bit_cast(unsigned int, f);
  u += 0x7FFFu + ((u >> 16) & 1u);
  return (u16)(u >> 16);
}
__device__ __forceinline__ void gload_lds16(const void* g, void* l) {
  __builtin_amdgcn_global_load_lds(
      (const __attribute__((address_space(1))) unsigned int*)g,
      (__attribute__((address_space(3))) unsigned int*)l, 16, 0, 0);
}

// ---------- transpose+convert: in fp32 [K][N] -> out bf16 [N][K] ----------
__global__ __launch_bounds__(256) void transpose_f32_bf16(const float* __restrict__ in,
                                                          u16* __restrict__ out,
                                                          int K, int N) {
  __shared__ float tile[32][33];
  int n0 = blockIdx.x * 32, k0 = blockIdx.y * 32;
  int tx = threadIdx.x & 31, ty = threadIdx.x >> 5;  // ty 0..7
#pragma unroll
  for (int i = 0; i < 4; i++) {
    int r = ty + i * 8;
    tile[r][tx] = in[(size_t)(k0 + r) * N + n0 + tx];
  }
  __syncthreads();
#pragma unroll
  for (int i = 0; i < 4; i++) {
    int r = ty + i * 8;
    out[(size_t)(n0 + r) * K + k0 + tx] = f2bf(tile[tx][r]);
  }
}

// ---------------- layernorm (Bessel std, eps added to std) -> bf16 ----------------
__global__ __launch_bounds__(256) void ln_f32(const float* __restrict__ xin,
                                              const float* __restrict__ wgt,
                                              const float* __restrict__ bia,
                                              u16* __restrict__ out) {
  int row = blockIdx.x, t = threadIdx.x;
  const float* xr = xin + (size_t)row * 1024 + t * 4;
  float4 f = *(const float4*)xr;
  float v[4] = {f.x, f.y, f.z, f.w};
  float s1 = v[0] + v[1] + v[2] + v[3];
  float s2 = v[0] * v[0] + v[1] * v[1] + v[2] * v[2] + v[3] * v[3];
#pragma unroll
  for (int off = 32; off; off >>= 1) {
    s1 += __shfl_down(s1, off);
    s2 += __shfl_down(s2, off);
  }
  __shared__ float red[8];
  int lane = t & 63, w = t >> 6;
  if (lane == 0) { red[w] = s1; red[4 + w] = s2; }
  __syncthreads();
  s1 = red[0] + red[1] + red[2] + red[3];
  s2 = red[4] + red[5] + red[6] + red[7];
  float mean = s1 * (1.f / 1024.f);
  float var = (s2 - 1024.f * mean * mean) * (1.f / 1023.f);
  var = var < 0.f ? 0.f : var;
  float inv = 1.f / (sqrtf(var) + 1e-5f);
  float4 wv = *(const float4*)(wgt + t * 4);
  float4 bv = *(const float4*)(bia + t * 4);
  float wa[4] = {wv.x, wv.y, wv.z, wv.w};
  float ba[4] = {bv.x, bv.y, bv.z, bv.w};
#pragma unroll
  for (int j = 0; j < 4; j++)
    out[(size_t)row * 1024 + t * 4 + j] = f2bf(wa[j] * ((v[j] - mean) * inv) + ba[j]);
}

// ------- MFMA GEMM, m97 single-buffer 2-barrier structure: C = A @ Bt^T -------
// 128x128 tile, BK=64, 256 thr (4 waves). Fallback for small-N chunked paths.
// T2 XOR-swizzle (conflicts 0); T1 XCD swizzle; grid %8 == 0 required.
// EPI 0: bf16 out (row-split at msplit)  1: f32 = v+res  2: bf16 gelu(v)
// EPI 3: f32 += v (no bias)  4: f32 += v (with bias)
template <int EPI>
__global__ __launch_bounds__(256) void gemm_bt(const u16* __restrict__ A,
                                               const u16* __restrict__ Bt,
                                               const float* __restrict__ bias,
                                               const float* __restrict__ res,
                                               void* __restrict__ outp,
                                               void* __restrict__ outp2,
                                               int msplit,
                                               int ldc, int K) {
  __shared__ __align__(16) u16 As[128 * 64];
  __shared__ __align__(16) u16 Bs[128 * 64];
  int tid = threadIdx.x;
  int lane = tid & 63, w = tid >> 6;
  int quad = lane >> 4, c16 = lane & 15;
  int wm = w >> 1, wn = w & 1;
  int nbx = gridDim.x;
  int nwg = nbx * gridDim.y;
  int bid = blockIdx.y * nbx + blockIdx.x;
  int swz = (bid & 7) * (nwg >> 3) + (bid >> 3);
  int bn = swz % nbx, bm = swz / nbx;
  const u16* Ab = A + (size_t)bm * 128 * K;
  const u16* Bb = Bt + (size_t)bn * 128 * K;

  int rbase = tid >> 3;                                  // 0..31
  int csrc = (((tid & 7) ^ ((tid >> 3) & 7))) * 8;       // u16 col offset
  int dbase = w * 512;                                   // u16 dest base per wave

  floatx4 zf = {0.f, 0.f, 0.f, 0.f};
  floatx4 acc[4][4];
#pragma unroll
  for (int i = 0; i < 4; i++)
#pragma unroll
    for (int j = 0; j < 4; j++) acc[i][j] = zf;

  auto stage = [&](int kt) {
    const u16* At = Ab + kt * 64;
    const u16* Bt2 = Bb + kt * 64;
#pragma unroll
    for (int j = 0; j < 4; j++) {
      int r = j * 32 + rbase;
      gload_lds16(At + (size_t)r * K + csrc, &As[j * 2048 + dbase]);
      gload_lds16(Bt2 + (size_t)r * K + csrc, &Bs[j * 2048 + dbase]);
    }
  };

  int nt = K >> 6;
  for (int t = 0; t < nt; ++t) {
    stage(t);
    asm volatile("s_waitcnt vmcnt(0)" ::: "memory");
    __builtin_amdgcn_s_barrier();
    __builtin_amdgcn_sched_barrier(0);
#pragma unroll
    for (int ks = 0; ks < 2; ++ks) {
      int col = (ks * 32 + quad * 8) ^ ((c16 & 7) * 8);  // T2 read swizzle
      short8 af[4], bfr[4];
#pragma unroll
      for (int mt = 0; mt < 4; mt++)
        af[mt] = *(const short8*)&As[(wm * 64 + mt * 16 + c16) * 64 + col];
#pragma unroll
      for (int nt2 = 0; nt2 < 4; nt2++)
        bfr[nt2] = *(const short8*)&Bs[(wn * 64 + nt2 * 16 + c16) * 64 + col];
#pragma unroll
      for (int mt = 0; mt < 4; mt++)
#pragma unroll
        for (int nt2 = 0; nt2 < 4; nt2++)
          acc[mt][nt2] = __builtin_amdgcn_mfma_f32_16x16x32_bf16(af[mt], bfr[nt2], acc[mt][nt2], 0, 0, 0);
    }
    __builtin_amdgcn_s_barrier();   // WAR: buffer overwritten by next stage
    __builtin_amdgcn_sched_barrier(0);
  }

  int gm0 = bm * 128 + wm * 64;
  int gn0 = bn * 128 + wn * 64;
#pragma unroll
  for (int nt2 = 0; nt2 < 4; nt2++) {
    int gn = gn0 + nt2 * 16 + c16;
    float bia = 0.f;
    if constexpr (EPI != 3) bia = bias[gn];
#pragma unroll
    for (int mt = 0; mt < 4; mt++) {
#pragma unroll
      for (int r = 0; r < 4; r++) {
        int gm = gm0 + mt * 16 + quad * 4 + r;
        float v = acc[mt][nt2][r] + bia;
        if constexpr (EPI == 0) {
          void* op = outp;
          int gmo = gm;
          if (gm >= msplit) { op = outp2; gmo = gm - msplit; }
          ((u16*)op)[(size_t)gmo * ldc + gn] = f2bf(v);
        } else if constexpr (EPI == 1) {
          size_t o = (size_t)gm * ldc + gn;
          ((float*)outp)[o] = v + res[o];
        } else if constexpr (EPI == 2) {
          size_t o = (size_t)gm * ldc + gn;
          float y = 0.7978845608f * (v + 0.044715f * v * v * v);
          float g = v / (1.f + __expf(-2.f * y));
          ((u16*)outp)[o] = f2bf(g);
        } else {
          size_t o = (size_t)gm * ldc + gn;
          ((float*)outp)[o] += v;
        }
      }
    }
  }
}

// ------- MFMA GEMM, 256x128 tile, 512 thr (8 waves, 4M x 2N) -------
// Same verified sync and T2 swizzle involution; 87 FLOP/staged-byte.
// N>=2048 outputs (qkv, fc). 48 KiB LDS.
template <int EPI>
__global__ __launch_bounds__(512) void gemm_bt2(const u16* __restrict__ A,
                                                const u16* __restrict__ Bt,
                                                const float* __restrict__ bias,
                                                const float* __restrict__ res,
                                                void* __restrict__ outp,
                                                void* __restrict__ outp2,
                                                int msplit,
                                                int ldc, int K) {
  __shared__ __align__(16) u16 As[256 * 64];
  __shared__ __align__(16) u16 Bs[128 * 64];
  int tid = threadIdx.x;
  int lane = tid & 63, w = tid >> 6;       // 8 waves
  int quad = lane >> 4, c16 = lane & 15;
  int wm = w >> 1, wn = w & 1;             // 4M x 2N -> per-wave 64x64
  int nbx = gridDim.x;
  int nwg = nbx * gridDim.y;
  int bid = blockIdx.y * nbx + blockIdx.x;
  int swz = (bid & 7) * (nwg >> 3) + (bid >> 3);
  int bn = swz % nbx, bm = swz / nbx;
  const u16* Ab = A + (size_t)bm * 256 * K;
  const u16* Bb = Bt + (size_t)bn * 128 * K;

  int rbase = tid >> 3;                                  // 0..63
  int csrc = (((tid & 7) ^ ((tid >> 3) & 7))) * 8;       // u16 col offset
  int dbase = w * 512;

  floatx4 zf = {0.f, 0.f, 0.f, 0.f};
  floatx4 acc[4][4];
#pragma unroll
  for (int i = 0; i < 4; i++)
#pragma unroll
    for (int j = 0; j < 4; j++) acc[i][j] = zf;

  auto stage = [&](int kt) {
    const u16* At = Ab + kt * 64;
    const u16* Bt2 = Bb + kt * 64;
#pragma unroll
    for (int j = 0; j < 4; j++)
      gload_lds16(At + (size_t)(j * 64 + rbase) * K + csrc, &As[j * 4096 + dbase]);
#pragma unroll
    for (int j = 0; j < 2; j++)
      gload_lds16(Bt2 + (size_t)(j * 64 + rbase) * K + csrc, &Bs[j * 4096 + dbase]);
  };

  int nt = K >> 6;
  for (int t = 0; t < nt; ++t) {
    stage(t);
    asm volatile("s_waitcnt vmcnt(0)" ::: "memory");
    __builtin_amdgcn_s_barrier();
    __builtin_amdgcn_sched_barrier(0);
#pragma unroll
    for (int ks = 0; ks < 2; ++ks) {
      int col = (ks * 32 + quad * 8) ^ ((c16 & 7) * 8);  // T2 read swizzle
      short8 af[4], bfr[4];
#pragma unroll
      for (int mt = 0; mt < 4; mt++)
        af[mt] = *(const short8*)&As[(wm * 64 + mt * 16 + c16) * 64 + col];
#pragma unroll
      for (int nt2 = 0; nt2 < 4; nt2++)
        bfr[nt2] = *(const short8*)&Bs[(wn * 64 + nt2 * 16 + c16) * 64 + col];
#pragma unroll
      for (int mt = 0; mt < 4; mt++)
#pragma unroll
        for (int nt2 = 0; nt2 < 4; nt2++)
          acc[mt][nt2] = __builtin_amdgcn_mfma_f32_16x16x32_bf16(af[mt], bfr[nt2], acc[mt][nt2], 0, 0, 0);
    }
    __builtin_amdgcn_s_barrier();
    __builtin_amdgcn_sched_barrier(0);
  }

  int gm0 = bm * 256 + wm * 64;
  int gn0 = bn * 128 + wn * 64;
#pragma unroll
  for (int nt2 = 0; nt2 < 4; nt2++) {
    int gn = gn0 + nt2 * 16 + c16;
    float bia = 0.f;
    if constexpr (EPI != 3) bia = bias[gn];
#pragma unroll
    for (int mt = 0; mt < 4; mt++) {
#pragma unroll
      for (int r = 0; r < 4; r++) {
        int gm = gm0 + mt * 16 + quad * 4 + r;
        float v = acc[mt][nt2][r] + bia;
        if constexpr (EPI == 0) {
          void* op = outp;
          int gmo = gm;
          if (gm >= msplit) { op = outp2; gmo = gm - msplit; }
          ((u16*)op)[(size_t)gmo * ldc + gn] = f2bf(v);
        } else if constexpr (EPI == 1) {
          size_t o = (size_t)gm * ldc + gn;
          ((float*)outp)[o] = v + res[o];
        } else if constexpr (EPI == 2) {
          size_t o = (size_t)gm * ldc + gn;
          float y = 0.7978845608f * (v + 0.044715f * v * v * v);
          float g = v / (1.f + __expf(-2.f * y));
          ((u16*)outp)[o] = f2bf(g);
        } else {
          size_t o = (size_t)gm * ldc + gn;
          ((float*)outp)[o] += v;
        }
      }
    }
  }
}

// ------- MFMA GEMM, 128x128 tile, 512 thr (8 waves, 2M x 4N) -------
// For GRID-STARVED N=1024 outputs (c_proj/proj: 256 blocks = 1 block/CU).
// 4-wave version leaves 1 wave/SIMD -> zero intra-SIMD latency hiding
// (measured: proj Occupancy 9.9%, MfmaUtil 17.6%). 8 waves = 2 waves/SIMD
// at the same 32 KiB LDS; per-wave 64x32 (acc[4][2]). Same sync + T2.
template <int EPI>
__global__ __launch_bounds__(512) void gemm_bt3(const u16* __restrict__ A,
                                                const u16* __restrict__ Bt,
                                                const float* __restrict__ bias,
                                                const float* __restrict__ res,
                                                void* __restrict__ outp,
                                                void* __restrict__ outp2,
                                                int msplit,
                                                int ldc, int K) {
  __shared__ __align__(16) u16 As[128 * 64];
  __shared__ __align__(16) u16 Bs[128 * 64];
  int tid = threadIdx.x;
  int lane = tid & 63, w = tid >> 6;       // 8 waves
  int quad = lane >> 4, c16 = lane & 15;
  int wm = w >> 2, wn = w & 3;             // 2M x 4N -> per-wave 64x32
  int nbx = gridDim.x;
  int nwg = nbx * gridDim.y;
  int bid = blockIdx.y * nbx + blockIdx.x;
  int swz = (bid & 7) * (nwg >> 3) + (bid >> 3);
  int bn = swz % nbx, bm = swz / nbx;
  const u16* Ab = A + (size_t)bm * 128 * K;
  const u16* Bb = Bt + (size_t)bn * 128 * K;

  // staging: 512 thr, rows j*64 + (tid>>3) (j=0,1), slot tid&7; dest lane-linear
  // (w*512 + j*4096 u16), source col pre-swizzled slot ^ (row&7).
  int rbase = tid >> 3;                                  // 0..63
  int csrc = (((tid & 7) ^ ((tid >> 3) & 7))) * 8;       // u16 col offset
  int dbase = w * 512;

  floatx4 zf = {0.f, 0.f, 0.f, 0.f};
  floatx4 acc[4][2];
#pragma unroll
  for (int i = 0; i < 4; i++)
#pragma unroll
    for (int j = 0; j < 2; j++) acc[i][j] = zf;

  auto stage = [&](int kt) {
    const u16* At = Ab + kt * 64;
    const u16* Bt2 = Bb + kt * 64;
#pragma unroll
    for (int j = 0; j < 2; j++) {
      gload_lds16(At + (size_t)(j * 64 + rbase) * K + csrc, &As[j * 4096 + dbase]);
      gload_lds16(Bt2 + (size_t)(j * 64 + rbase) * K + csrc, &Bs[j * 4096 + dbase]);
    }
  };

  int nt = K >> 6;
  for (int t = 0; t < nt; ++t) {
    stage(t);
    asm volatile("s_waitcnt vmcnt(0)" ::: "memory");
    __builtin_amdgcn_s_barrier();
    __builtin_amdgcn_sched_barrier(0);
#pragma unroll
    for (int ks = 0; ks < 2; ++ks) {
      int col = (ks * 32 + quad * 8) ^ ((c16 & 7) * 8);  // T2 read swizzle
      short8 af[4], bfr[2];
#pragma unroll
      for (int mt = 0; mt < 4; mt++)
        af[mt] = *(const short8*)&As[(wm * 64 + mt * 16 + c16) * 64 + col];
#pragma unroll
      for (int nt2 = 0; nt2 < 2; nt2++)
        bfr[nt2] = *(const short8*)&Bs[(wn * 32 + nt2 * 16 + c16) * 64 + col];
#pragma unroll
      for (int mt = 0; mt < 4; mt++)
#pragma unroll
        for (int nt2 = 0; nt2 < 2; nt2++)
          acc[mt][nt2] = __builtin_amdgcn_mfma_f32_16x16x32_bf16(af[mt], bfr[nt2], acc[mt][nt2], 0, 0, 0);
    }
    __builtin_amdgcn_s_barrier();
    __builtin_amdgcn_sched_barrier(0);
  }

  int gm0 = bm * 128 + wm * 64;
  int gn0 = bn * 128 + wn * 32;
#pragma unroll
  for (int nt2 = 0; nt2 < 2; nt2++) {
    int gn = gn0 + nt2 * 16 + c16;
    float bia = 0.f;
    if constexpr (EPI != 3) bia = bias[gn];
#pragma unroll
    for (int mt = 0; mt < 4; mt++) {
#pragma unroll
      for (int r = 0; r < 4; r++) {
        int gm = gm0 + mt * 16 + quad * 4 + r;
        float v = acc[mt][nt2][r] + bia;
        if constexpr (EPI == 0) {
          void* op = outp;
          int gmo = gm;
          if (gm >= msplit) { op = outp2; gmo = gm - msplit; }
          ((u16*)op)[(size_t)gmo * ldc + gn] = f2bf(v);
        } else if constexpr (EPI == 1) {
          size_t o = (size_t)gm * ldc + gn;
          ((float*)outp)[o] = v + res[o];
        } else if constexpr (EPI == 2) {
          size_t o = (size_t)gm * ldc + gn;
          float y = 0.7978845608f * (v + 0.044715f * v * v * v);
          float g = v / (1.f + __expf(-2.f * y));
          ((u16*)outp)[o] = f2bf(g);
        } else {
          size_t o = (size_t)gm * ldc + gn;
          ((float*)outp)[o] += v;
        }
      }
    }
  }
}

// ---------------- flash attention v2: wave-split pair, 64-key tiles ----------------
// Ks stride 72 (pad); Vt [d][key ^ (d&56) ^ ((d&7)<<3)] full xor-swizzle.
// Q pre-scaled by 0.125 (exact). Row-sum via MFMA vs ones (l = P.1);
// T13 defer-max (skip rescale while max growth < 8).
__device__ __forceinline__ void attn_process(
    const short8& qf0, const short8& qf1,
    float* m_run, floatx4& lacc, floatx4* oacc,
    const u16* __restrict__ Ks, const u16* __restrict__ Vt, u16* __restrict__ pw,
    int kt, int qt, int wrow, int quad, int c16, bool diag) {
  floatx4 zf = {0.f, 0.f, 0.f, 0.f};
  floatx4 s[4];
#pragma unroll
  for (int n = 0; n < 4; n++) {
    short8 kf0 = *(const short8*)&Ks[(n * 16 + c16) * 72 + quad * 8];
    short8 kf1 = *(const short8*)&Ks[(n * 16 + c16) * 72 + 32 + quad * 8];
    floatx4 a = zf;
    a = __builtin_amdgcn_mfma_f32_16x16x32_bf16(qf0, kf0, a, 0, 0, 0);
    a = __builtin_amdgcn_mfma_f32_16x16x32_bf16(qf1, kf1, a, 0, 0, 0);
    s[n] = a;
  }
  if (diag) {
#pragma unroll
    for (int n = 0; n < 4; n++) {
      int kg = kt * 64 + n * 16 + c16;
#pragma unroll
      for (int r = 0; r < 4; r++) {
        int qg = qt * 64 + wrow * 16 + quad * 4 + r;
        s[n][r] = (kg > qg) ? -1e30f : s[n][r];
      }
    }
  }
  float mt[4];
#pragma unroll
  for (int r = 0; r < 4; r++)
    mt[r] = fmaxf(fmaxf(s[0][r], s[1][r]), fmaxf(s[2][r], s[3][r]));
#pragma unroll
  for (int off = 1; off < 16; off <<= 1)
#pragma unroll
    for (int r = 0; r < 4; r++) mt[r] = fmaxf(mt[r], __shfl_xor(mt[r], off));
  bool need = false;
#pragma unroll
  for (int r = 0; r < 4; r++) need |= (mt[r] > m_run[r] + 8.f);
  if (__any(need)) {
#pragma unroll
    for (int r = 0; r < 4; r++) {
      float mn = fmaxf(m_run[r], mt[r]);
      float alpha = __expf(m_run[r] - mn);
      m_run[r] = mn;
      lacc[r] *= alpha;
#pragma unroll
      for (int c = 0; c < 4; c++) oacc[c][r] *= alpha;
    }
  }
#pragma unroll
  for (int n = 0; n < 4; n++)
#pragma unroll
    for (int r = 0; r < 4; r++)
      s[n][r] = __expf(s[n][r] - m_run[r]);
  // P (C-layout) -> per-wave LDS, stride 72
#pragma unroll
  for (int n = 0; n < 4; n++)
#pragma unroll
    for (int r = 0; r < 4; r++)
      pw[(quad * 4 + r) * 72 + n * 16 + c16] = f2bf(s[n][r]);
  short8 pf0 = *(const short8*)&pw[c16 * 72 + quad * 8];
  short8 pf1 = *(const short8*)&pw[c16 * 72 + 32 + quad * 8];
  // l += P.1 via MFMA (bf16 1.0 = 0x3F80)
  short8 ones;
#pragma unroll
  for (int j = 0; j < 8; j++) ones[j] = (short)0x3F80;
  lacc = __builtin_amdgcn_mfma_f32_16x16x32_bf16(pf0, ones, lacc, 0, 0, 0);
  lacc = __builtin_amdgcn_mfma_f32_16x16x32_bf16(pf1, ones, lacc, 0, 0, 0);
#pragma unroll
  for (int c = 0; c < 4; c++) {
    int d = c * 16 + c16;
    int cd = (d & 56) ^ ((d & 7) << 3);
    short8 vf0 = *(const short8*)&Vt[d * 64 + ((quad * 8) ^ cd)];
    short8 vf1 = *(const short8*)&Vt[d * 64 + ((32 + quad * 8) ^ cd)];
    oacc[c] = __builtin_amdgcn_mfma_f32_16x16x32_bf16(pf0, vf0, oacc[c], 0, 0, 0);
    oacc[c] = __builtin_amdgcn_mfma_f32_16x16x32_bf16(pf1, vf1, oacc[c], 0, 0, 0);
  }
}

// multiply bf16 octet by 0.125 (power of two -> exact)
__device__ __forceinline__ short8 scale8_eighth(short8 v) {
  short8 r;
#pragma unroll
  for (int j = 0; j < 8; j++) {
    unsigned int b = ((unsigned int)(u16)v[j]) << 16;
    float f = __builtin_bit_cast(float, b) * 0.125f;
    r[j] = (short)(u16)(__builtin_bit_cast(unsigned int, f) >> 16);
  }
  return r;
}

// grid (16 pairs, 16 heads, 2 batches), 512 thr.
__global__ __launch_bounds__(512) void attn_mfma2(const u16* __restrict__ qkv0,
                                                  const u16* __restrict__ qkv1,
                                                  u16* __restrict__ aout) {
  int pr = blockIdx.x, h = blockIdx.y;
  const u16* qkvb = blockIdx.z ? qkv1 : qkv0;
  aout += (size_t)blockIdx.z * 2048 * 1024;
  int qt0 = pr, qt1 = 31 - pr;
  int tid = threadIdx.x, lane = tid & 63, w = tid >> 6;  // w 0..7
  int quad = lane >> 4, c16 = lane & 15;
  int wrow = w & 3, tb = w >> 2;          // tb 0: tile qt1, 1: tile qt0
  int qt_my = tb ? qt0 : qt1;
  __shared__ __align__(16) u16 Ks[2][64 * 72];
  __shared__ __align__(16) u16 Vt[2][64 * 64];
  __shared__ __align__(16) u16 Ps[8][16 * 72];

  size_t qoff = (size_t)(qt_my * 64 + wrow * 16 + c16) * 3072 + h * 64;
  short8 qf0 = scale8_eighth(*(const short8*)(qkvb + qoff + quad * 8));
  short8 qf1 = scale8_eighth(*(const short8*)(qkvb + qoff + 32 + quad * 8));

  floatx4 zf = {0.f, 0.f, 0.f, 0.f};
  float m[4];
  floatx4 lacc;
  floatx4 o[4];
#pragma unroll
  for (int r = 0; r < 4; r++) m[r] = -1e30f;
  lacc = zf;
#pragma unroll
  for (int c = 0; c < 4; c++) o[c] = zf;

  int srow = tid >> 3;
  int sd8 = (tid & 7) * 8;
  short8 kr, vr;

  auto issue = [&](int kt) {
    size_t gb = (size_t)(kt * 64 + srow) * 3072 + h * 64 + sd8;
    kr = *(const short8*)(qkvb + gb + 1024);
    vr = *(const short8*)(qkvb + gb + 2048);
  };
  auto commit = [&](int b) {
    *(short8*)&Ks[b][srow * 72 + sd8] = kr;
    u16* vt = Vt[b];
#pragma unroll
    for (int j = 0; j < 8; j++) {
      int d = sd8 + j;
      vt[d * 64 + (srow ^ (d & 56) ^ ((d & 7) << 3))] = (u16)vr[j];
    }
  };

  u16* pw = &Ps[w][0];
  issue(0);
  commit(0);
  __syncthreads();
  int cur = 0;
  for (int kt = 0; kt <= qt1; ++kt) {
    if (kt < qt1) issue(kt + 1);

    if (tb == 0 || kt <= qt0)   // wave-uniform branch; barriers stay outside
      attn_process(qf0, qf1, m, lacc, o, Ks[cur], Vt[cur], pw, kt, qt_my, wrow,
                   quad, c16, kt == qt_my);

    if (kt < qt1) {
      commit(cur ^ 1);
      __syncthreads();
      cur ^= 1;
    }
  }

  size_t ob = (size_t)(qt_my * 64 + wrow * 16) * 1024 + h * 64;
#pragma unroll
  for (int r = 0; r < 4; r++) {
    float inv = 1.f / lacc[r];
#pragma unroll
    for (int c = 0; c < 4; c++)
      aout[ob + (size_t)(quad * 4 + r) * 1024 + c * 16 + c16] = f2bf(o[c][r] * inv);
  }
}

extern "C" void kernel_launch(void* const* d_in, const int* in_sizes, int n_in,
                              void* d_out, int out_size, void* d_ws, size_t ws_size,
                              hipStream_t stream) {
  const float* x        = (const float*)d_in[0];
  const float* ln1_w    = (const float*)d_in[1];
  const float* ln1_b    = (const float*)d_in[2];
  const float* c_attn_w = (const float*)d_in[3];
  const float* c_attn_b = (const float*)d_in[4];
  const float* c_proj_w = (const float*)d_in[5];
  const float* c_proj_b = (const float*)d_in[6];
  const float* ln2_w    = (const float*)d_in[7];
  const float* ln2_b    = (const float*)d_in[8];
  const float* fc_w     = (const float*)d_in[9];
  const float* fc_b     = (const float*)d_in[10];
  const float* proj_w   = (const float*)d_in[11];
  const float* proj_b   = (const float*)d_in[12];

  char* ws = (char*)d_ws;
  const size_t MiB = 1u << 20;
  const int BIG = 1 << 30;

  // ---- phase 1 (merged batches; peak ws = 28 MiB + qkv0 parked in d_out) ----
  u16* wt_attn  = (u16*)(ws + 0);          // [3072][1024] bf16, 6 MiB
  u16* wt_cproj = (u16*)(ws + 6 * MiB);    // [1024][1024] bf16, 2 MiB
  u16* ln1b     = (u16*)(ws + 8 * MiB);    // [4096][1024] bf16, 8 MiB
  u16* qkv1     = (u16*)(ws + 16 * MiB);   // batch1 [2048][3072] bf16, 12 MiB
  u16* qkv0     = (u16*)d_out;             // batch0 [2048][3072] bf16 in out buf (dead until c_proj)
  u16* attn_out = (u16*)(ws + 8 * MiB);    // [4096][1024] bf16, reuses ln1b slot
  float* x1     = (float*)d_out;           // [4096][1024] fp32; final out in place

  transpose_f32_bf16<<<dim3(96, 32), 256, 0, stream>>>(c_attn_w, wt_attn, 1024, 3072);
  transpose_f32_bf16<<<dim3(32, 32), 256, 0, stream>>>(c_proj_w, wt_cproj, 1024, 1024);
  ln_f32<<<4096, 256, 0, stream>>>(x, ln1_w, ln1_b, ln1b);
  // one merged qkv GEMM (256x128 tiles), rows >=2048 routed to qkv1
  gemm_bt2<0><<<dim3(24, 16), 512, 0, stream>>>(ln1b, wt_attn, c_attn_b, nullptr,
                                                qkv0, qkv1, 2048, 3072, 1024);
  attn_mfma2<<<dim3(16, 16, 2), 512, 0, stream>>>(qkv0, qkv1, attn_out);
  gemm_bt3<1><<<dim3(8, 32), 512, 0, stream>>>(attn_out, wt_cproj, c_proj_b, x,
                                               x1, nullptr, BIG, 1024, 1024);

  // ---- phase 2 (chunk count adapts to workspace) ----
  int NC = (ws_size >= 58720256) ? 1 : (ws_size >= 37748736) ? 2 : 4;
  int CN = 4096 / NC;
  u16* wt_fc = (u16*)(ws + 0);                                 // [4096][1024] bf16, 8 MiB
  u16* ln2b  = (u16*)(ws + 8 * MiB);                           // [4096][1024] bf16, 8 MiB
  u16* h_c   = (u16*)(ws + 16 * MiB);                          // [4096][CN] bf16
  u16* projT = (u16*)(ws + 16 * MiB + (size_t)4096 * CN * 2);  // [1024][CN] bf16

  transpose_f32_bf16<<<dim3(128, 32), 256, 0, stream>>>(fc_w, wt_fc, 1024, 4096);
  ln_f32<<<4096, 256, 0, stream>>>(x1, ln2_w, ln2_b, ln2b);
  for (int c = 0; c < NC; c++) {
    transpose_f32_bf16<<<dim3(32, CN / 32), 256, 0, stream>>>(
        proj_w + (size_t)c * CN * 1024, projT, CN, 1024);
    if (CN >= 2048)   // 256x128 tiles (grid = CN/128 x 16, %8==0)
      gemm_bt2<2><<<dim3(CN / 128, 16), 512, 0, stream>>>(
          ln2b, wt_fc + (size_t)c * CN * 1024, fc_b + c * CN, nullptr,
          h_c, nullptr, BIG, CN, 1024);
    else
      gemm_bt<2><<<dim3(CN / 128, 32), 256, 0, stream>>>(
          ln2b, wt_fc + (size_t)c * CN * 1024, fc_b + c * CN, nullptr,
          h_c, nullptr, BIG, CN, 1024);
    if (NC == 1)
      gemm_bt3<1><<<dim3(8, 32), 512, 0, stream>>>(h_c, projT, proj_b, x1,
                                                   x1, nullptr, BIG, 1024, CN);
    else if (c < NC - 1)
      gemm_bt3<3><<<dim3(8, 32), 512, 0, stream>>>(h_c, projT, nullptr, nullptr,
                                                   x1, nullptr, BIG, 1024, CN);
    else
      gemm_bt3<4><<<dim3(8, 32), 512, 0, stream>>>(h_c, projT, proj_b, nullptr,
                                                   x1, nullptr, BIG, 1024, CN);
  }
}